// Round 13
// baseline (559.722 us; speedup 1.0000x reference)
//
#include <hip/hip_runtime.h>
#include <hip/hip_bf16.h>
#include <stdint.h>

#define D_DIM 1024
#define H_DIM 4096
#define E_NUM 8
#define NTOK  4096   // B*S
#define CAP_E 4096
#define BM 128
#define BN 128
#define BK 64        // bf16 elems per K-tile; LDS row = 128 B = 8 chunks of 16 B

typedef __bf16 bf16x8 __attribute__((ext_vector_type(8)));
typedef float  f32x4  __attribute__((ext_vector_type(4)));

static __device__ __forceinline__ unsigned short f2bf(float f) {
    union { float f; unsigned u; } v; v.f = f;
    unsigned r = v.u + 0x7fffu + ((v.u >> 16) & 1u);   // RNE
    return (unsigned short)(r >> 16);
}

static __device__ __forceinline__ void gload16(const unsigned short* g, unsigned short* l) {
    __builtin_amdgcn_global_load_lds(
        (const __attribute__((address_space(1))) unsigned int*)g,
        (__attribute__((address_space(3))) unsigned int*)l,
        16, 0, 0);
}

// exact-erf GELU via Abramowitz-Stegun 7.1.26 (|err| <= 1.5e-7)
static __device__ __forceinline__ float gelu_f(float v) {
    const float z = fabsf(v) * 0.70710678118654752f;
    const float t = __builtin_amdgcn_rcpf(__builtin_fmaf(0.3275911f, z, 1.f));
    float p = __builtin_fmaf(1.061405429f, t, -1.453152027f);
    p = __builtin_fmaf(p, t, 1.421413741f);
    p = __builtin_fmaf(p, t, -0.284496736f);
    p = __builtin_fmaf(p, t, 0.254829592f);
    const float e = 1.f - p * t * __expf(-z * z);
    const float erfv = (v < 0.f) ? -e : e;
    return v * (0.5f + 0.5f * erfv);
}

// ---------------- gating (+ fused x->bf16 convert) --------------------------
__global__ __launch_bounds__(256) void gate_kernel(
    const float* __restrict__ x, const float* __restrict__ gw,
    const float* __restrict__ gb, int* __restrict__ counts,
    int* __restrict__ tok_list, float* __restrict__ prob_list,
    unsigned short* __restrict__ xb)
{
    const int wave = threadIdx.x >> 6, lane = threadIdx.x & 63;
    const int t = blockIdx.x * 4 + wave;
    double s[E_NUM];
#pragma unroll
    for (int j = 0; j < E_NUM; ++j) s[j] = 0.0;
    const float* xr = x + (size_t)t * D_DIM;
    unsigned short* xbr = xb + (size_t)t * D_DIM;
#pragma unroll
    for (int i = 0; i < D_DIM / 64; ++i) {
        const int d = i * 64 + lane;
        const float xv = xr[d];
        xbr[d] = f2bf(xv);
        const float4 g0 = *(const float4*)(gw + d * 8);
        const float4 g1 = *(const float4*)(gw + d * 8 + 4);
        s[0] += (double)xv * g0.x; s[1] += (double)xv * g0.y;
        s[2] += (double)xv * g0.z; s[3] += (double)xv * g0.w;
        s[4] += (double)xv * g1.x; s[5] += (double)xv * g1.y;
        s[6] += (double)xv * g1.z; s[7] += (double)xv * g1.w;
    }
#pragma unroll
    for (int off = 32; off >= 1; off >>= 1)
#pragma unroll
        for (int j = 0; j < E_NUM; ++j) s[j] += __shfl_xor(s[j], off, 64);

    if (lane == 0) {
#pragma unroll
        for (int j = 0; j < E_NUM; ++j) s[j] += (double)gb[j];
        int i0 = 0;
        for (int j = 1; j < E_NUM; ++j) if (s[j] > s[i0]) i0 = j;
        int i1 = (i0 == 0) ? 1 : 0;
        for (int j = 0; j < E_NUM; ++j) if (j != i0 && s[j] > s[i1]) i1 = j;
        const double e1 = exp(s[i1] - s[i0]);
        const float p0 = (float)(1.0 / (1.0 + e1));
        const float p1 = (float)(e1 / (1.0 + e1));
        int pos0 = atomicAdd(&counts[i0], 1);
        tok_list[i0 * CAP_E + pos0]  = t;
        prob_list[i0 * CAP_E + pos0] = p0;
        int pos1 = atomicAdd(&counts[i1], 1);
        tok_list[i1 * CAP_E + pos1]  = t;
        prob_list[i1 * CAP_E + pos1] = p1;
    }
}

__global__ void offsets_kernel(const int* __restrict__ counts, int* __restrict__ offsets) {
    if (threadIdx.x == 0) {
        int acc = 0;
        for (int e = 0; e < E_NUM; ++e) { offsets[e] = acc; acc += counts[e]; }
    }
}

// ---------------- weight transpose+convert: in [R][C] fp32 -> out [C][R] bf16
__global__ __launch_bounds__(256) void wtrans_kernel(
    const float* __restrict__ in, unsigned short* __restrict__ out, int R, int C)
{
    __shared__ unsigned tile[64][33];
    const size_t slab = (size_t)blockIdx.z * (size_t)R * C;
    const float* inp = in + slab;
    unsigned short* outp = out + slab;
    const int c0 = blockIdx.x * 64, r0 = blockIdx.y * 64;
    const int tid = threadIdx.x;
    const int cq = tid & 15, p0 = tid >> 4;
#pragma unroll
    for (int s = 0; s < 2; ++s) {
        const int p = p0 + s * 16;
        const int r = r0 + 2 * p;
        const int c = c0 + cq * 4;
        const float4 va = *(const float4*)(inp + (size_t)r * C + c);
        const float4 vb = *(const float4*)(inp + (size_t)(r + 1) * C + c);
        const float* fa = (const float*)&va;
        const float* fb = (const float*)&vb;
#pragma unroll
        for (int i = 0; i < 4; ++i)
            tile[cq * 4 + i][p] = (unsigned)f2bf(fa[i]) | ((unsigned)f2bf(fb[i]) << 16);
    }
    __syncthreads();
    const int cl = tid >> 2, q = tid & 3;
#pragma unroll
    for (int s = 0; s < 2; ++s) {
        const int qq = q + s * 4;
        uint4 wv;
        wv.x = tile[cl][qq * 4 + 0]; wv.y = tile[cl][qq * 4 + 1];
        wv.z = tile[cl][qq * 4 + 2]; wv.w = tile[cl][qq * 4 + 3];
        *(uint4*)(outp + (size_t)(c0 + cl) * R + r0 + qq * 8) = wv;
    }
}

// ---------------- FC1: 128x128, dbuf single-barrier, e->XCD pinned ----------
__global__ __launch_bounds__(256) void expert_fc1(
    const unsigned short* __restrict__ xb, const unsigned short* __restrict__ w1t,
    const float* __restrict__ b1, const int* __restrict__ counts,
    const int* __restrict__ offsets, const int* __restrict__ tok_list,
    unsigned short* __restrict__ h_ws,
    int e_param, int we_param, int row_start, int cap, int packed)
{
    __shared__ __align__(16) unsigned short As[2][BM * BK];   // 32 KB
    __shared__ __align__(16) unsigned short Bs[2][BM * BK];   // 32 KB

    int e, bx, by;
    if (e_param >= 0) { e = e_param; bx = (int)blockIdx.x & 31; by = (int)blockIdx.x >> 5; }
    else { e = (int)blockIdx.x & 7; const int r = (int)blockIdx.x >> 3; bx = r & 31; by = r >> 5; }

    const int we = (we_param >= 0) ? we_param : e;
    const int cnt = counts[e];
    const int row_end = min(cnt, row_start + cap);
    const int row0 = row_start + by * BM;
    if (row0 >= row_end) return;
    const int n0 = bx * BN;
    const int hb = packed ? offsets[e] : 0;
    const int tid = threadIdx.x;

    const int wv = tid >> 6, lane = tid & 63;
    const int schunk = (lane & 7) ^ (lane >> 3);
    const unsigned short* __restrict__ w1e = w1t + (size_t)we * H_DIM * D_DIM;

    const unsigned short* aptr[4];
    const unsigned short* bptr[4];
#pragma unroll
    for (int j = 0; j < 4; ++j) {
        const int r = (wv * 4 + j) * 8 + (lane >> 3);
        const int rr = min(row0 + r, row_end - 1);
        aptr[j] = xb + (size_t)tok_list[e * CAP_E + rr] * D_DIM + schunk * 8;
        bptr[j] = w1e + (size_t)(n0 + r) * D_DIM + schunk * 8;
    }

    const int wr = (wv >> 1) * 64, wc = (wv & 1) * 64;
    const int rl = lane & 15, x7 = lane & 7, kg = lane >> 4;
    int aoff[2][4], boff[2][4];
#pragma unroll
    for (int s = 0; s < 2; ++s) {
        const int slot = ((((s << 2) + kg) ^ x7) << 3);
#pragma unroll
        for (int m = 0; m < 4; ++m) aoff[s][m] = ((wr + m * 16 + rl) << 6) + slot;
#pragma unroll
        for (int n = 0; n < 4; ++n) boff[s][n] = ((wc + n * 16 + rl) << 6) + slot;
    }

    f32x4 acc[4][4];
#pragma unroll
    for (int m = 0; m < 4; ++m)
#pragma unroll
        for (int n = 0; n < 4; ++n) acc[m][n] = (f32x4){0.f, 0.f, 0.f, 0.f};

    // prologue: stage tile 0 into buf 0
#pragma unroll
    for (int j = 0; j < 4; ++j) {
        gload16(aptr[j], &As[0][(wv * 4 + j) * 512]);
        gload16(bptr[j], &Bs[0][(wv * 4 + j) * 512]);
    }
    __syncthreads();

    const int NT = D_DIM / BK;   // 16
    int cur = 0;
    for (int t = 0; t < NT; ++t) {
        if (t + 1 < NT) {                    // issue next-tile stage FIRST
            const int kn = (t + 1) * BK;
#pragma unroll
            for (int j = 0; j < 4; ++j) {
                gload16(aptr[j] + kn, &As[cur ^ 1][(wv * 4 + j) * 512]);
                gload16(bptr[j] + kn, &Bs[cur ^ 1][(wv * 4 + j) * 512]);
            }
        }
        const unsigned short* Ac = As[cur];
        const unsigned short* Bc = Bs[cur];
        __builtin_amdgcn_s_setprio(1);
#pragma unroll
        for (int s = 0; s < 2; ++s) {
            bf16x8 af[4], bfv[4];
#pragma unroll
            for (int m = 0; m < 4; ++m) af[m] = *(const bf16x8*)&Ac[aoff[s][m]];
#pragma unroll
            for (int n = 0; n < 4; ++n) bfv[n] = *(const bf16x8*)&Bc[boff[s][n]];
#pragma unroll
            for (int m = 0; m < 4; ++m)
#pragma unroll
                for (int n = 0; n < 4; ++n)
                    acc[m][n] = __builtin_amdgcn_mfma_f32_16x16x32_bf16(af[m], bfv[n], acc[m][n], 0, 0, 0);
        }
        __builtin_amdgcn_s_setprio(0);
        __syncthreads();                     // drains stage (vmcnt0) + reads done
        cur ^= 1;
    }

    // epilogue: GELU + bias, LDS-bounce to coalesced 16B stores.
    // Scratch reuses As (contiguous 32 KB >= 64*132*2 B = 16.5 KB).
    unsigned short* smem = &As[0][0];
    const float* __restrict__ b1e = b1 + e * H_DIM;
    const int crb = (lane >> 4) * 4, ccol = lane & 15;
    float bias[4];
#pragma unroll
    for (int n = 0; n < 4; ++n) bias[n] = b1e[n0 + wc + n * 16 + ccol];

    __syncthreads();
    const int mychunk = wr >> 6;
#pragma unroll
    for (int c = 0; c < 2; ++c) {
        if (mychunk == c) {
#pragma unroll
            for (int n = 0; n < 4; ++n)
#pragma unroll
                for (int m = 0; m < 4; ++m)
#pragma unroll
                    for (int j = 0; j < 4; ++j) {
                        const int rloc = m * 16 + crb + j;
                        const int col = wc + n * 16 + ccol;
                        smem[rloc * 132 + col] = f2bf(gelu_f(acc[m][n][j] + bias[n]));
                    }
        }
        __syncthreads();
#pragma unroll
        for (int i = 0; i < 4; ++i) {
            const int idx = tid + i * 256;
            const int row = idx >> 4, c8 = idx & 15;
            const uint4 val = *(const uint4*)&smem[row * 132 + c8 * 8];
            const int gr = row0 + c * 64 + row;
            if (gr < row_end)
                *(uint4*)&h_ws[(size_t)(hb + gr - row_start) * H_DIM + n0 + c8 * 8] = val;
        }
        __syncthreads();
    }
}

// ---------------- FC2: 128x128, dbuf single-barrier, split-K=2, atomics -----
// full decode: bx = bid&7 (column-stripe -> XCD); r=bid>>3: by=r&31, ks=r>>5;
// e = bid>>9.
__global__ __launch_bounds__(256) void expert_fc2(
    const unsigned short* __restrict__ h_ws, const unsigned short* __restrict__ w2t,
    const float* __restrict__ b2, const int* __restrict__ counts,
    const int* __restrict__ offsets, const int* __restrict__ tok_list,
    const float* __restrict__ prob_list, float* __restrict__ out,
    int splitk, int e_param, int we_param, int row_start, int cap, int packed)
{
    __shared__ __align__(16) unsigned short As[2][BM * BK];   // 32 KB
    __shared__ __align__(16) unsigned short Bs[2][BM * BK];   // 32 KB

    int e, bx, by, ks;
    if (e_param >= 0) { e = e_param; bx = (int)blockIdx.x & 7; by = (int)blockIdx.x >> 3; ks = 0; }
    else { e = (int)blockIdx.x >> 9; const int r = ((int)blockIdx.x >> 3) & 63;
           bx = (int)blockIdx.x & 7; by = r & 31; ks = r >> 5; }

    const int we = (we_param >= 0) ? we_param : e;
    const int cnt = counts[e];
    const int row_end = min(cnt, row_start + cap);
    const int row0 = row_start + by * BM;
    if (row0 >= row_end) return;
    const int n0 = bx * BN;
    const int hb = packed ? offsets[e] : 0;
    const int tid = threadIdx.x;

    const int kspan = H_DIM / splitk;
    const int k0 = ks * kspan;

    const int wv = tid >> 6, lane = tid & 63;
    const int schunk = (lane & 7) ^ (lane >> 3);
    const unsigned short* __restrict__ w2e = w2t + (size_t)we * D_DIM * H_DIM;

    const unsigned short* aptr[4];
    const unsigned short* bptr[4];
#pragma unroll
    for (int j = 0; j < 4; ++j) {
        const int rloc = (wv * 4 + j) * 8 + (lane >> 3);
        int r = row0 + rloc; if (r >= row_end) r = row_end - 1;
        aptr[j] = h_ws + (size_t)(hb + r - row_start) * H_DIM + k0 + schunk * 8;
        bptr[j] = w2e + (size_t)(n0 + rloc) * H_DIM + k0 + schunk * 8;
    }

    const int wr = (wv >> 1) * 64, wc = (wv & 1) * 64;
    const int rl = lane & 15, x7 = lane & 7, kg = lane >> 4;
    int aoff[2][4], boff[2][4];
#pragma unroll
    for (int s = 0; s < 2; ++s) {
        const int slot = ((((s << 2) + kg) ^ x7) << 3);
#pragma unroll
        for (int m = 0; m < 4; ++m) aoff[s][m] = ((wr + m * 16 + rl) << 6) + slot;
#pragma unroll
        for (int n = 0; n < 4; ++n) boff[s][n] = ((wc + n * 16 + rl) << 6) + slot;
    }

    f32x4 acc[4][4];
#pragma unroll
    for (int m = 0; m < 4; ++m)
#pragma unroll
        for (int n = 0; n < 4; ++n) acc[m][n] = (f32x4){0.f, 0.f, 0.f, 0.f};

    // prologue
#pragma unroll
    for (int j = 0; j < 4; ++j) {
        gload16(aptr[j], &As[0][(wv * 4 + j) * 512]);
        gload16(bptr[j], &Bs[0][(wv * 4 + j) * 512]);
    }
    __syncthreads();

    const int NT = kspan / BK;
    int cur = 0;
    for (int t = 0; t < NT; ++t) {
        if (t + 1 < NT) {
            const int kn = (t + 1) * BK;
#pragma unroll
            for (int j = 0; j < 4; ++j) {
                gload16(aptr[j] + kn, &As[cur ^ 1][(wv * 4 + j) * 512]);
                gload16(bptr[j] + kn, &Bs[cur ^ 1][(wv * 4 + j) * 512]);
            }
        }
        const unsigned short* Ac = As[cur];
        const unsigned short* Bc = Bs[cur];
        __builtin_amdgcn_s_setprio(1);
#pragma unroll
        for (int s = 0; s < 2; ++s) {
            bf16x8 af[4], bfv[4];
#pragma unroll
            for (int m = 0; m < 4; ++m) af[m] = *(const bf16x8*)&Ac[aoff[s][m]];
#pragma unroll
            for (int n = 0; n < 4; ++n) bfv[n] = *(const bf16x8*)&Bc[boff[s][n]];
#pragma unroll
            for (int m = 0; m < 4; ++m)
#pragma unroll
                for (int n = 0; n < 4; ++n)
                    acc[m][n] = __builtin_amdgcn_mfma_f32_16x16x32_bf16(af[m], bfv[n], acc[m][n], 0, 0, 0);
        }
        __builtin_amdgcn_s_setprio(0);
        __syncthreads();
        cur ^= 1;
    }

    const float* __restrict__ b2e = b2 + e * D_DIM;
    const int crb = (lane >> 4) * 4, ccol = lane & 15;
#pragma unroll
    for (int n = 0; n < 4; ++n) {
        const int gc = n0 + wc + n * 16 + ccol;
        const float bias = (ks == 0) ? b2e[gc] : 0.f;
#pragma unroll
        for (int m = 0; m < 4; ++m) {
#pragma unroll
            for (int j = 0; j < 4; ++j) {
                const int gr = row0 + wr + m * 16 + crb + j;
                if (gr < row_end) {
                    const float yv = acc[m][n][j] + bias;
                    const int t = tok_list[e * CAP_E + gr];
                    const float p = prob_list[e * CAP_E + gr];
                    atomicAdd(&out[(size_t)t * D_DIM + gc], p * yv);
                }
            }
        }
    }
}

extern "C" void kernel_launch(void* const* d_in, const int* in_sizes, int n_in,
                              void* d_out, int out_size, void* d_ws, size_t ws_size,
                              hipStream_t stream)
{
    const float* x  = (const float*)d_in[0];
    const float* w1 = (const float*)d_in[1];
    const float* b1 = (const float*)d_in[2];
    const float* w2 = (const float*)d_in[3];
    const float* b2 = (const float*)d_in[4];
    const float* gw = (const float*)d_in[5];
    const float* gb = (const float*)d_in[6];
    float* out = (float*)d_out;

    char* w = (char*)d_ws;
    int*   counts    = (int*)w;
    int*   offsets   = (int*)(w + 64);
    int*   tok_list  = (int*)(w + 128);
    float* prob_list = (float*)(w + 128 + (size_t)CAP_E * E_NUM * 4);
    size_t off = 128 + 2 * (size_t)CAP_E * E_NUM * 4;
    off = (off + 255) & ~(size_t)255;
    unsigned short* xb = (unsigned short*)(w + off);
    off += (size_t)NTOK * D_DIM * 2;

    const size_t wslab = (size_t)D_DIM * H_DIM * 2;       // bf16 per expert
    const size_t hfull = (size_t)2 * NTOK * H_DIM * 2;    // packed h, bf16
    const size_t need_full = off + 2 * E_NUM * wslab + hfull;

    hipMemsetAsync(d_out, 0, (size_t)out_size * sizeof(float), stream);
    hipMemsetAsync(counts, 0, 64, stream);

    gate_kernel<<<NTOK / 4, 256, 0, stream>>>(x, gw, gb, counts, tok_list, prob_list, xb);
    offsets_kernel<<<1, 64, 0, stream>>>(counts, offsets);

    if (ws_size >= need_full) {
        unsigned short* w1t = (unsigned short*)(w + off);
        unsigned short* w2t = (unsigned short*)(w + off + E_NUM * wslab);
        unsigned short* h_ws = (unsigned short*)(w + off + 2 * E_NUM * wslab);

        wtrans_kernel<<<dim3(H_DIM / 64, D_DIM / 64, E_NUM), 256, 0, stream>>>(w1, w1t, D_DIM, H_DIM);
        wtrans_kernel<<<dim3(D_DIM / 64, H_DIM / 64, E_NUM), 256, 0, stream>>>(w2, w2t, H_DIM, D_DIM);

        // fc1: 8 e * 32 bx * 32 by (e -> XCD pinned; empties early-exit)
        expert_fc1<<<8 * 32 * 32, 256, 0, stream>>>(
            xb, w1t, b1, counts, offsets, tok_list, h_ws, -1, -1, 0, NTOK, 1);
        // fc2: 8 bx * 32 by * 2 ks * 8 e = 4096 blocks (column-stripe -> XCD)
        expert_fc2<<<8 * 32 * 2 * 8, 256, 0, stream>>>(
            h_ws, w2t, b2, counts, offsets, tok_list, prob_list, out,
            2, -1, -1, 0, NTOK, 1);
    } else {
        // per-expert chunked fallback (atomics)
        unsigned short* w1te = (unsigned short*)(w + off);
        unsigned short* w2te = (unsigned short*)(w + off + wslab);
        size_t h_off = off + 2 * wslab;
        unsigned short* h_e = (unsigned short*)(w + h_off);
        size_t h_avail = (ws_size > h_off) ? (ws_size - h_off) / ((size_t)H_DIM * 2) : 0;
        int cap = (int)((h_avail < (size_t)NTOK) ? h_avail : (size_t)NTOK);
        cap = (cap / BM) * BM;
        if (cap < BM) cap = BM;
        const int chunks = (NTOK + cap - 1) / cap;
        for (int e = 0; e < E_NUM; ++e) {
            wtrans_kernel<<<dim3(H_DIM / 64, D_DIM / 64, 1), 256, 0, stream>>>(
                w1 + (size_t)e * D_DIM * H_DIM, w1te, D_DIM, H_DIM);
            wtrans_kernel<<<dim3(D_DIM / 64, H_DIM / 64, 1), 256, 0, stream>>>(
                w2 + (size_t)e * H_DIM * D_DIM, w2te, H_DIM, D_DIM);
            for (int c = 0; c < chunks; ++c) {
                const int rs = c * cap;
                const int gy1 = (cap + BM - 1) / BM;
                expert_fc1<<<32 * gy1, 256, 0, stream>>>(
                    xb, w1te, b1, counts, offsets, tok_list, h_e,
                    e, 0, rs, cap, 0);
                expert_fc2<<<8 * gy1, 256, 0, stream>>>(
                    h_e, w2te, b2, counts, offsets, tok_list, prob_list, out,
                    1, e, 0, rs, cap, 0);
            }
        }
    }
}

// Round 14
// 507.364 us; speedup vs baseline: 1.1032x; 1.1032x over previous
//
#include <hip/hip_runtime.h>
#include <hip/hip_bf16.h>
#include <stdint.h>

#define D_DIM 1024
#define H_DIM 4096
#define E_NUM 8
#define NTOK  4096   // B*S
#define CAP_E 4096
#define BM 128
#define BN 128
#define BK 64        // bf16 elems per K-tile; LDS row = 128 B = 8 chunks of 16 B

typedef __bf16 bf16x8 __attribute__((ext_vector_type(8)));
typedef float  f32x4  __attribute__((ext_vector_type(4)));

static __device__ __forceinline__ unsigned short f2bf(float f) {
    union { float f; unsigned u; } v; v.f = f;
    unsigned r = v.u + 0x7fffu + ((v.u >> 16) & 1u);   // RNE
    return (unsigned short)(r >> 16);
}

static __device__ __forceinline__ void gload16(const unsigned short* g, unsigned short* l) {
    __builtin_amdgcn_global_load_lds(
        (const __attribute__((address_space(1))) unsigned int*)g,
        (__attribute__((address_space(3))) unsigned int*)l,
        16, 0, 0);
}

// exact-erf GELU via Abramowitz-Stegun 7.1.26 (|err| <= 1.5e-7)
static __device__ __forceinline__ float gelu_f(float v) {
    const float z = fabsf(v) * 0.70710678118654752f;
    const float t = __builtin_amdgcn_rcpf(__builtin_fmaf(0.3275911f, z, 1.f));
    float p = __builtin_fmaf(1.061405429f, t, -1.453152027f);
    p = __builtin_fmaf(p, t, 1.421413741f);
    p = __builtin_fmaf(p, t, -0.284496736f);
    p = __builtin_fmaf(p, t, 0.254829592f);
    const float e = 1.f - p * t * __expf(-z * z);
    const float erfv = (v < 0.f) ? -e : e;
    return v * (0.5f + 0.5f * erfv);
}

// ---------------- gating (+ fused x->bf16 convert) --------------------------
__global__ __launch_bounds__(256) void gate_kernel(
    const float* __restrict__ x, const float* __restrict__ gw,
    const float* __restrict__ gb, int* __restrict__ counts,
    int* __restrict__ tok_list, float* __restrict__ prob_list,
    unsigned short* __restrict__ xb)
{
    const int wave = threadIdx.x >> 6, lane = threadIdx.x & 63;
    const int t = blockIdx.x * 4 + wave;
    double s[E_NUM];
#pragma unroll
    for (int j = 0; j < E_NUM; ++j) s[j] = 0.0;
    const float* xr = x + (size_t)t * D_DIM;
    unsigned short* xbr = xb + (size_t)t * D_DIM;
#pragma unroll
    for (int i = 0; i < D_DIM / 64; ++i) {
        const int d = i * 64 + lane;
        const float xv = xr[d];
        xbr[d] = f2bf(xv);
        const float4 g0 = *(const float4*)(gw + d * 8);
        const float4 g1 = *(const float4*)(gw + d * 8 + 4);
        s[0] += (double)xv * g0.x; s[1] += (double)xv * g0.y;
        s[2] += (double)xv * g0.z; s[3] += (double)xv * g0.w;
        s[4] += (double)xv * g1.x; s[5] += (double)xv * g1.y;
        s[6] += (double)xv * g1.z; s[7] += (double)xv * g1.w;
    }
#pragma unroll
    for (int off = 32; off >= 1; off >>= 1)
#pragma unroll
        for (int j = 0; j < E_NUM; ++j) s[j] += __shfl_xor(s[j], off, 64);

    if (lane == 0) {
#pragma unroll
        for (int j = 0; j < E_NUM; ++j) s[j] += (double)gb[j];
        int i0 = 0;
        for (int j = 1; j < E_NUM; ++j) if (s[j] > s[i0]) i0 = j;
        int i1 = (i0 == 0) ? 1 : 0;
        for (int j = 0; j < E_NUM; ++j) if (j != i0 && s[j] > s[i1]) i1 = j;
        const double e1 = exp(s[i1] - s[i0]);
        const float p0 = (float)(1.0 / (1.0 + e1));
        const float p1 = (float)(e1 / (1.0 + e1));
        int pos0 = atomicAdd(&counts[i0], 1);
        tok_list[i0 * CAP_E + pos0]  = t;
        prob_list[i0 * CAP_E + pos0] = p0;
        int pos1 = atomicAdd(&counts[i1], 1);
        tok_list[i1 * CAP_E + pos1]  = t;
        prob_list[i1 * CAP_E + pos1] = p1;
    }
}

__global__ void offsets_kernel(const int* __restrict__ counts, int* __restrict__ offsets) {
    if (threadIdx.x == 0) {
        int acc = 0;
        for (int e = 0; e < E_NUM; ++e) { offsets[e] = acc; acc += counts[e]; }
    }
}

// ---------------- weight transpose+convert: in [R][C] fp32 -> out [C][R] bf16
__global__ __launch_bounds__(256) void wtrans_kernel(
    const float* __restrict__ in, unsigned short* __restrict__ out, int R, int C)
{
    __shared__ unsigned tile[64][33];
    const size_t slab = (size_t)blockIdx.z * (size_t)R * C;
    const float* inp = in + slab;
    unsigned short* outp = out + slab;
    const int c0 = blockIdx.x * 64, r0 = blockIdx.y * 64;
    const int tid = threadIdx.x;
    const int cq = tid & 15, p0 = tid >> 4;
#pragma unroll
    for (int s = 0; s < 2; ++s) {
        const int p = p0 + s * 16;
        const int r = r0 + 2 * p;
        const int c = c0 + cq * 4;
        const float4 va = *(const float4*)(inp + (size_t)r * C + c);
        const float4 vb = *(const float4*)(inp + (size_t)(r + 1) * C + c);
        const float* fa = (const float*)&va;
        const float* fb = (const float*)&vb;
#pragma unroll
        for (int i = 0; i < 4; ++i)
            tile[cq * 4 + i][p] = (unsigned)f2bf(fa[i]) | ((unsigned)f2bf(fb[i]) << 16);
    }
    __syncthreads();
    const int cl = tid >> 2, q = tid & 3;
#pragma unroll
    for (int s = 0; s < 2; ++s) {
        const int qq = q + s * 4;
        uint4 wv;
        wv.x = tile[cl][qq * 4 + 0]; wv.y = tile[cl][qq * 4 + 1];
        wv.z = tile[cl][qq * 4 + 2]; wv.w = tile[cl][qq * 4 + 3];
        *(uint4*)(outp + (size_t)(c0 + cl) * R + r0 + qq * 8) = wv;
    }
}

// ---------------- FC1: 128x128 tile, 32KB, e->XCD pinned, LDS-bounce epi ----
__global__ __launch_bounds__(256) void expert_fc1(
    const unsigned short* __restrict__ xb, const unsigned short* __restrict__ w1t,
    const float* __restrict__ b1, const int* __restrict__ counts,
    const int* __restrict__ offsets, const int* __restrict__ tok_list,
    unsigned short* __restrict__ h_ws,
    int e_param, int we_param, int row_start, int cap, int packed)
{
    __shared__ __align__(16) unsigned short smem[2 * BM * BK];   // 32 KB
    unsigned short* As = smem;
    unsigned short* Bs = smem + BM * BK;

    int e, bx, by;
    if (e_param >= 0) { e = e_param; bx = (int)blockIdx.x & 31; by = (int)blockIdx.x >> 5; }
    else { e = (int)blockIdx.x & 7; const int r = (int)blockIdx.x >> 3; bx = r & 31; by = r >> 5; }

    const int we = (we_param >= 0) ? we_param : e;
    const int cnt = counts[e];
    const int row_end = min(cnt, row_start + cap);
    const int row0 = row_start + by * BM;
    if (row0 >= row_end) return;
    const int n0 = bx * BN;
    const int hb = packed ? offsets[e] : 0;
    const int tid = threadIdx.x;

    const int wv = tid >> 6, lane = tid & 63;
    const int schunk = (lane & 7) ^ (lane >> 3);
    const unsigned short* __restrict__ w1e = w1t + (size_t)we * H_DIM * D_DIM;

    const unsigned short* aptr[4];
    const unsigned short* bptr[4];
#pragma unroll
    for (int j = 0; j < 4; ++j) {
        const int r = (wv * 4 + j) * 8 + (lane >> 3);
        const int rr = min(row0 + r, row_end - 1);
        aptr[j] = xb + (size_t)tok_list[e * CAP_E + rr] * D_DIM + schunk * 8;
        bptr[j] = w1e + (size_t)(n0 + r) * D_DIM + schunk * 8;
    }

    const int wr = (wv >> 1) * 64, wc = (wv & 1) * 64;
    const int rl = lane & 15, x7 = lane & 7, kg = lane >> 4;
    int aoff[2][4], boff[2][4];
#pragma unroll
    for (int s = 0; s < 2; ++s) {
        const int slot = ((((s << 2) + kg) ^ x7) << 3);
#pragma unroll
        for (int m = 0; m < 4; ++m) aoff[s][m] = ((wr + m * 16 + rl) << 6) + slot;
#pragma unroll
        for (int n = 0; n < 4; ++n) boff[s][n] = ((wc + n * 16 + rl) << 6) + slot;
    }

    f32x4 acc[4][4];
#pragma unroll
    for (int m = 0; m < 4; ++m)
#pragma unroll
        for (int n = 0; n < 4; ++n) acc[m][n] = (f32x4){0.f, 0.f, 0.f, 0.f};

    for (int kk = 0; kk < D_DIM; kk += BK) {
        __syncthreads();
#pragma unroll
        for (int j = 0; j < 4; ++j) {
            gload16(aptr[j] + kk, &As[(wv * 4 + j) * 512]);
            gload16(bptr[j] + kk, &Bs[(wv * 4 + j) * 512]);
        }
        __syncthreads();
#pragma unroll
        for (int s = 0; s < 2; ++s) {
            bf16x8 af[4], bfv[4];
#pragma unroll
            for (int m = 0; m < 4; ++m) af[m] = *(const bf16x8*)&As[aoff[s][m]];
#pragma unroll
            for (int n = 0; n < 4; ++n) bfv[n] = *(const bf16x8*)&Bs[boff[s][n]];
#pragma unroll
            for (int m = 0; m < 4; ++m)
#pragma unroll
                for (int n = 0; n < 4; ++n)
                    acc[m][n] = __builtin_amdgcn_mfma_f32_16x16x32_bf16(af[m], bfv[n], acc[m][n], 0, 0, 0);
        }
    }

    // epilogue: GELU + bias, LDS-bounce to coalesced 16B stores
    const float* __restrict__ b1e = b1 + e * H_DIM;
    const int crb = (lane >> 4) * 4, ccol = lane & 15;
    float bias[4];
#pragma unroll
    for (int n = 0; n < 4; ++n) bias[n] = b1e[n0 + wc + n * 16 + ccol];

    __syncthreads();
    const int mychunk = wr >> 6;
#pragma unroll
    for (int c = 0; c < 2; ++c) {
        if (mychunk == c) {
#pragma unroll
            for (int n = 0; n < 4; ++n)
#pragma unroll
                for (int m = 0; m < 4; ++m)
#pragma unroll
                    for (int j = 0; j < 4; ++j) {
                        const int rloc = m * 16 + crb + j;
                        const int col = wc + n * 16 + ccol;
                        smem[rloc * 132 + col] = f2bf(gelu_f(acc[m][n][j] + bias[n]));
                    }
        }
        __syncthreads();
#pragma unroll
        for (int i = 0; i < 4; ++i) {
            const int idx = tid + i * 256;
            const int row = idx >> 4, c8 = idx & 15;
            const uint4 val = *(const uint4*)&smem[row * 132 + c8 * 8];
            const int gr = row0 + c * 64 + row;
            if (gr < row_end)
                *(uint4*)&h_ws[(size_t)(hb + gr - row_start) * H_DIM + n0 + c8 * 8] = val;
        }
        __syncthreads();
    }
}

// ---------------- FC2: 128x128, 32KB, split-K=2, atomic combine -------------
// full decode: bx = bid&7 (column-stripe -> XCD); r=bid>>3: by=r&31, ks=r>>5;
// e = bid>>9.  All experts spread across all XCDs (balance > locality here).
__global__ __launch_bounds__(256) void expert_fc2(
    const unsigned short* __restrict__ h_ws, const unsigned short* __restrict__ w2t,
    const float* __restrict__ b2, const int* __restrict__ counts,
    const int* __restrict__ offsets, const int* __restrict__ tok_list,
    const float* __restrict__ prob_list, float* __restrict__ out,
    int splitk, int e_param, int we_param, int row_start, int cap, int packed)
{
    __shared__ __align__(16) unsigned short As[BM * BK];   // 16 KB
    __shared__ __align__(16) unsigned short Bs[BM * BK];   // 16 KB

    int e, bx, by, ks;
    if (e_param >= 0) { e = e_param; bx = (int)blockIdx.x & 7; by = (int)blockIdx.x >> 3; ks = 0; }
    else { e = (int)blockIdx.x >> 9; const int r = ((int)blockIdx.x >> 3) & 63;
           bx = (int)blockIdx.x & 7; by = r & 31; ks = r >> 5; }

    const int we = (we_param >= 0) ? we_param : e;
    const int cnt = counts[e];
    const int row_end = min(cnt, row_start + cap);
    const int row0 = row_start + by * BM;
    if (row0 >= row_end) return;
    const int n0 = bx * BN;
    const int hb = packed ? offsets[e] : 0;
    const int tid = threadIdx.x;

    const int kspan = H_DIM / splitk;
    const int k0 = ks * kspan;

    const int wv = tid >> 6, lane = tid & 63;
    const int schunk = (lane & 7) ^ (lane >> 3);
    const unsigned short* __restrict__ w2e = w2t + (size_t)we * D_DIM * H_DIM;

    const unsigned short* aptr[4];
    const unsigned short* bptr[4];
#pragma unroll
    for (int j = 0; j < 4; ++j) {
        const int rloc = (wv * 4 + j) * 8 + (lane >> 3);
        int r = row0 + rloc; if (r >= row_end) r = row_end - 1;
        aptr[j] = h_ws + (size_t)(hb + r - row_start) * H_DIM + k0 + schunk * 8;
        bptr[j] = w2e + (size_t)(n0 + rloc) * H_DIM + k0 + schunk * 8;
    }

    const int wr = (wv >> 1) * 64, wc = (wv & 1) * 64;
    const int rl = lane & 15, x7 = lane & 7, kg = lane >> 4;
    int aoff[2][4], boff[2][4];
#pragma unroll
    for (int s = 0; s < 2; ++s) {
        const int slot = ((((s << 2) + kg) ^ x7) << 3);
#pragma unroll
        for (int m = 0; m < 4; ++m) aoff[s][m] = ((wr + m * 16 + rl) << 6) + slot;
#pragma unroll
        for (int n = 0; n < 4; ++n) boff[s][n] = ((wc + n * 16 + rl) << 6) + slot;
    }

    f32x4 acc[4][4];
#pragma unroll
    for (int m = 0; m < 4; ++m)
#pragma unroll
        for (int n = 0; n < 4; ++n) acc[m][n] = (f32x4){0.f, 0.f, 0.f, 0.f};

    for (int kk = 0; kk < kspan; kk += BK) {
        __syncthreads();
#pragma unroll
        for (int j = 0; j < 4; ++j) {
            gload16(aptr[j] + kk, &As[(wv * 4 + j) * 512]);
            gload16(bptr[j] + kk, &Bs[(wv * 4 + j) * 512]);
        }
        __syncthreads();
#pragma unroll
        for (int s = 0; s < 2; ++s) {
            bf16x8 af[4], bfv[4];
#pragma unroll
            for (int m = 0; m < 4; ++m) af[m] = *(const bf16x8*)&As[aoff[s][m]];
#pragma unroll
            for (int n = 0; n < 4; ++n) bfv[n] = *(const bf16x8*)&Bs[boff[s][n]];
#pragma unroll
            for (int m = 0; m < 4; ++m)
#pragma unroll
                for (int n = 0; n < 4; ++n)
                    acc[m][n] = __builtin_amdgcn_mfma_f32_16x16x32_bf16(af[m], bfv[n], acc[m][n], 0, 0, 0);
        }
    }

    const float* __restrict__ b2e = b2 + e * D_DIM;
    const int crb = (lane >> 4) * 4, ccol = lane & 15;
#pragma unroll
    for (int n = 0; n < 4; ++n) {
        const int gc = n0 + wc + n * 16 + ccol;
        const float bias = (ks == 0) ? b2e[gc] : 0.f;
#pragma unroll
        for (int m = 0; m < 4; ++m) {
#pragma unroll
            for (int j = 0; j < 4; ++j) {
                const int gr = row0 + wr + m * 16 + crb + j;
                if (gr < row_end) {
                    const float yv = acc[m][n][j] + bias;
                    const int t = tok_list[e * CAP_E + gr];
                    const float p = prob_list[e * CAP_E + gr];
                    atomicAdd(&out[(size_t)t * D_DIM + gc], p * yv);
                }
            }
        }
    }
}

extern "C" void kernel_launch(void* const* d_in, const int* in_sizes, int n_in,
                              void* d_out, int out_size, void* d_ws, size_t ws_size,
                              hipStream_t stream)
{
    const float* x  = (const float*)d_in[0];
    const float* w1 = (const float*)d_in[1];
    const float* b1 = (const float*)d_in[2];
    const float* w2 = (const float*)d_in[3];
    const float* b2 = (const float*)d_in[4];
    const float* gw = (const float*)d_in[5];
    const float* gb = (const float*)d_in[6];
    float* out = (float*)d_out;

    char* w = (char*)d_ws;
    int*   counts    = (int*)w;
    int*   offsets   = (int*)(w + 64);
    int*   tok_list  = (int*)(w + 128);
    float* prob_list = (float*)(w + 128 + (size_t)CAP_E * E_NUM * 4);
    size_t off = 128 + 2 * (size_t)CAP_E * E_NUM * 4;
    off = (off + 255) & ~(size_t)255;
    unsigned short* xb = (unsigned short*)(w + off);
    off += (size_t)NTOK * D_DIM * 2;

    const size_t wslab = (size_t)D_DIM * H_DIM * 2;       // bf16 per expert
    const size_t hfull = (size_t)2 * NTOK * H_DIM * 2;    // packed h, bf16
    const size_t need_full = off + 2 * E_NUM * wslab + hfull;

    hipMemsetAsync(d_out, 0, (size_t)out_size * sizeof(float), stream);
    hipMemsetAsync(counts, 0, 64, stream);

    gate_kernel<<<NTOK / 4, 256, 0, stream>>>(x, gw, gb, counts, tok_list, prob_list, xb);
    offsets_kernel<<<1, 64, 0, stream>>>(counts, offsets);

    if (ws_size >= need_full) {
        unsigned short* w1t = (unsigned short*)(w + off);
        unsigned short* w2t = (unsigned short*)(w + off + E_NUM * wslab);
        unsigned short* h_ws = (unsigned short*)(w + off + 2 * E_NUM * wslab);

        wtrans_kernel<<<dim3(H_DIM / 64, D_DIM / 64, E_NUM), 256, 0, stream>>>(w1, w1t, D_DIM, H_DIM);
        wtrans_kernel<<<dim3(D_DIM / 64, H_DIM / 64, E_NUM), 256, 0, stream>>>(w2, w2t, H_DIM, D_DIM);

        // fc1: 8 e * 32 bx * 32 by (e -> XCD pinned; empties early-exit)
        expert_fc1<<<8 * 32 * 32, 256, 0, stream>>>(
            xb, w1t, b1, counts, offsets, tok_list, h_ws, -1, -1, 0, NTOK, 1);
        // fc2: 8 bx * 32 by * 2 ks * 8 e = 4096 blocks (column-stripe -> XCD)
        expert_fc2<<<8 * 32 * 2 * 8, 256, 0, stream>>>(
            h_ws, w2t, b2, counts, offsets, tok_list, prob_list, out,
            2, -1, -1, 0, NTOK, 1);
    } else {
        // per-expert chunked fallback (atomics)
        unsigned short* w1te = (unsigned short*)(w + off);
        unsigned short* w2te = (unsigned short*)(w + off + wslab);
        size_t h_off = off + 2 * wslab;
        unsigned short* h_e = (unsigned short*)(w + h_off);
        size_t h_avail = (ws_size > h_off) ? (ws_size - h_off) / ((size_t)H_DIM * 2) : 0;
        int cap = (int)((h_avail < (size_t)NTOK) ? h_avail : (size_t)NTOK);
        cap = (cap / BM) * BM;
        if (cap < BM) cap = BM;
        const int chunks = (NTOK + cap - 1) / cap;
        for (int e = 0; e < E_NUM; ++e) {
            wtrans_kernel<<<dim3(H_DIM / 64, D_DIM / 64, 1), 256, 0, stream>>>(
                w1 + (size_t)e * D_DIM * H_DIM, w1te, D_DIM, H_DIM);
            wtrans_kernel<<<dim3(D_DIM / 64, H_DIM / 64, 1), 256, 0, stream>>>(
                w2 + (size_t)e * H_DIM * D_DIM, w2te, H_DIM, D_DIM);
            for (int c = 0; c < chunks; ++c) {
                const int rs = c * cap;
                const int gy1 = (cap + BM - 1) / BM;
                expert_fc1<<<32 * gy1, 256, 0, stream>>>(
                    xb, w1te, b1, counts, offsets, tok_list, h_e,
                    e, 0, rs, cap, 0);
                expert_fc2<<<8 * gy1, 256, 0, stream>>>(
                    h_e, w2te, b2, counts, offsets, tok_list, prob_list, out,
                    1, e, 0, rs, cap, 0);
            }
        }
    }
}

// Round 15
// 483.610 us; speedup vs baseline: 1.1574x; 1.0491x over previous
//
#include <hip/hip_runtime.h>
#include <hip/hip_bf16.h>
#include <stdint.h>

#define D_DIM 1024
#define H_DIM 4096
#define E_NUM 8
#define NTOK  4096   // B*S
#define CAP_E 4096
#define BM 128
#define BN 128
#define BK 64        // bf16 elems per K-tile; LDS row = 128 B = 8 chunks of 16 B

typedef __bf16 bf16x8 __attribute__((ext_vector_type(8)));
typedef float  f32x4  __attribute__((ext_vector_type(4)));

static __device__ __forceinline__ unsigned short f2bf(float f) {
    union { float f; unsigned u; } v; v.f = f;
    unsigned r = v.u + 0x7fffu + ((v.u >> 16) & 1u);   // RNE
    return (unsigned short)(r >> 16);
}

static __device__ __forceinline__ void gload16(const unsigned short* g, unsigned short* l) {
    __builtin_amdgcn_global_load_lds(
        (const __attribute__((address_space(1))) unsigned int*)g,
        (__attribute__((address_space(3))) unsigned int*)l,
        16, 0, 0);
}

// exact-erf GELU via Abramowitz-Stegun 7.1.26 (|err| <= 1.5e-7)
static __device__ __forceinline__ float gelu_f(float v) {
    const float z = fabsf(v) * 0.70710678118654752f;
    const float t = __builtin_amdgcn_rcpf(__builtin_fmaf(0.3275911f, z, 1.f));
    float p = __builtin_fmaf(1.061405429f, t, -1.453152027f);
    p = __builtin_fmaf(p, t, 1.421413741f);
    p = __builtin_fmaf(p, t, -0.284496736f);
    p = __builtin_fmaf(p, t, 0.254829592f);
    const float e = 1.f - p * t * __expf(-z * z);
    const float erfv = (v < 0.f) ? -e : e;
    return v * (0.5f + 0.5f * erfv);
}

// ---------------- gating (+ fused x->bf16 convert) --------------------------
__global__ __launch_bounds__(256) void gate_kernel(
    const float* __restrict__ x, const float* __restrict__ gw,
    const float* __restrict__ gb, int* __restrict__ counts,
    int* __restrict__ tok_list, float* __restrict__ prob_list,
    unsigned short* __restrict__ xb)
{
    const int wave = threadIdx.x >> 6, lane = threadIdx.x & 63;
    const int t = blockIdx.x * 4 + wave;
    double s[E_NUM];
#pragma unroll
    for (int j = 0; j < E_NUM; ++j) s[j] = 0.0;
    const float* xr = x + (size_t)t * D_DIM;
    unsigned short* xbr = xb + (size_t)t * D_DIM;
#pragma unroll
    for (int i = 0; i < D_DIM / 64; ++i) {
        const int d = i * 64 + lane;
        const float xv = xr[d];
        xbr[d] = f2bf(xv);
        const float4 g0 = *(const float4*)(gw + d * 8);
        const float4 g1 = *(const float4*)(gw + d * 8 + 4);
        s[0] += (double)xv * g0.x; s[1] += (double)xv * g0.y;
        s[2] += (double)xv * g0.z; s[3] += (double)xv * g0.w;
        s[4] += (double)xv * g1.x; s[5] += (double)xv * g1.y;
        s[6] += (double)xv * g1.z; s[7] += (double)xv * g1.w;
    }
#pragma unroll
    for (int off = 32; off >= 1; off >>= 1)
#pragma unroll
        for (int j = 0; j < E_NUM; ++j) s[j] += __shfl_xor(s[j], off, 64);

    if (lane == 0) {
#pragma unroll
        for (int j = 0; j < E_NUM; ++j) s[j] += (double)gb[j];
        int i0 = 0;
        for (int j = 1; j < E_NUM; ++j) if (s[j] > s[i0]) i0 = j;
        int i1 = (i0 == 0) ? 1 : 0;
        for (int j = 0; j < E_NUM; ++j) if (j != i0 && s[j] > s[i1]) i1 = j;
        const double e1 = exp(s[i1] - s[i0]);
        const float p0 = (float)(1.0 / (1.0 + e1));
        const float p1 = (float)(e1 / (1.0 + e1));
        int pos0 = atomicAdd(&counts[i0], 1);
        tok_list[i0 * CAP_E + pos0]  = t;
        prob_list[i0 * CAP_E + pos0] = p0;
        int pos1 = atomicAdd(&counts[i1], 1);
        tok_list[i1 * CAP_E + pos1]  = t;
        prob_list[i1 * CAP_E + pos1] = p1;
    }
}

__global__ void offsets_kernel(const int* __restrict__ counts, int* __restrict__ offsets) {
    if (threadIdx.x == 0) {
        int acc = 0;
        for (int e = 0; e < E_NUM; ++e) { offsets[e] = acc; acc += counts[e]; }
    }
}

// ---------------- weight transpose+convert: in [R][C] fp32 -> out [C][R] bf16
__global__ __launch_bounds__(256) void wtrans_kernel(
    const float* __restrict__ in, unsigned short* __restrict__ out, int R, int C)
{
    __shared__ unsigned tile[64][33];
    const size_t slab = (size_t)blockIdx.z * (size_t)R * C;
    const float* inp = in + slab;
    unsigned short* outp = out + slab;
    const int c0 = blockIdx.x * 64, r0 = blockIdx.y * 64;
    const int tid = threadIdx.x;
    const int cq = tid & 15, p0 = tid >> 4;
#pragma unroll
    for (int s = 0; s < 2; ++s) {
        const int p = p0 + s * 16;
        const int r = r0 + 2 * p;
        const int c = c0 + cq * 4;
        const float4 va = *(const float4*)(inp + (size_t)r * C + c);
        const float4 vb = *(const float4*)(inp + (size_t)(r + 1) * C + c);
        const float* fa = (const float*)&va;
        const float* fb = (const float*)&vb;
#pragma unroll
        for (int i = 0; i < 4; ++i)
            tile[cq * 4 + i][p] = (unsigned)f2bf(fa[i]) | ((unsigned)f2bf(fb[i]) << 16);
    }
    __syncthreads();
    const int cl = tid >> 2, q = tid & 3;
#pragma unroll
    for (int s = 0; s < 2; ++s) {
        const int qq = q + s * 4;
        uint4 wv;
        wv.x = tile[cl][qq * 4 + 0]; wv.y = tile[cl][qq * 4 + 1];
        wv.z = tile[cl][qq * 4 + 2]; wv.w = tile[cl][qq * 4 + 3];
        *(uint4*)(outp + (size_t)(c0 + cl) * R + r0 + qq * 8) = wv;
    }
}

// ---------------- FC1: 128x128 tile, 32KB, e->XCD pinned, LDS-bounce epi ----
__global__ __launch_bounds__(256) void expert_fc1(
    const unsigned short* __restrict__ xb, const unsigned short* __restrict__ w1t,
    const float* __restrict__ b1, const int* __restrict__ counts,
    const int* __restrict__ offsets, const int* __restrict__ tok_list,
    unsigned short* __restrict__ h_ws,
    int e_param, int we_param, int row_start, int cap, int packed)
{
    __shared__ __align__(16) unsigned short smem[2 * BM * BK];   // 32 KB
    unsigned short* As = smem;
    unsigned short* Bs = smem + BM * BK;

    int e, bx, by;
    if (e_param >= 0) { e = e_param; bx = (int)blockIdx.x & 31; by = (int)blockIdx.x >> 5; }
    else { e = (int)blockIdx.x & 7; const int r = (int)blockIdx.x >> 3; bx = r & 31; by = r >> 5; }

    const int we = (we_param >= 0) ? we_param : e;
    const int cnt = counts[e];
    const int row_end = min(cnt, row_start + cap);
    const int row0 = row_start + by * BM;
    if (row0 >= row_end) return;
    const int n0 = bx * BN;
    const int hb = packed ? offsets[e] : 0;
    const int tid = threadIdx.x;

    const int wv = tid >> 6, lane = tid & 63;
    const int schunk = (lane & 7) ^ (lane >> 3);
    const unsigned short* __restrict__ w1e = w1t + (size_t)we * H_DIM * D_DIM;

    const unsigned short* aptr[4];
    const unsigned short* bptr[4];
#pragma unroll
    for (int j = 0; j < 4; ++j) {
        const int r = (wv * 4 + j) * 8 + (lane >> 3);
        const int rr = min(row0 + r, row_end - 1);
        aptr[j] = xb + (size_t)tok_list[e * CAP_E + rr] * D_DIM + schunk * 8;
        bptr[j] = w1e + (size_t)(n0 + r) * D_DIM + schunk * 8;
    }

    const int wr = (wv >> 1) * 64, wc = (wv & 1) * 64;
    const int rl = lane & 15, x7 = lane & 7, kg = lane >> 4;
    int aoff[2][4], boff[2][4];
#pragma unroll
    for (int s = 0; s < 2; ++s) {
        const int slot = ((((s << 2) + kg) ^ x7) << 3);
#pragma unroll
        for (int m = 0; m < 4; ++m) aoff[s][m] = ((wr + m * 16 + rl) << 6) + slot;
#pragma unroll
        for (int n = 0; n < 4; ++n) boff[s][n] = ((wc + n * 16 + rl) << 6) + slot;
    }

    f32x4 acc[4][4];
#pragma unroll
    for (int m = 0; m < 4; ++m)
#pragma unroll
        for (int n = 0; n < 4; ++n) acc[m][n] = (f32x4){0.f, 0.f, 0.f, 0.f};

    for (int kk = 0; kk < D_DIM; kk += BK) {
        __syncthreads();
#pragma unroll
        for (int j = 0; j < 4; ++j) {
            gload16(aptr[j] + kk, &As[(wv * 4 + j) * 512]);
            gload16(bptr[j] + kk, &Bs[(wv * 4 + j) * 512]);
        }
        __syncthreads();
#pragma unroll
        for (int s = 0; s < 2; ++s) {
            bf16x8 af[4], bfv[4];
#pragma unroll
            for (int m = 0; m < 4; ++m) af[m] = *(const bf16x8*)&As[aoff[s][m]];
#pragma unroll
            for (int n = 0; n < 4; ++n) bfv[n] = *(const bf16x8*)&Bs[boff[s][n]];
#pragma unroll
            for (int m = 0; m < 4; ++m)
#pragma unroll
                for (int n = 0; n < 4; ++n)
                    acc[m][n] = __builtin_amdgcn_mfma_f32_16x16x32_bf16(af[m], bfv[n], acc[m][n], 0, 0, 0);
        }
    }

    // epilogue: GELU + bias, LDS-bounce to coalesced 16B stores
    const float* __restrict__ b1e = b1 + e * H_DIM;
    const int crb = (lane >> 4) * 4, ccol = lane & 15;
    float bias[4];
#pragma unroll
    for (int n = 0; n < 4; ++n) bias[n] = b1e[n0 + wc + n * 16 + ccol];

    __syncthreads();
    const int mychunk = wr >> 6;
#pragma unroll
    for (int c = 0; c < 2; ++c) {
        if (mychunk == c) {
#pragma unroll
            for (int n = 0; n < 4; ++n)
#pragma unroll
                for (int m = 0; m < 4; ++m)
#pragma unroll
                    for (int j = 0; j < 4; ++j) {
                        const int rloc = m * 16 + crb + j;
                        const int col = wc + n * 16 + ccol;
                        smem[rloc * 132 + col] = f2bf(gelu_f(acc[m][n][j] + bias[n]));
                    }
        }
        __syncthreads();
#pragma unroll
        for (int i = 0; i < 4; ++i) {
            const int idx = tid + i * 256;
            const int row = idx >> 4, c8 = idx & 15;
            const uint4 val = *(const uint4*)&smem[row * 132 + c8 * 8];
            const int gr = row0 + c * 64 + row;
            if (gr < row_end)
                *(uint4*)&h_ws[(size_t)(hb + gr - row_start) * H_DIM + n0 + c8 * 8] = val;
        }
        __syncthreads();
    }
}

// ---------------- FC2: 64x128 tile, 24KB, split-K=2, atomic combine ---------
// full decode: bx = bid&7 (column-stripe -> XCD); r=bid>>3: by=r&63; r>>=6:
// ks=r&1, e=r>>1.  BM=64 doubles active blocks (2048) vs 128-row tiles.
__global__ __launch_bounds__(256) void expert_fc2(
    const unsigned short* __restrict__ h_ws, const unsigned short* __restrict__ w2t,
    const float* __restrict__ b2, const int* __restrict__ counts,
    const int* __restrict__ offsets, const int* __restrict__ tok_list,
    const float* __restrict__ prob_list, float* __restrict__ out,
    int splitk, int e_param, int we_param, int row_start, int cap, int packed)
{
    __shared__ __align__(16) unsigned short As[64 * BK];    // 8 KB
    __shared__ __align__(16) unsigned short Bs[128 * BK];   // 16 KB

    int e, bx, by, ks;
    if (e_param >= 0) { e = e_param; bx = (int)blockIdx.x & 7; by = (int)blockIdx.x >> 3; ks = 0; }
    else { bx = (int)blockIdx.x & 7; int r = (int)blockIdx.x >> 3;
           by = r & 63; r >>= 6; ks = r & 1; e = r >> 1; }

    const int we = (we_param >= 0) ? we_param : e;
    const int cnt = counts[e];
    const int row_end = min(cnt, row_start + cap);
    const int row0 = row_start + by * 64;
    if (row0 >= row_end) return;
    const int n0 = bx * BN;
    const int hb = packed ? offsets[e] : 0;
    const int tid = threadIdx.x;

    const int kspan = H_DIM / splitk;
    const int k0 = ks * kspan;

    const int wv = tid >> 6, lane = tid & 63;
    const int schunk = (lane & 7) ^ (lane >> 3);
    const unsigned short* __restrict__ w2e = w2t + (size_t)we * D_DIM * H_DIM;

    // A: 64 rows -> 8 groups of 8; wave wv stages groups wv*2+j (j<2)
    const unsigned short* aptr[2];
#pragma unroll
    for (int j = 0; j < 2; ++j) {
        const int rloc = (wv * 2 + j) * 8 + (lane >> 3);   // 0..63
        int r = row0 + rloc; if (r >= row_end) r = row_end - 1;
        aptr[j] = h_ws + (size_t)(hb + r - row_start) * H_DIM + k0 + schunk * 8;
    }
    // B: 128 rows (D cols) -> 16 groups; wave wv stages groups wv*4+j (j<4)
    const unsigned short* bptr[4];
#pragma unroll
    for (int j = 0; j < 4; ++j) {
        const int rloc = (wv * 4 + j) * 8 + (lane >> 3);   // 0..127
        bptr[j] = w2e + (size_t)(n0 + rloc) * H_DIM + k0 + schunk * 8;
    }

    // wave layout: 1 x 4 (all waves share the 64 A-rows; wave covers 32 cols)
    const int wc = wv * 32;
    const int rl = lane & 15, x7 = lane & 7, kg = lane >> 4;
    int aoff[2][4], boff[2][2];
#pragma unroll
    for (int s = 0; s < 2; ++s) {
        const int slot = ((((s << 2) + kg) ^ x7) << 3);
#pragma unroll
        for (int m = 0; m < 4; ++m) aoff[s][m] = ((m * 16 + rl) << 6) + slot;
#pragma unroll
        for (int n = 0; n < 2; ++n) boff[s][n] = ((wc + n * 16 + rl) << 6) + slot;
    }

    f32x4 acc[4][2];
#pragma unroll
    for (int m = 0; m < 4; ++m)
#pragma unroll
        for (int n = 0; n < 2; ++n) acc[m][n] = (f32x4){0.f, 0.f, 0.f, 0.f};

    for (int kk = 0; kk < kspan; kk += BK) {
        __syncthreads();
#pragma unroll
        for (int j = 0; j < 2; ++j)
            gload16(aptr[j] + kk, &As[(wv * 2 + j) * 512]);
#pragma unroll
        for (int j = 0; j < 4; ++j)
            gload16(bptr[j] + kk, &Bs[(wv * 4 + j) * 512]);
        __syncthreads();
#pragma unroll
        for (int s = 0; s < 2; ++s) {
            bf16x8 af[4], bfv[2];
#pragma unroll
            for (int m = 0; m < 4; ++m) af[m] = *(const bf16x8*)&As[aoff[s][m]];
#pragma unroll
            for (int n = 0; n < 2; ++n) bfv[n] = *(const bf16x8*)&Bs[boff[s][n]];
#pragma unroll
            for (int m = 0; m < 4; ++m)
#pragma unroll
                for (int n = 0; n < 2; ++n)
                    acc[m][n] = __builtin_amdgcn_mfma_f32_16x16x32_bf16(af[m], bfv[n], acc[m][n], 0, 0, 0);
        }
    }

    const float* __restrict__ b2e = b2 + e * D_DIM;
    const int crb = (lane >> 4) * 4, ccol = lane & 15;
#pragma unroll
    for (int n = 0; n < 2; ++n) {
        const int gc = n0 + wc + n * 16 + ccol;
        const float bias = (ks == 0) ? b2e[gc] : 0.f;
#pragma unroll
        for (int m = 0; m < 4; ++m) {
#pragma unroll
            for (int j = 0; j < 4; ++j) {
                const int gr = row0 + m * 16 + crb + j;
                if (gr < row_end) {
                    const float yv = acc[m][n][j] + bias;
                    const int t = tok_list[e * CAP_E + gr];
                    const float p = prob_list[e * CAP_E + gr];
                    atomicAdd(&out[(size_t)t * D_DIM + gc], p * yv);
                }
            }
        }
    }
}

extern "C" void kernel_launch(void* const* d_in, const int* in_sizes, int n_in,
                              void* d_out, int out_size, void* d_ws, size_t ws_size,
                              hipStream_t stream)
{
    const float* x  = (const float*)d_in[0];
    const float* w1 = (const float*)d_in[1];
    const float* b1 = (const float*)d_in[2];
    const float* w2 = (const float*)d_in[3];
    const float* b2 = (const float*)d_in[4];
    const float* gw = (const float*)d_in[5];
    const float* gb = (const float*)d_in[6];
    float* out = (float*)d_out;

    char* w = (char*)d_ws;
    int*   counts    = (int*)w;
    int*   offsets   = (int*)(w + 64);
    int*   tok_list  = (int*)(w + 128);
    float* prob_list = (float*)(w + 128 + (size_t)CAP_E * E_NUM * 4);
    size_t off = 128 + 2 * (size_t)CAP_E * E_NUM * 4;
    off = (off + 255) & ~(size_t)255;
    unsigned short* xb = (unsigned short*)(w + off);
    off += (size_t)NTOK * D_DIM * 2;

    const size_t wslab = (size_t)D_DIM * H_DIM * 2;       // bf16 per expert
    const size_t hfull = (size_t)2 * NTOK * H_DIM * 2;    // packed h, bf16
    const size_t need_full = off + 2 * E_NUM * wslab + hfull;

    hipMemsetAsync(d_out, 0, (size_t)out_size * sizeof(float), stream);
    hipMemsetAsync(counts, 0, 64, stream);

    gate_kernel<<<NTOK / 4, 256, 0, stream>>>(x, gw, gb, counts, tok_list, prob_list, xb);
    offsets_kernel<<<1, 64, 0, stream>>>(counts, offsets);

    if (ws_size >= need_full) {
        unsigned short* w1t = (unsigned short*)(w + off);
        unsigned short* w2t = (unsigned short*)(w + off + E_NUM * wslab);
        unsigned short* h_ws = (unsigned short*)(w + off + 2 * E_NUM * wslab);

        wtrans_kernel<<<dim3(H_DIM / 64, D_DIM / 64, E_NUM), 256, 0, stream>>>(w1, w1t, D_DIM, H_DIM);
        wtrans_kernel<<<dim3(D_DIM / 64, H_DIM / 64, E_NUM), 256, 0, stream>>>(w2, w2t, H_DIM, D_DIM);

        // fc1: 8 e * 32 bx * 32 by (e -> XCD pinned; empties early-exit)
        expert_fc1<<<8 * 32 * 32, 256, 0, stream>>>(
            xb, w1t, b1, counts, offsets, tok_list, h_ws, -1, -1, 0, NTOK, 1);
        // fc2: 8 bx * 64 by * 2 ks * 8 e = 8192 blocks (64-row tiles; ~2048 active)
        expert_fc2<<<8 * 64 * 2 * 8, 256, 0, stream>>>(
            h_ws, w2t, b2, counts, offsets, tok_list, prob_list, out,
            2, -1, -1, 0, NTOK, 1);
    } else {
        // per-expert chunked fallback (atomics)
        unsigned short* w1te = (unsigned short*)(w + off);
        unsigned short* w2te = (unsigned short*)(w + off + wslab);
        size_t h_off = off + 2 * wslab;
        unsigned short* h_e = (unsigned short*)(w + h_off);
        size_t h_avail = (ws_size > h_off) ? (ws_size - h_off) / ((size_t)H_DIM * 2) : 0;
        int cap = (int)((h_avail < (size_t)NTOK) ? h_avail : (size_t)NTOK);
        cap = (cap / BM) * BM;
        if (cap < BM) cap = BM;
        const int chunks = (NTOK + cap - 1) / cap;
        for (int e = 0; e < E_NUM; ++e) {
            wtrans_kernel<<<dim3(H_DIM / 64, D_DIM / 64, 1), 256, 0, stream>>>(
                w1 + (size_t)e * D_DIM * H_DIM, w1te, D_DIM, H_DIM);
            wtrans_kernel<<<dim3(D_DIM / 64, H_DIM / 64, 1), 256, 0, stream>>>(
                w2 + (size_t)e * H_DIM * D_DIM, w2te, H_DIM, D_DIM);
            for (int c = 0; c < chunks; ++c) {
                const int rs = c * cap;
                expert_fc1<<<32 * ((cap + BM - 1) / BM), 256, 0, stream>>>(
                    xb, w1te, b1, counts, offsets, tok_list, h_e,
                    e, 0, rs, cap, 0);
                expert_fc2<<<8 * ((cap + 63) / 64), 256, 0, stream>>>(
                    h_e, w2te, b2, counts, offsets, tok_list, prob_list, out,
                    1, e, 0, rs, cap, 0);
            }
        }
    }
}

// Round 16
// 469.888 us; speedup vs baseline: 1.1912x; 1.0292x over previous
//
#include <hip/hip_runtime.h>
#include <hip/hip_bf16.h>
#include <stdint.h>

#define D_DIM 1024
#define H_DIM 4096
#define E_NUM 8
#define NTOK  4096   // B*S
#define CAP_E 4096
#define BM 128
#define BN 128
#define BK 64        // bf16 elems per K-tile; LDS row = 128 B = 8 chunks of 16 B

typedef __bf16 bf16x8 __attribute__((ext_vector_type(8)));
typedef float  f32x4  __attribute__((ext_vector_type(4)));

static __device__ __forceinline__ unsigned short f2bf(float f) {
    union { float f; unsigned u; } v; v.f = f;
    unsigned r = v.u + 0x7fffu + ((v.u >> 16) & 1u);   // RNE
    return (unsigned short)(r >> 16);
}

static __device__ __forceinline__ void gload16(const unsigned short* g, unsigned short* l) {
    __builtin_amdgcn_global_load_lds(
        (const __attribute__((address_space(1))) unsigned int*)g,
        (__attribute__((address_space(3))) unsigned int*)l,
        16, 0, 0);
}

// exact-erf GELU via Abramowitz-Stegun 7.1.26 (|err| <= 1.5e-7)
static __device__ __forceinline__ float gelu_f(float v) {
    const float z = fabsf(v) * 0.70710678118654752f;
    const float t = __builtin_amdgcn_rcpf(__builtin_fmaf(0.3275911f, z, 1.f));
    float p = __builtin_fmaf(1.061405429f, t, -1.453152027f);
    p = __builtin_fmaf(p, t, 1.421413741f);
    p = __builtin_fmaf(p, t, -0.284496736f);
    p = __builtin_fmaf(p, t, 0.254829592f);
    const float e = 1.f - p * t * __expf(-z * z);
    const float erfv = (v < 0.f) ? -e : e;
    return v * (0.5f + 0.5f * erfv);
}

// ---------------- gating (+ fused x->bf16 convert) --------------------------
__global__ __launch_bounds__(256) void gate_kernel(
    const float* __restrict__ x, const float* __restrict__ gw,
    const float* __restrict__ gb, int* __restrict__ counts,
    int* __restrict__ tok_list, float* __restrict__ prob_list,
    unsigned short* __restrict__ xb)
{
    const int wave = threadIdx.x >> 6, lane = threadIdx.x & 63;
    const int t = blockIdx.x * 4 + wave;
    double s[E_NUM];
#pragma unroll
    for (int j = 0; j < E_NUM; ++j) s[j] = 0.0;
    const float* xr = x + (size_t)t * D_DIM;
    unsigned short* xbr = xb + (size_t)t * D_DIM;
#pragma unroll
    for (int i = 0; i < D_DIM / 64; ++i) {
        const int d = i * 64 + lane;
        const float xv = xr[d];
        xbr[d] = f2bf(xv);
        const float4 g0 = *(const float4*)(gw + d * 8);
        const float4 g1 = *(const float4*)(gw + d * 8 + 4);
        s[0] += (double)xv * g0.x; s[1] += (double)xv * g0.y;
        s[2] += (double)xv * g0.z; s[3] += (double)xv * g0.w;
        s[4] += (double)xv * g1.x; s[5] += (double)xv * g1.y;
        s[6] += (double)xv * g1.z; s[7] += (double)xv * g1.w;
    }
#pragma unroll
    for (int off = 32; off >= 1; off >>= 1)
#pragma unroll
        for (int j = 0; j < E_NUM; ++j) s[j] += __shfl_xor(s[j], off, 64);

    if (lane == 0) {
#pragma unroll
        for (int j = 0; j < E_NUM; ++j) s[j] += (double)gb[j];
        int i0 = 0;
        for (int j = 1; j < E_NUM; ++j) if (s[j] > s[i0]) i0 = j;
        int i1 = (i0 == 0) ? 1 : 0;
        for (int j = 0; j < E_NUM; ++j) if (j != i0 && s[j] > s[i1]) i1 = j;
        const double e1 = exp(s[i1] - s[i0]);
        const float p0 = (float)(1.0 / (1.0 + e1));
        const float p1 = (float)(e1 / (1.0 + e1));
        int pos0 = atomicAdd(&counts[i0], 1);
        tok_list[i0 * CAP_E + pos0]  = t;
        prob_list[i0 * CAP_E + pos0] = p0;
        int pos1 = atomicAdd(&counts[i1], 1);
        tok_list[i1 * CAP_E + pos1]  = t;
        prob_list[i1 * CAP_E + pos1] = p1;
    }
}

__global__ void offsets_kernel(const int* __restrict__ counts, int* __restrict__ offsets) {
    if (threadIdx.x == 0) {
        int acc = 0;
        for (int e = 0; e < E_NUM; ++e) { offsets[e] = acc; acc += counts[e]; }
    }
}

// ---------------- weight transpose+convert: in [R][C] fp32 -> out [C][R] bf16
__global__ __launch_bounds__(256) void wtrans_kernel(
    const float* __restrict__ in, unsigned short* __restrict__ out, int R, int C)
{
    __shared__ unsigned tile[64][33];
    const size_t slab = (size_t)blockIdx.z * (size_t)R * C;
    const float* inp = in + slab;
    unsigned short* outp = out + slab;
    const int c0 = blockIdx.x * 64, r0 = blockIdx.y * 64;
    const int tid = threadIdx.x;
    const int cq = tid & 15, p0 = tid >> 4;
#pragma unroll
    for (int s = 0; s < 2; ++s) {
        const int p = p0 + s * 16;
        const int r = r0 + 2 * p;
        const int c = c0 + cq * 4;
        const float4 va = *(const float4*)(inp + (size_t)r * C + c);
        const float4 vb = *(const float4*)(inp + (size_t)(r + 1) * C + c);
        const float* fa = (const float*)&va;
        const float* fb = (const float*)&vb;
#pragma unroll
        for (int i = 0; i < 4; ++i)
            tile[cq * 4 + i][p] = (unsigned)f2bf(fa[i]) | ((unsigned)f2bf(fb[i]) << 16);
    }
    __syncthreads();
    const int cl = tid >> 2, q = tid & 3;
#pragma unroll
    for (int s = 0; s < 2; ++s) {
        const int qq = q + s * 4;
        uint4 wv;
        wv.x = tile[cl][qq * 4 + 0]; wv.y = tile[cl][qq * 4 + 1];
        wv.z = tile[cl][qq * 4 + 2]; wv.w = tile[cl][qq * 4 + 3];
        *(uint4*)(outp + (size_t)(c0 + cl) * R + r0 + qq * 8) = wv;
    }
}

// ---------------- FC1: 64x128 tile, 24KB, e->XCD pinned, LDS-bounce epi -----
// full decode: e = bid&7; r=bid>>3: bx=r&31 (H col tile), by=r>>5 (0..63).
__global__ __launch_bounds__(256) void expert_fc1(
    const unsigned short* __restrict__ xb, const unsigned short* __restrict__ w1t,
    const float* __restrict__ b1, const int* __restrict__ counts,
    const int* __restrict__ offsets, const int* __restrict__ tok_list,
    unsigned short* __restrict__ h_ws,
    int e_param, int we_param, int row_start, int cap, int packed)
{
    __shared__ __align__(16) unsigned short smem[12288];   // 24 KB
    unsigned short* As = smem;           // [64][64] bf16
    unsigned short* Bs = smem + 4096;    // [128][64] bf16

    int e, bx, by;
    if (e_param >= 0) { e = e_param; bx = (int)blockIdx.x & 31; by = (int)blockIdx.x >> 5; }
    else { e = (int)blockIdx.x & 7; const int r = (int)blockIdx.x >> 3; bx = r & 31; by = r >> 5; }

    const int we = (we_param >= 0) ? we_param : e;
    const int cnt = counts[e];
    const int row_end = min(cnt, row_start + cap);
    const int row0 = row_start + by * 64;
    if (row0 >= row_end) return;
    const int n0 = bx * BN;
    const int hb = packed ? offsets[e] : 0;
    const int tid = threadIdx.x;

    const int wv = tid >> 6, lane = tid & 63;
    const int schunk = (lane & 7) ^ (lane >> 3);
    const unsigned short* __restrict__ w1e = w1t + (size_t)we * H_DIM * D_DIM;

    // A: 64 token rows -> 8 groups of 8; wave wv stages groups wv*2+j (j<2)
    const unsigned short* aptr[2];
#pragma unroll
    for (int j = 0; j < 2; ++j) {
        const int rloc = (wv * 2 + j) * 8 + (lane >> 3);   // 0..63
        const int rr = min(row0 + rloc, row_end - 1);
        aptr[j] = xb + (size_t)tok_list[e * CAP_E + rr] * D_DIM + schunk * 8;
    }
    // B: 128 H-rows -> 16 groups; wave wv stages groups wv*4+j (j<4)
    const unsigned short* bptr[4];
#pragma unroll
    for (int j = 0; j < 4; ++j) {
        const int rloc = (wv * 4 + j) * 8 + (lane >> 3);   // 0..127
        bptr[j] = w1e + (size_t)(n0 + rloc) * D_DIM + schunk * 8;
    }

    // wave layout 1x4: all waves share 64 rows; wave covers 32 cols
    const int wc = wv * 32;
    const int rl = lane & 15, x7 = lane & 7, kg = lane >> 4;
    int aoff[2][4], boff[2][2];
#pragma unroll
    for (int s = 0; s < 2; ++s) {
        const int slot = ((((s << 2) + kg) ^ x7) << 3);
#pragma unroll
        for (int m = 0; m < 4; ++m) aoff[s][m] = ((m * 16 + rl) << 6) + slot;
#pragma unroll
        for (int n = 0; n < 2; ++n) boff[s][n] = ((wc + n * 16 + rl) << 6) + slot;
    }

    f32x4 acc[4][2];
#pragma unroll
    for (int m = 0; m < 4; ++m)
#pragma unroll
        for (int n = 0; n < 2; ++n) acc[m][n] = (f32x4){0.f, 0.f, 0.f, 0.f};

    for (int kk = 0; kk < D_DIM; kk += BK) {
        __syncthreads();
#pragma unroll
        for (int j = 0; j < 2; ++j)
            gload16(aptr[j] + kk, &As[(wv * 2 + j) * 512]);
#pragma unroll
        for (int j = 0; j < 4; ++j)
            gload16(bptr[j] + kk, &Bs[(wv * 4 + j) * 512]);
        __syncthreads();
#pragma unroll
        for (int s = 0; s < 2; ++s) {
            bf16x8 af[4], bfv[2];
#pragma unroll
            for (int m = 0; m < 4; ++m) af[m] = *(const bf16x8*)&As[aoff[s][m]];
#pragma unroll
            for (int n = 0; n < 2; ++n) bfv[n] = *(const bf16x8*)&Bs[boff[s][n]];
#pragma unroll
            for (int m = 0; m < 4; ++m)
#pragma unroll
                for (int n = 0; n < 2; ++n)
                    acc[m][n] = __builtin_amdgcn_mfma_f32_16x16x32_bf16(af[m], bfv[n], acc[m][n], 0, 0, 0);
        }
    }

    // epilogue: GELU + bias, LDS-bounce (64 rows x stride 132) -> 16B stores
    const float* __restrict__ b1e = b1 + e * H_DIM;
    const int crb = (lane >> 4) * 4, ccol = lane & 15;
    float bias[2];
#pragma unroll
    for (int n = 0; n < 2; ++n) bias[n] = b1e[n0 + wc + n * 16 + ccol];

    __syncthreads();   // all LDS frag reads done before reuse
#pragma unroll
    for (int n = 0; n < 2; ++n)
#pragma unroll
        for (int m = 0; m < 4; ++m)
#pragma unroll
            for (int j = 0; j < 4; ++j) {
                const int rloc = m * 16 + crb + j;
                const int col = wc + n * 16 + ccol;
                smem[rloc * 132 + col] = f2bf(gelu_f(acc[m][n][j] + bias[n]));
            }
    __syncthreads();
#pragma unroll
    for (int i = 0; i < 4; ++i) {
        const int idx = tid + i * 256;          // 0..1023
        const int row = idx >> 4, c8 = idx & 15;
        const uint4 val = *(const uint4*)&smem[row * 132 + c8 * 8];
        const int gr = row0 + row;
        if (gr < row_end)
            *(uint4*)&h_ws[(size_t)(hb + gr - row_start) * H_DIM + n0 + c8 * 8] = val;
    }
}

// ---------------- FC2: 64x128 tile, 24KB, split-K=2, atomic combine ---------
// full decode: bx = bid&7 (column-stripe -> XCD); r=bid>>3: by=r&63; r>>=6:
// ks=r&1, e=r>>1.  BM=64 doubles active blocks (2048) vs 128-row tiles.
__global__ __launch_bounds__(256) void expert_fc2(
    const unsigned short* __restrict__ h_ws, const unsigned short* __restrict__ w2t,
    const float* __restrict__ b2, const int* __restrict__ counts,
    const int* __restrict__ offsets, const int* __restrict__ tok_list,
    const float* __restrict__ prob_list, float* __restrict__ out,
    int splitk, int e_param, int we_param, int row_start, int cap, int packed)
{
    __shared__ __align__(16) unsigned short As[64 * BK];    // 8 KB
    __shared__ __align__(16) unsigned short Bs[128 * BK];   // 16 KB

    int e, bx, by, ks;
    if (e_param >= 0) { e = e_param; bx = (int)blockIdx.x & 7; by = (int)blockIdx.x >> 3; ks = 0; }
    else { bx = (int)blockIdx.x & 7; int r = (int)blockIdx.x >> 3;
           by = r & 63; r >>= 6; ks = r & 1; e = r >> 1; }

    const int we = (we_param >= 0) ? we_param : e;
    const int cnt = counts[e];
    const int row_end = min(cnt, row_start + cap);
    const int row0 = row_start + by * 64;
    if (row0 >= row_end) return;
    const int n0 = bx * BN;
    const int hb = packed ? offsets[e] : 0;
    const int tid = threadIdx.x;

    const int kspan = H_DIM / splitk;
    const int k0 = ks * kspan;

    const int wv = tid >> 6, lane = tid & 63;
    const int schunk = (lane & 7) ^ (lane >> 3);
    const unsigned short* __restrict__ w2e = w2t + (size_t)we * D_DIM * H_DIM;

    const unsigned short* aptr[2];
#pragma unroll
    for (int j = 0; j < 2; ++j) {
        const int rloc = (wv * 2 + j) * 8 + (lane >> 3);   // 0..63
        int r = row0 + rloc; if (r >= row_end) r = row_end - 1;
        aptr[j] = h_ws + (size_t)(hb + r - row_start) * H_DIM + k0 + schunk * 8;
    }
    const unsigned short* bptr[4];
#pragma unroll
    for (int j = 0; j < 4; ++j) {
        const int rloc = (wv * 4 + j) * 8 + (lane >> 3);   // 0..127
        bptr[j] = w2e + (size_t)(n0 + rloc) * H_DIM + k0 + schunk * 8;
    }

    const int wc = wv * 32;
    const int rl = lane & 15, x7 = lane & 7, kg = lane >> 4;
    int aoff[2][4], boff[2][2];
#pragma unroll
    for (int s = 0; s < 2; ++s) {
        const int slot = ((((s << 2) + kg) ^ x7) << 3);
#pragma unroll
        for (int m = 0; m < 4; ++m) aoff[s][m] = ((m * 16 + rl) << 6) + slot;
#pragma unroll
        for (int n = 0; n < 2; ++n) boff[s][n] = ((wc + n * 16 + rl) << 6) + slot;
    }

    f32x4 acc[4][2];
#pragma unroll
    for (int m = 0; m < 4; ++m)
#pragma unroll
        for (int n = 0; n < 2; ++n) acc[m][n] = (f32x4){0.f, 0.f, 0.f, 0.f};

    for (int kk = 0; kk < kspan; kk += BK) {
        __syncthreads();
#pragma unroll
        for (int j = 0; j < 2; ++j)
            gload16(aptr[j] + kk, &As[(wv * 2 + j) * 512]);
#pragma unroll
        for (int j = 0; j < 4; ++j)
            gload16(bptr[j] + kk, &Bs[(wv * 4 + j) * 512]);
        __syncthreads();
#pragma unroll
        for (int s = 0; s < 2; ++s) {
            bf16x8 af[4], bfv[2];
#pragma unroll
            for (int m = 0; m < 4; ++m) af[m] = *(const bf16x8*)&As[aoff[s][m]];
#pragma unroll
            for (int n = 0; n < 2; ++n) bfv[n] = *(const bf16x8*)&Bs[boff[s][n]];
#pragma unroll
            for (int m = 0; m < 4; ++m)
#pragma unroll
                for (int n = 0; n < 2; ++n)
                    acc[m][n] = __builtin_amdgcn_mfma_f32_16x16x32_bf16(af[m], bfv[n], acc[m][n], 0, 0, 0);
        }
    }

    const float* __restrict__ b2e = b2 + e * D_DIM;
    const int crb = (lane >> 4) * 4, ccol = lane & 15;
#pragma unroll
    for (int n = 0; n < 2; ++n) {
        const int gc = n0 + wc + n * 16 + ccol;
        const float bias = (ks == 0) ? b2e[gc] : 0.f;
#pragma unroll
        for (int m = 0; m < 4; ++m) {
#pragma unroll
            for (int j = 0; j < 4; ++j) {
                const int gr = row0 + m * 16 + crb + j;
                if (gr < row_end) {
                    const float yv = acc[m][n][j] + bias;
                    const int t = tok_list[e * CAP_E + gr];
                    const float p = prob_list[e * CAP_E + gr];
                    atomicAdd(&out[(size_t)t * D_DIM + gc], p * yv);
                }
            }
        }
    }
}

extern "C" void kernel_launch(void* const* d_in, const int* in_sizes, int n_in,
                              void* d_out, int out_size, void* d_ws, size_t ws_size,
                              hipStream_t stream)
{
    const float* x  = (const float*)d_in[0];
    const float* w1 = (const float*)d_in[1];
    const float* b1 = (const float*)d_in[2];
    const float* w2 = (const float*)d_in[3];
    const float* b2 = (const float*)d_in[4];
    const float* gw = (const float*)d_in[5];
    const float* gb = (const float*)d_in[6];
    float* out = (float*)d_out;

    char* w = (char*)d_ws;
    int*   counts    = (int*)w;
    int*   offsets   = (int*)(w + 64);
    int*   tok_list  = (int*)(w + 128);
    float* prob_list = (float*)(w + 128 + (size_t)CAP_E * E_NUM * 4);
    size_t off = 128 + 2 * (size_t)CAP_E * E_NUM * 4;
    off = (off + 255) & ~(size_t)255;
    unsigned short* xb = (unsigned short*)(w + off);
    off += (size_t)NTOK * D_DIM * 2;

    const size_t wslab = (size_t)D_DIM * H_DIM * 2;       // bf16 per expert
    const size_t hfull = (size_t)2 * NTOK * H_DIM * 2;    // packed h, bf16
    const size_t need_full = off + 2 * E_NUM * wslab + hfull;

    hipMemsetAsync(d_out, 0, (size_t)out_size * sizeof(float), stream);
    hipMemsetAsync(counts, 0, 64, stream);

    gate_kernel<<<NTOK / 4, 256, 0, stream>>>(x, gw, gb, counts, tok_list, prob_list, xb);
    offsets_kernel<<<1, 64, 0, stream>>>(counts, offsets);

    if (ws_size >= need_full) {
        unsigned short* w1t = (unsigned short*)(w + off);
        unsigned short* w2t = (unsigned short*)(w + off + E_NUM * wslab);
        unsigned short* h_ws = (unsigned short*)(w + off + 2 * E_NUM * wslab);

        wtrans_kernel<<<dim3(H_DIM / 64, D_DIM / 64, E_NUM), 256, 0, stream>>>(w1, w1t, D_DIM, H_DIM);
        wtrans_kernel<<<dim3(D_DIM / 64, H_DIM / 64, E_NUM), 256, 0, stream>>>(w2, w2t, H_DIM, D_DIM);

        // fc1: 8 e * 32 bx * 64 by (64-row tiles; e -> XCD pinned)
        expert_fc1<<<8 * 32 * 64, 256, 0, stream>>>(
            xb, w1t, b1, counts, offsets, tok_list, h_ws, -1, -1, 0, NTOK, 1);
        // fc2: 8 bx * 64 by * 2 ks * 8 e = 8192 blocks (64-row tiles)
        expert_fc2<<<8 * 64 * 2 * 8, 256, 0, stream>>>(
            h_ws, w2t, b2, counts, offsets, tok_list, prob_list, out,
            2, -1, -1, 0, NTOK, 1);
    } else {
        // per-expert chunked fallback (atomics)
        unsigned short* w1te = (unsigned short*)(w + off);
        unsigned short* w2te = (unsigned short*)(w + off + wslab);
        size_t h_off = off + 2 * wslab;
        unsigned short* h_e = (unsigned short*)(w + h_off);
        size_t h_avail = (ws_size > h_off) ? (ws_size - h_off) / ((size_t)H_DIM * 2) : 0;
        int cap = (int)((h_avail < (size_t)NTOK) ? h_avail : (size_t)NTOK);
        cap = (cap / BM) * BM;
        if (cap < BM) cap = BM;
        const int chunks = (NTOK + cap - 1) / cap;
        for (int e = 0; e < E_NUM; ++e) {
            wtrans_kernel<<<dim3(H_DIM / 64, D_DIM / 64, 1), 256, 0, stream>>>(
                w1 + (size_t)e * D_DIM * H_DIM, w1te, D_DIM, H_DIM);
            wtrans_kernel<<<dim3(D_DIM / 64, H_DIM / 64, 1), 256, 0, stream>>>(
                w2 + (size_t)e * H_DIM * D_DIM, w2te, H_DIM, D_DIM);
            for (int c = 0; c < chunks; ++c) {
                const int rs = c * cap;
                expert_fc1<<<32 * ((cap + 63) / 64), 256, 0, stream>>>(
                    xb, w1te, b1, counts, offsets, tok_list, h_e,
                    e, 0, rs, cap, 0);
                expert_fc2<<<8 * ((cap + 63) / 64), 256, 0, stream>>>(
                    h_e, w2te, b2, counts, offsets, tok_list, prob_list, out,
                    1, e, 0, rs, cap, 0);
            }
        }
    }
}

// Round 17
// 450.581 us; speedup vs baseline: 1.2422x; 1.0428x over previous
//
#include <hip/hip_runtime.h>
#include <hip/hip_bf16.h>
#include <stdint.h>

#define D_DIM 1024
#define H_DIM 4096
#define E_NUM 8
#define NTOK  4096   // B*S
#define CAP_E 4096
#define BM 128
#define BN 128
#define BK 64        // bf16 elems per K-tile; LDS row = 128 B = 8 chunks of 16 B

#define GATE_BLKS (NTOK / 4)          // 1024
#define W1T_BLKS  (64 * 16 * E_NUM)   // 8192  (H/64 x D/64 x E)
#define FC1_BLKS  (E_NUM * 32 * 64)   // 16384 (e x bx x by)
#define W2T_BLKS  (16 * 64 * E_NUM)   // 8192  (D/64 x H/64 x E)

typedef __bf16 bf16x8 __attribute__((ext_vector_type(8)));
typedef float  f32x4  __attribute__((ext_vector_type(4)));

static __device__ __forceinline__ unsigned short f2bf(float f) {
    union { float f; unsigned u; } v; v.f = f;
    unsigned r = v.u + 0x7fffu + ((v.u >> 16) & 1u);   // RNE
    return (unsigned short)(r >> 16);
}

static __device__ __forceinline__ void gload16(const unsigned short* g, unsigned short* l) {
    __builtin_amdgcn_global_load_lds(
        (const __attribute__((address_space(1))) unsigned int*)g,
        (__attribute__((address_space(3))) unsigned int*)l,
        16, 0, 0);
}

// exact-erf GELU via Abramowitz-Stegun 7.1.26 (|err| <= 1.5e-7)
static __device__ __forceinline__ float gelu_f(float v) {
    const float z = fabsf(v) * 0.70710678118654752f;
    const float t = __builtin_amdgcn_rcpf(__builtin_fmaf(0.3275911f, z, 1.f));
    float p = __builtin_fmaf(1.061405429f, t, -1.453152027f);
    p = __builtin_fmaf(p, t, 1.421413741f);
    p = __builtin_fmaf(p, t, -0.284496736f);
    p = __builtin_fmaf(p, t, 0.254829592f);
    const float e = 1.f - p * t * __expf(-z * z);
    const float erfv = (v < 0.f) ? -e : e;
    return v * (0.5f + 0.5f * erfv);
}

// ================= bodies (verified logic, dispatch-agnostic) ===============

static __device__ void gate_body(
    const float* __restrict__ x, const float* __restrict__ gw,
    const float* __restrict__ gb, int* __restrict__ counts,
    int* __restrict__ tok_list, float* __restrict__ prob_list,
    unsigned short* __restrict__ xb, int bid)
{
    const int wave = threadIdx.x >> 6, lane = threadIdx.x & 63;
    const int t = bid * 4 + wave;
    double s[E_NUM];
#pragma unroll
    for (int j = 0; j < E_NUM; ++j) s[j] = 0.0;
    const float* xr = x + (size_t)t * D_DIM;
    unsigned short* xbr = xb + (size_t)t * D_DIM;
#pragma unroll
    for (int i = 0; i < D_DIM / 64; ++i) {
        const int d = i * 64 + lane;
        const float xv = xr[d];
        xbr[d] = f2bf(xv);
        const float4 g0 = *(const float4*)(gw + d * 8);
        const float4 g1 = *(const float4*)(gw + d * 8 + 4);
        s[0] += (double)xv * g0.x; s[1] += (double)xv * g0.y;
        s[2] += (double)xv * g0.z; s[3] += (double)xv * g0.w;
        s[4] += (double)xv * g1.x; s[5] += (double)xv * g1.y;
        s[6] += (double)xv * g1.z; s[7] += (double)xv * g1.w;
    }
#pragma unroll
    for (int off = 32; off >= 1; off >>= 1)
#pragma unroll
        for (int j = 0; j < E_NUM; ++j) s[j] += __shfl_xor(s[j], off, 64);

    if (lane == 0) {
#pragma unroll
        for (int j = 0; j < E_NUM; ++j) s[j] += (double)gb[j];
        int i0 = 0;
        for (int j = 1; j < E_NUM; ++j) if (s[j] > s[i0]) i0 = j;
        int i1 = (i0 == 0) ? 1 : 0;
        for (int j = 0; j < E_NUM; ++j) if (j != i0 && s[j] > s[i1]) i1 = j;
        const double e1 = exp(s[i1] - s[i0]);
        const float p0 = (float)(1.0 / (1.0 + e1));
        const float p1 = (float)(e1 / (1.0 + e1));
        int pos0 = atomicAdd(&counts[i0], 1);
        tok_list[i0 * CAP_E + pos0]  = t;
        prob_list[i0 * CAP_E + pos0] = p0;
        int pos1 = atomicAdd(&counts[i1], 1);
        tok_list[i1 * CAP_E + pos1]  = t;
        prob_list[i1 * CAP_E + pos1] = p1;
    }
}

// transpose+convert one 64x64 tile: in [R][C] fp32 -> out [C][R] bf16
static __device__ void wtrans_body(
    char* pool, const float* __restrict__ in, unsigned short* __restrict__ out,
    int R, int C, int cx, int cy, int bz)
{
    unsigned (*tile)[33] = (unsigned (*)[33])pool;   // 64x33 = 8448 B
    const size_t slab = (size_t)bz * (size_t)R * C;
    const float* inp = in + slab;
    unsigned short* outp = out + slab;
    const int c0 = cx * 64, r0 = cy * 64;
    const int tid = threadIdx.x;
    const int cq = tid & 15, p0 = tid >> 4;
#pragma unroll
    for (int s = 0; s < 2; ++s) {
        const int p = p0 + s * 16;
        const int r = r0 + 2 * p;
        const int c = c0 + cq * 4;
        const float4 va = *(const float4*)(inp + (size_t)r * C + c);
        const float4 vb = *(const float4*)(inp + (size_t)(r + 1) * C + c);
        const float* fa = (const float*)&va;
        const float* fb = (const float*)&vb;
#pragma unroll
        for (int i = 0; i < 4; ++i)
            tile[cq * 4 + i][p] = (unsigned)f2bf(fa[i]) | ((unsigned)f2bf(fb[i]) << 16);
    }
    __syncthreads();
    const int cl = tid >> 2, q = tid & 3;
#pragma unroll
    for (int s = 0; s < 2; ++s) {
        const int qq = q + s * 4;
        uint4 wv;
        wv.x = tile[cl][qq * 4 + 0]; wv.y = tile[cl][qq * 4 + 1];
        wv.z = tile[cl][qq * 4 + 2]; wv.w = tile[cl][qq * 4 + 3];
        *(uint4*)(outp + (size_t)(c0 + cl) * R + r0 + qq * 8) = wv;
    }
}

// FC1 64x128 tile, 24KB pool, LDS-bounce epilogue
static __device__ void fc1_body(
    char* pool,
    const unsigned short* __restrict__ xb, const unsigned short* __restrict__ w1t,
    const float* __restrict__ b1, const int* __restrict__ counts,
    const int* __restrict__ offsets, const int* __restrict__ tok_list,
    unsigned short* __restrict__ h_ws,
    int e, int we, int bx, int by, int row_start, int cap, int packed)
{
    unsigned short* smem = (unsigned short*)pool;   // 12288 shorts
    unsigned short* As = smem;                      // [64][64]
    unsigned short* Bs = smem + 4096;               // [128][64]

    const int cnt = counts[e];
    const int row_end = min(cnt, row_start + cap);
    const int row0 = row_start + by * 64;
    if (row0 >= row_end) return;
    const int n0 = bx * BN;
    const int hb = packed ? offsets[e] : 0;
    const int tid = threadIdx.x;

    const int wv = tid >> 6, lane = tid & 63;
    const int schunk = (lane & 7) ^ (lane >> 3);
    const unsigned short* __restrict__ w1e = w1t + (size_t)we * H_DIM * D_DIM;

    const unsigned short* aptr[2];
#pragma unroll
    for (int j = 0; j < 2; ++j) {
        const int rloc = (wv * 2 + j) * 8 + (lane >> 3);   // 0..63
        const int rr = min(row0 + rloc, row_end - 1);
        aptr[j] = xb + (size_t)tok_list[e * CAP_E + rr] * D_DIM + schunk * 8;
    }
    const unsigned short* bptr[4];
#pragma unroll
    for (int j = 0; j < 4; ++j) {
        const int rloc = (wv * 4 + j) * 8 + (lane >> 3);   // 0..127
        bptr[j] = w1e + (size_t)(n0 + rloc) * D_DIM + schunk * 8;
    }

    const int wc = wv * 32;
    const int rl = lane & 15, x7 = lane & 7, kg = lane >> 4;
    int aoff[2][4], boff[2][2];
#pragma unroll
    for (int s = 0; s < 2; ++s) {
        const int slot = ((((s << 2) + kg) ^ x7) << 3);
#pragma unroll
        for (int m = 0; m < 4; ++m) aoff[s][m] = ((m * 16 + rl) << 6) + slot;
#pragma unroll
        for (int n = 0; n < 2; ++n) boff[s][n] = ((wc + n * 16 + rl) << 6) + slot;
    }

    f32x4 acc[4][2];
#pragma unroll
    for (int m = 0; m < 4; ++m)
#pragma unroll
        for (int n = 0; n < 2; ++n) acc[m][n] = (f32x4){0.f, 0.f, 0.f, 0.f};

    for (int kk = 0; kk < D_DIM; kk += BK) {
        __syncthreads();
#pragma unroll
        for (int j = 0; j < 2; ++j)
            gload16(aptr[j] + kk, &As[(wv * 2 + j) * 512]);
#pragma unroll
        for (int j = 0; j < 4; ++j)
            gload16(bptr[j] + kk, &Bs[(wv * 4 + j) * 512]);
        __syncthreads();
#pragma unroll
        for (int s = 0; s < 2; ++s) {
            bf16x8 af[4], bfv[2];
#pragma unroll
            for (int m = 0; m < 4; ++m) af[m] = *(const bf16x8*)&As[aoff[s][m]];
#pragma unroll
            for (int n = 0; n < 2; ++n) bfv[n] = *(const bf16x8*)&Bs[boff[s][n]];
#pragma unroll
            for (int m = 0; m < 4; ++m)
#pragma unroll
                for (int n = 0; n < 2; ++n)
                    acc[m][n] = __builtin_amdgcn_mfma_f32_16x16x32_bf16(af[m], bfv[n], acc[m][n], 0, 0, 0);
        }
    }

    // epilogue: GELU + bias, LDS-bounce (64 rows x stride 132) -> 16B stores
    const float* __restrict__ b1e = b1 + e * H_DIM;
    const int crb = (lane >> 4) * 4, ccol = lane & 15;
    float bias[2];
#pragma unroll
    for (int n = 0; n < 2; ++n) bias[n] = b1e[n0 + wc + n * 16 + ccol];

    __syncthreads();
#pragma unroll
    for (int n = 0; n < 2; ++n)
#pragma unroll
        for (int m = 0; m < 4; ++m)
#pragma unroll
            for (int j = 0; j < 4; ++j) {
                const int rloc = m * 16 + crb + j;
                const int col = wc + n * 16 + ccol;
                smem[rloc * 132 + col] = f2bf(gelu_f(acc[m][n][j] + bias[n]));
            }
    __syncthreads();
#pragma unroll
    for (int i = 0; i < 4; ++i) {
        const int idx = tid + i * 256;
        const int row = idx >> 4, c8 = idx & 15;
        const uint4 val = *(const uint4*)&smem[row * 132 + c8 * 8];
        const int gr = row0 + row;
        if (gr < row_end)
            *(uint4*)&h_ws[(size_t)(hb + gr - row_start) * H_DIM + n0 + c8 * 8] = val;
    }
}

// ================= kernels ==================================================

__global__ __launch_bounds__(256) void fused_gate_w1trans(
    const float* __restrict__ x, const float* __restrict__ gw,
    const float* __restrict__ gb, int* __restrict__ counts,
    int* __restrict__ tok_list, float* __restrict__ prob_list,
    unsigned short* __restrict__ xb,
    const float* __restrict__ w1, unsigned short* __restrict__ w1t)
{
    __shared__ __align__(16) char pool[8448];
    const int bid = (int)blockIdx.x;
    if (bid < GATE_BLKS) {
        gate_body(x, gw, gb, counts, tok_list, prob_list, xb, bid);
    } else {
        int i = bid - GATE_BLKS;
        const int cx = i & 63; i >>= 6;
        const int cy = i & 15; i >>= 4;
        wtrans_body(pool, w1, w1t, D_DIM, H_DIM, cx, cy, i);
    }
}

__global__ __launch_bounds__(256) void gate_kernel(
    const float* __restrict__ x, const float* __restrict__ gw,
    const float* __restrict__ gb, int* __restrict__ counts,
    int* __restrict__ tok_list, float* __restrict__ prob_list,
    unsigned short* __restrict__ xb)
{
    gate_body(x, gw, gb, counts, tok_list, prob_list, xb, (int)blockIdx.x);
}

__global__ void offsets_kernel(const int* __restrict__ counts, int* __restrict__ offsets) {
    if (threadIdx.x == 0) {
        int acc = 0;
        for (int e = 0; e < E_NUM; ++e) { offsets[e] = acc; acc += counts[e]; }
    }
}

__global__ __launch_bounds__(256) void wtrans_kernel(
    const float* __restrict__ in, unsigned short* __restrict__ out, int R, int C)
{
    __shared__ __align__(16) char pool[8448];
    wtrans_body(pool, in, out, R, C, (int)blockIdx.x, (int)blockIdx.y, (int)blockIdx.z);
}

__global__ __launch_bounds__(256) void fused_fc1_w2trans(
    const unsigned short* __restrict__ xb, const unsigned short* __restrict__ w1t,
    const float* __restrict__ b1, const int* __restrict__ counts,
    const int* __restrict__ offsets, const int* __restrict__ tok_list,
    unsigned short* __restrict__ h_ws,
    const float* __restrict__ w2, unsigned short* __restrict__ w2t)
{
    __shared__ __align__(16) char pool[24576];
    const int bid = (int)blockIdx.x;
    if (bid < FC1_BLKS) {
        const int e = bid & 7; const int r = bid >> 3;
        fc1_body(pool, xb, w1t, b1, counts, offsets, tok_list, h_ws,
                 e, e, r & 31, r >> 5, 0, NTOK, 1);
    } else {
        int i = bid - FC1_BLKS;
        const int cx = i & 15; i >>= 4;
        const int cy = i & 63; i >>= 6;
        wtrans_body(pool, w2, w2t, H_DIM, D_DIM, cx, cy, i);
    }
}

__global__ __launch_bounds__(256) void expert_fc1(
    const unsigned short* __restrict__ xb, const unsigned short* __restrict__ w1t,
    const float* __restrict__ b1, const int* __restrict__ counts,
    const int* __restrict__ offsets, const int* __restrict__ tok_list,
    unsigned short* __restrict__ h_ws,
    int e_param, int we_param, int row_start, int cap, int packed)
{
    __shared__ __align__(16) char pool[24576];
    const int bx = (int)blockIdx.x & 31, by = (int)blockIdx.x >> 5;
    fc1_body(pool, xb, w1t, b1, counts, offsets, tok_list, h_ws,
             e_param, we_param, bx, by, row_start, cap, packed);
}

// ---------------- FC2: 64x128 tile, 24KB, split-K=2, atomic combine ---------
// full decode: bx = bid&7 (column-stripe -> XCD); r=bid>>3: by=r&63; r>>=6:
// ks=r&1, e=r>>1.
__global__ __launch_bounds__(256) void expert_fc2(
    const unsigned short* __restrict__ h_ws, const unsigned short* __restrict__ w2t,
    const float* __restrict__ b2, const int* __restrict__ counts,
    const int* __restrict__ offsets, const int* __restrict__ tok_list,
    const float* __restrict__ prob_list, float* __restrict__ out,
    int splitk, int e_param, int we_param, int row_start, int cap, int packed)
{
    __shared__ __align__(16) unsigned short As[64 * BK];    // 8 KB
    __shared__ __align__(16) unsigned short Bs[128 * BK];   // 16 KB

    int e, bx, by, ks;
    if (e_param >= 0) { e = e_param; bx = (int)blockIdx.x & 7; by = (int)blockIdx.x >> 3; ks = 0; }
    else { bx = (int)blockIdx.x & 7; int r = (int)blockIdx.x >> 3;
           by = r & 63; r >>= 6; ks = r & 1; e = r >> 1; }

    const int we = (we_param >= 0) ? we_param : e;
    const int cnt = counts[e];
    const int row_end = min(cnt, row_start + cap);
    const int row0 = row_start + by * 64;
    if (row0 >= row_end) return;
    const int n0 = bx * BN;
    const int hb = packed ? offsets[e] : 0;
    const int tid = threadIdx.x;

    const int kspan = H_DIM / splitk;
    const int k0 = ks * kspan;

    const int wv = tid >> 6, lane = tid & 63;
    const int schunk = (lane & 7) ^ (lane >> 3);
    const unsigned short* __restrict__ w2e = w2t + (size_t)we * D_DIM * H_DIM;

    const unsigned short* aptr[2];
#pragma unroll
    for (int j = 0; j < 2; ++j) {
        const int rloc = (wv * 2 + j) * 8 + (lane >> 3);   // 0..63
        int r = row0 + rloc; if (r >= row_end) r = row_end - 1;
        aptr[j] = h_ws + (size_t)(hb + r - row_start) * H_DIM + k0 + schunk * 8;
    }
    const unsigned short* bptr[4];
#pragma unroll
    for (int j = 0; j < 4; ++j) {
        const int rloc = (wv * 4 + j) * 8 + (lane >> 3);   // 0..127
        bptr[j] = w2e + (size_t)(n0 + rloc) * H_DIM + k0 + schunk * 8;
    }

    const int wc = wv * 32;
    const int rl = lane & 15, x7 = lane & 7, kg = lane >> 4;
    int aoff[2][4], boff[2][2];
#pragma unroll
    for (int s = 0; s < 2; ++s) {
        const int slot = ((((s << 2) + kg) ^ x7) << 3);
#pragma unroll
        for (int m = 0; m < 4; ++m) aoff[s][m] = ((m * 16 + rl) << 6) + slot;
#pragma unroll
        for (int n = 0; n < 2; ++n) boff[s][n] = ((wc + n * 16 + rl) << 6) + slot;
    }

    f32x4 acc[4][2];
#pragma unroll
    for (int m = 0; m < 4; ++m)
#pragma unroll
        for (int n = 0; n < 2; ++n) acc[m][n] = (f32x4){0.f, 0.f, 0.f, 0.f};

    for (int kk = 0; kk < kspan; kk += BK) {
        __syncthreads();
#pragma unroll
        for (int j = 0; j < 2; ++j)
            gload16(aptr[j] + kk, &As[(wv * 2 + j) * 512]);
#pragma unroll
        for (int j = 0; j < 4; ++j)
            gload16(bptr[j] + kk, &Bs[(wv * 4 + j) * 512]);
        __syncthreads();
#pragma unroll
        for (int s = 0; s < 2; ++s) {
            bf16x8 af[4], bfv[2];
#pragma unroll
            for (int m = 0; m < 4; ++m) af[m] = *(const bf16x8*)&As[aoff[s][m]];
#pragma unroll
            for (int n = 0; n < 2; ++n) bfv[n] = *(const bf16x8*)&Bs[boff[s][n]];
#pragma unroll
            for (int m = 0; m < 4; ++m)
#pragma unroll
                for (int n = 0; n < 2; ++n)
                    acc[m][n] = __builtin_amdgcn_mfma_f32_16x16x32_bf16(af[m], bfv[n], acc[m][n], 0, 0, 0);
        }
    }

    const float* __restrict__ b2e = b2 + e * D_DIM;
    const int crb = (lane >> 4) * 4, ccol = lane & 15;
#pragma unroll
    for (int n = 0; n < 2; ++n) {
        const int gc = n0 + wc + n * 16 + ccol;
        const float bias = (ks == 0) ? b2e[gc] : 0.f;
#pragma unroll
        for (int m = 0; m < 4; ++m) {
#pragma unroll
            for (int j = 0; j < 4; ++j) {
                const int gr = row0 + m * 16 + crb + j;
                if (gr < row_end) {
                    const float yv = acc[m][n][j] + bias;
                    const int t = tok_list[e * CAP_E + gr];
                    const float p = prob_list[e * CAP_E + gr];
                    atomicAdd(&out[(size_t)t * D_DIM + gc], p * yv);
                }
            }
        }
    }
}

extern "C" void kernel_launch(void* const* d_in, const int* in_sizes, int n_in,
                              void* d_out, int out_size, void* d_ws, size_t ws_size,
                              hipStream_t stream)
{
    const float* x  = (const float*)d_in[0];
    const float* w1 = (const float*)d_in[1];
    const float* b1 = (const float*)d_in[2];
    const float* w2 = (const float*)d_in[3];
    const float* b2 = (const float*)d_in[4];
    const float* gw = (const float*)d_in[5];
    const float* gb = (const float*)d_in[6];
    float* out = (float*)d_out;

    char* w = (char*)d_ws;
    int*   counts    = (int*)w;
    int*   offsets   = (int*)(w + 64);
    int*   tok_list  = (int*)(w + 128);
    float* prob_list = (float*)(w + 128 + (size_t)CAP_E * E_NUM * 4);
    size_t off = 128 + 2 * (size_t)CAP_E * E_NUM * 4;
    off = (off + 255) & ~(size_t)255;
    unsigned short* xb = (unsigned short*)(w + off);
    off += (size_t)NTOK * D_DIM * 2;

    const size_t wslab = (size_t)D_DIM * H_DIM * 2;       // bf16 per expert
    const size_t hfull = (size_t)2 * NTOK * H_DIM * 2;    // packed h, bf16
    const size_t need_full = off + 2 * E_NUM * wslab + hfull;

    hipMemsetAsync(d_out, 0, (size_t)out_size * sizeof(float), stream);
    hipMemsetAsync(counts, 0, 64, stream);

    if (ws_size >= need_full) {
        unsigned short* w1t = (unsigned short*)(w + off);
        unsigned short* w2t = (unsigned short*)(w + off + E_NUM * wslab);
        unsigned short* h_ws = (unsigned short*)(w + off + 2 * E_NUM * wslab);

        // A: gate || w1-transpose (independent roles, one launch)
        fused_gate_w1trans<<<GATE_BLKS + W1T_BLKS, 256, 0, stream>>>(
            x, gw, gb, counts, tok_list, prob_list, xb, w1, w1t);
        offsets_kernel<<<1, 64, 0, stream>>>(counts, offsets);
        // B: fc1 || w2-transpose (fc1 reads A's outputs; w2t read only by fc2)
        fused_fc1_w2trans<<<FC1_BLKS + W2T_BLKS, 256, 0, stream>>>(
            xb, w1t, b1, counts, offsets, tok_list, h_ws, w2, w2t);
        // C: fc2
        expert_fc2<<<8 * 64 * 2 * 8, 256, 0, stream>>>(
            h_ws, w2t, b2, counts, offsets, tok_list, prob_list, out,
            2, -1, -1, 0, NTOK, 1);
    } else {
        // per-expert chunked fallback (atomics)
        gate_kernel<<<GATE_BLKS, 256, 0, stream>>>(x, gw, gb, counts, tok_list, prob_list, xb);
        offsets_kernel<<<1, 64, 0, stream>>>(counts, offsets);
        unsigned short* w1te = (unsigned short*)(w + off);
        unsigned short* w2te = (unsigned short*)(w + off + wslab);
        size_t h_off = off + 2 * wslab;
        unsigned short* h_e = (unsigned short*)(w + h_off);
        size_t h_avail = (ws_size > h_off) ? (ws_size - h_off) / ((size_t)H_DIM * 2) : 0;
        int cap = (int)((h_avail < (size_t)NTOK) ? h_avail : (size_t)NTOK);
        cap = (cap / BM) * BM;
        if (cap < BM) cap = BM;
        const int chunks = (NTOK + cap - 1) / cap;
        for (int e = 0; e < E_NUM; ++e) {
            wtrans_kernel<<<dim3(H_DIM / 64, D_DIM / 64, 1), 256, 0, stream>>>(
                w1 + (size_t)e * D_DIM * H_DIM, w1te, D_DIM, H_DIM);
            wtrans_kernel<<<dim3(D_DIM / 64, H_DIM / 64, 1), 256, 0, stream>>>(
                w2 + (size_t)e * H_DIM * D_DIM, w2te, H_DIM, D_DIM);
            for (int c = 0; c < chunks; ++c) {
                const int rs = c * cap;
                expert_fc1<<<32 * ((cap + 63) / 64), 256, 0, stream>>>(
                    xb, w1te, b1, counts, offsets, tok_list, h_e,
                    e, 0, rs, cap, 0);
                expert_fc2<<<8 * ((cap + 63) / 64), 256, 0, stream>>>(
                    h_e, w2te, b2, counts, offsets, tok_list, prob_list, out,
                    1, e, 0, rs, cap, 0);
            }
        }
    }
}

// Round 18
// 387.319 us; speedup vs baseline: 1.4451x; 1.1633x over previous
//
#include <hip/hip_runtime.h>
#include <hip/hip_bf16.h>
#include <stdint.h>

#define D_DIM 1024
#define H_DIM 4096
#define E_NUM 8
#define NTOK  4096   // B*S
#define CAP_E 4096
#define BM 128
#define BN 128
#define BK 64        // bf16 elems per K-tile; LDS row = 128 B = 8 chunks of 16 B

#define GATE_BLKS (NTOK / 16)         // 256 (16 tokens per block)
#define W1T_BLKS  (64 * 16 * E_NUM)   // 8192  (H/64 x D/64 x E)
#define FC1_BLKS  (E_NUM * 32 * 64)   // 16384 (e x bx x by)
#define W2T_BLKS  (16 * 64 * E_NUM)   // 8192  (D/64 x H/64 x E)

typedef __bf16 bf16x8 __attribute__((ext_vector_type(8)));
typedef float  f32x4  __attribute__((ext_vector_type(4)));

static __device__ __forceinline__ unsigned short f2bf(float f) {
    union { float f; unsigned u; } v; v.f = f;
    unsigned r = v.u + 0x7fffu + ((v.u >> 16) & 1u);   // RNE
    return (unsigned short)(r >> 16);
}

static __device__ __forceinline__ void gload16(const unsigned short* g, unsigned short* l) {
    __builtin_amdgcn_global_load_lds(
        (const __attribute__((address_space(1))) unsigned int*)g,
        (__attribute__((address_space(3))) unsigned int*)l,
        16, 0, 0);
}

// exact-erf GELU via Abramowitz-Stegun 7.1.26 (|err| <= 1.5e-7)
static __device__ __forceinline__ float gelu_f(float v) {
    const float z = fabsf(v) * 0.70710678118654752f;
    const float t = __builtin_amdgcn_rcpf(__builtin_fmaf(0.3275911f, z, 1.f));
    float p = __builtin_fmaf(1.061405429f, t, -1.453152027f);
    p = __builtin_fmaf(p, t, 1.421413741f);
    p = __builtin_fmaf(p, t, -0.284496736f);
    p = __builtin_fmaf(p, t, 0.254829592f);
    const float e = 1.f - p * t * __expf(-z * z);
    const float erfv = (v < 0.f) ? -e : e;
    return v * (0.5f + 0.5f * erfv);
}

// ================= bodies (verified logic, dispatch-agnostic) ===============

// gate: 16 tokens per 256-thread block; LDS histogram -> 8 atomics per block
static __device__ void gate_body(
    const float* __restrict__ x, const float* __restrict__ gw,
    const float* __restrict__ gb, int* __restrict__ counts,
    int* __restrict__ tok_list, float* __restrict__ prob_list,
    unsigned short* __restrict__ xb, char* pool, int bid)
{
    int*   se0  = (int*)pool;          // [16]
    int*   se1  = se0 + 16;            // [16]
    float* sp0  = (float*)(se1 + 16);  // [16]
    float* sp1  = sp0 + 16;            // [16]
    int*   hc   = (int*)(sp1 + 16);    // [8]
    int*   base = hc + 8;              // [8]

    const int wave = threadIdx.x >> 6, lane = threadIdx.x & 63;
#pragma unroll
    for (int g = 0; g < 4; ++g) {
        const int slot = g * 4 + wave;
        const int t = bid * 16 + slot;
        double s[E_NUM];
#pragma unroll
        for (int j = 0; j < E_NUM; ++j) s[j] = 0.0;
        const float* xr = x + (size_t)t * D_DIM;
        unsigned short* xbr = xb + (size_t)t * D_DIM;
#pragma unroll
        for (int i = 0; i < D_DIM / 64; ++i) {
            const int d = i * 64 + lane;
            const float xv = xr[d];
            xbr[d] = f2bf(xv);
            const float4 g0 = *(const float4*)(gw + d * 8);
            const float4 g1 = *(const float4*)(gw + d * 8 + 4);
            s[0] += (double)xv * g0.x; s[1] += (double)xv * g0.y;
            s[2] += (double)xv * g0.z; s[3] += (double)xv * g0.w;
            s[4] += (double)xv * g1.x; s[5] += (double)xv * g1.y;
            s[6] += (double)xv * g1.z; s[7] += (double)xv * g1.w;
        }
#pragma unroll
        for (int off = 32; off >= 1; off >>= 1)
#pragma unroll
            for (int j = 0; j < E_NUM; ++j) s[j] += __shfl_xor(s[j], off, 64);

        if (lane == 0) {
#pragma unroll
            for (int j = 0; j < E_NUM; ++j) s[j] += (double)gb[j];
            int i0 = 0;
            for (int j = 1; j < E_NUM; ++j) if (s[j] > s[i0]) i0 = j;
            int i1 = (i0 == 0) ? 1 : 0;
            for (int j = 0; j < E_NUM; ++j) if (j != i0 && s[j] > s[i1]) i1 = j;
            const double e1 = exp(s[i1] - s[i0]);
            se0[slot] = i0;
            se1[slot] = i1;
            sp0[slot] = (float)(1.0 / (1.0 + e1));
            sp1[slot] = (float)(e1 / (1.0 + e1));
        }
    }
    __syncthreads();
    if (threadIdx.x == 0) {
        int h[E_NUM];
#pragma unroll
        for (int e = 0; e < E_NUM; ++e) h[e] = 0;
        for (int k = 0; k < 16; ++k) { h[se0[k]]++; h[se1[k]]++; }
#pragma unroll
        for (int e = 0; e < E_NUM; ++e) hc[e] = h[e];
    }
    __syncthreads();
    if (threadIdx.x < E_NUM)
        base[threadIdx.x] = atomicAdd(&counts[threadIdx.x], hc[threadIdx.x]);
    __syncthreads();
    if (threadIdx.x == 0) {
        int cur[E_NUM];
#pragma unroll
        for (int e = 0; e < E_NUM; ++e) cur[e] = base[e];
        for (int k = 0; k < 16; ++k) {
            const int t = bid * 16 + k;
            int e = se0[k]; int pos = cur[e]++;
            tok_list[e * CAP_E + pos] = t; prob_list[e * CAP_E + pos] = sp0[k];
            e = se1[k]; pos = cur[e]++;
            tok_list[e * CAP_E + pos] = t; prob_list[e * CAP_E + pos] = sp1[k];
        }
    }
}

// transpose+convert one 64x64 tile: in [R][C] fp32 -> out [C][R] bf16
static __device__ void wtrans_body(
    char* pool, const float* __restrict__ in, unsigned short* __restrict__ out,
    int R, int C, int cx, int cy, int bz)
{
    unsigned (*tile)[33] = (unsigned (*)[33])pool;   // 64x33 = 8448 B
    const size_t slab = (size_t)bz * (size_t)R * C;
    const float* inp = in + slab;
    unsigned short* outp = out + slab;
    const int c0 = cx * 64, r0 = cy * 64;
    const int tid = threadIdx.x;
    const int cq = tid & 15, p0 = tid >> 4;
#pragma unroll
    for (int s = 0; s < 2; ++s) {
        const int p = p0 + s * 16;
        const int r = r0 + 2 * p;
        const int c = c0 + cq * 4;
        const float4 va = *(const float4*)(inp + (size_t)r * C + c);
        const float4 vb = *(const float4*)(inp + (size_t)(r + 1) * C + c);
        const float* fa = (const float*)&va;
        const float* fb = (const float*)&vb;
#pragma unroll
        for (int i = 0; i < 4; ++i)
            tile[cq * 4 + i][p] = (unsigned)f2bf(fa[i]) | ((unsigned)f2bf(fb[i]) << 16);
    }
    __syncthreads();
    const int cl = tid >> 2, q = tid & 3;
#pragma unroll
    for (int s = 0; s < 2; ++s) {
        const int qq = q + s * 4;
        uint4 wv;
        wv.x = tile[cl][qq * 4 + 0]; wv.y = tile[cl][qq * 4 + 1];
        wv.z = tile[cl][qq * 4 + 2]; wv.w = tile[cl][qq * 4 + 3];
        *(uint4*)(outp + (size_t)(c0 + cl) * R + r0 + qq * 8) = wv;
    }
}

// FC1 64x128 tile, 24KB pool, LDS-bounce epilogue
static __device__ void fc1_body(
    char* pool,
    const unsigned short* __restrict__ xb, const unsigned short* __restrict__ w1t,
    const float* __restrict__ b1, const int* __restrict__ counts,
    const int* __restrict__ offsets, const int* __restrict__ tok_list,
    unsigned short* __restrict__ h_ws,
    int e, int we, int bx, int by, int row_start, int cap, int packed)
{
    unsigned short* smem = (unsigned short*)pool;   // 12288 shorts
    unsigned short* As = smem;                      // [64][64]
    unsigned short* Bs = smem + 4096;               // [128][64]

    const int cnt = counts[e];
    const int row_end = min(cnt, row_start + cap);
    const int row0 = row_start + by * 64;
    if (row0 >= row_end) return;
    const int n0 = bx * BN;
    const int hb = packed ? offsets[e] : 0;
    const int tid = threadIdx.x;

    const int wv = tid >> 6, lane = tid & 63;
    const int schunk = (lane & 7) ^ (lane >> 3);
    const unsigned short* __restrict__ w1e = w1t + (size_t)we * H_DIM * D_DIM;

    const unsigned short* aptr[2];
#pragma unroll
    for (int j = 0; j < 2; ++j) {
        const int rloc = (wv * 2 + j) * 8 + (lane >> 3);   // 0..63
        const int rr = min(row0 + rloc, row_end - 1);
        aptr[j] = xb + (size_t)tok_list[e * CAP_E + rr] * D_DIM + schunk * 8;
    }
    const unsigned short* bptr[4];
#pragma unroll
    for (int j = 0; j < 4; ++j) {
        const int rloc = (wv * 4 + j) * 8 + (lane >> 3);   // 0..127
        bptr[j] = w1e + (size_t)(n0 + rloc) * D_DIM + schunk * 8;
    }

    const int wc = wv * 32;
    const int rl = lane & 15, x7 = lane & 7, kg = lane >> 4;
    int aoff[2][4], boff[2][2];
#pragma unroll
    for (int s = 0; s < 2; ++s) {
        const int slot = ((((s << 2) + kg) ^ x7) << 3);
#pragma unroll
        for (int m = 0; m < 4; ++m) aoff[s][m] = ((m * 16 + rl) << 6) + slot;
#pragma unroll
        for (int n = 0; n < 2; ++n) boff[s][n] = ((wc + n * 16 + rl) << 6) + slot;
    }

    f32x4 acc[4][2];
#pragma unroll
    for (int m = 0; m < 4; ++m)
#pragma unroll
        for (int n = 0; n < 2; ++n) acc[m][n] = (f32x4){0.f, 0.f, 0.f, 0.f};

    for (int kk = 0; kk < D_DIM; kk += BK) {
        __syncthreads();
#pragma unroll
        for (int j = 0; j < 2; ++j)
            gload16(aptr[j] + kk, &As[(wv * 2 + j) * 512]);
#pragma unroll
        for (int j = 0; j < 4; ++j)
            gload16(bptr[j] + kk, &Bs[(wv * 4 + j) * 512]);
        __syncthreads();
#pragma unroll
        for (int s = 0; s < 2; ++s) {
            bf16x8 af[4], bfv[2];
#pragma unroll
            for (int m = 0; m < 4; ++m) af[m] = *(const bf16x8*)&As[aoff[s][m]];
#pragma unroll
            for (int n = 0; n < 2; ++n) bfv[n] = *(const bf16x8*)&Bs[boff[s][n]];
#pragma unroll
            for (int m = 0; m < 4; ++m)
#pragma unroll
                for (int n = 0; n < 2; ++n)
                    acc[m][n] = __builtin_amdgcn_mfma_f32_16x16x32_bf16(af[m], bfv[n], acc[m][n], 0, 0, 0);
        }
    }

    // epilogue: GELU + bias, LDS-bounce (64 rows x stride 132) -> 16B stores
    const float* __restrict__ b1e = b1 + e * H_DIM;
    const int crb = (lane >> 4) * 4, ccol = lane & 15;
    float bias[2];
#pragma unroll
    for (int n = 0; n < 2; ++n) bias[n] = b1e[n0 + wc + n * 16 + ccol];

    __syncthreads();
#pragma unroll
    for (int n = 0; n < 2; ++n)
#pragma unroll
        for (int m = 0; m < 4; ++m)
#pragma unroll
            for (int j = 0; j < 4; ++j) {
                const int rloc = m * 16 + crb + j;
                const int col = wc + n * 16 + ccol;
                smem[rloc * 132 + col] = f2bf(gelu_f(acc[m][n][j] + bias[n]));
            }
    __syncthreads();
#pragma unroll
    for (int i = 0; i < 4; ++i) {
        const int idx = tid + i * 256;
        const int row = idx >> 4, c8 = idx & 15;
        const uint4 val = *(const uint4*)&smem[row * 132 + c8 * 8];
        const int gr = row0 + row;
        if (gr < row_end)
            *(uint4*)&h_ws[(size_t)(hb + gr - row_start) * H_DIM + n0 + c8 * 8] = val;
    }
}

// ================= kernels ==================================================

__global__ __launch_bounds__(256) void fused_gate_w1trans(
    const float* __restrict__ x, const float* __restrict__ gw,
    const float* __restrict__ gb, int* __restrict__ counts,
    int* __restrict__ tok_list, float* __restrict__ prob_list,
    unsigned short* __restrict__ xb,
    const float* __restrict__ w1, unsigned short* __restrict__ w1t)
{
    __shared__ __align__(16) char pool[8448];
    const int bid = (int)blockIdx.x;
    if (bid < GATE_BLKS) {
        gate_body(x, gw, gb, counts, tok_list, prob_list, xb, pool, bid);
    } else {
        int i = bid - GATE_BLKS;
        const int cx = i & 63; i >>= 6;
        const int cy = i & 15; i >>= 4;
        wtrans_body(pool, w1, w1t, D_DIM, H_DIM, cx, cy, i);
    }
}

__global__ __launch_bounds__(256) void gate_kernel(
    const float* __restrict__ x, const float* __restrict__ gw,
    const float* __restrict__ gb, int* __restrict__ counts,
    int* __restrict__ tok_list, float* __restrict__ prob_list,
    unsigned short* __restrict__ xb)
{
    __shared__ __align__(16) char pool[8448];
    gate_body(x, gw, gb, counts, tok_list, prob_list, xb, pool, (int)blockIdx.x);
}

__global__ void offsets_kernel(const int* __restrict__ counts, int* __restrict__ offsets) {
    if (threadIdx.x == 0) {
        int acc = 0;
        for (int e = 0; e < E_NUM; ++e) { offsets[e] = acc; acc += counts[e]; }
    }
}

__global__ __launch_bounds__(256) void wtrans_kernel(
    const float* __restrict__ in, unsigned short* __restrict__ out, int R, int C)
{
    __shared__ __align__(16) char pool[8448];
    wtrans_body(pool, in, out, R, C, (int)blockIdx.x, (int)blockIdx.y, (int)blockIdx.z);
}

__global__ __launch_bounds__(256) void fused_fc1_w2trans(
    const unsigned short* __restrict__ xb, const unsigned short* __restrict__ w1t,
    const float* __restrict__ b1, const int* __restrict__ counts,
    const int* __restrict__ offsets, const int* __restrict__ tok_list,
    unsigned short* __restrict__ h_ws,
    const float* __restrict__ w2, unsigned short* __restrict__ w2t)
{
    __shared__ __align__(16) char pool[24576];
    const int bid = (int)blockIdx.x;
    if (bid < FC1_BLKS) {
        const int e = bid & 7; const int r = bid >> 3;
        fc1_body(pool, xb, w1t, b1, counts, offsets, tok_list, h_ws,
                 e, e, r & 31, r >> 5, 0, NTOK, 1);
    } else {
        int i = bid - FC1_BLKS;
        const int cx = i & 15; i >>= 4;
        const int cy = i & 63; i >>= 6;
        wtrans_body(pool, w2, w2t, H_DIM, D_DIM, cx, cy, i);
    }
}

__global__ __launch_bounds__(256) void expert_fc1(
    const unsigned short* __restrict__ xb, const unsigned short* __restrict__ w1t,
    const float* __restrict__ b1, const int* __restrict__ counts,
    const int* __restrict__ offsets, const int* __restrict__ tok_list,
    unsigned short* __restrict__ h_ws,
    int e_param, int we_param, int row_start, int cap, int packed)
{
    __shared__ __align__(16) char pool[24576];
    const int bx = (int)blockIdx.x & 31, by = (int)blockIdx.x >> 5;
    fc1_body(pool, xb, w1t, b1, counts, offsets, tok_list, h_ws,
             e_param, we_param, bx, by, row_start, cap, packed);
}

// ---------------- FC2: 64x128 tile, 24KB, split-K=2, atomic combine ---------
// full decode: bx = bid&7 (column-stripe -> XCD); r=bid>>3: by=r&63; r>>=6:
// ks=r&1, e=r>>1.
__global__ __launch_bounds__(256) void expert_fc2(
    const unsigned short* __restrict__ h_ws, const unsigned short* __restrict__ w2t,
    const float* __restrict__ b2, const int* __restrict__ counts,
    const int* __restrict__ offsets, const int* __restrict__ tok_list,
    const float* __restrict__ prob_list, float* __restrict__ out,
    int splitk, int e_param, int we_param, int row_start, int cap, int packed)
{
    __shared__ __align__(16) unsigned short As[64 * BK];    // 8 KB
    __shared__ __align__(16) unsigned short Bs[128 * BK];   // 16 KB

    int e, bx, by, ks;
    if (e_param >= 0) { e = e_param; bx = (int)blockIdx.x & 7; by = (int)blockIdx.x >> 3; ks = 0; }
    else { bx = (int)blockIdx.x & 7; int r = (int)blockIdx.x >> 3;
           by = r & 63; r >>= 6; ks = r & 1; e = r >> 1; }

    const int we = (we_param >= 0) ? we_param : e;
    const int cnt = counts[e];
    const int row_end = min(cnt, row_start + cap);
    const int row0 = row_start + by * 64;
    if (row0 >= row_end) return;
    const int n0 = bx * BN;
    const int hb = packed ? offsets[e] : 0;
    const int tid = threadIdx.x;

    const int kspan = H_DIM / splitk;
    const int k0 = ks * kspan;

    const int wv = tid >> 6, lane = tid & 63;
    const int schunk = (lane & 7) ^ (lane >> 3);
    const unsigned short* __restrict__ w2e = w2t + (size_t)we * D_DIM * H_DIM;

    const unsigned short* aptr[2];
#pragma unroll
    for (int j = 0; j < 2; ++j) {
        const int rloc = (wv * 2 + j) * 8 + (lane >> 3);   // 0..63
        int r = row0 + rloc; if (r >= row_end) r = row_end - 1;
        aptr[j] = h_ws + (size_t)(hb + r - row_start) * H_DIM + k0 + schunk * 8;
    }
    const unsigned short* bptr[4];
#pragma unroll
    for (int j = 0; j < 4; ++j) {
        const int rloc = (wv * 4 + j) * 8 + (lane >> 3);   // 0..127
        bptr[j] = w2e + (size_t)(n0 + rloc) * H_DIM + k0 + schunk * 8;
    }

    const int wc = wv * 32;
    const int rl = lane & 15, x7 = lane & 7, kg = lane >> 4;
    int aoff[2][4], boff[2][2];
#pragma unroll
    for (int s = 0; s < 2; ++s) {
        const int slot = ((((s << 2) + kg) ^ x7) << 3);
#pragma unroll
        for (int m = 0; m < 4; ++m) aoff[s][m] = ((m * 16 + rl) << 6) + slot;
#pragma unroll
        for (int n = 0; n < 2; ++n) boff[s][n] = ((wc + n * 16 + rl) << 6) + slot;
    }

    f32x4 acc[4][2];
#pragma unroll
    for (int m = 0; m < 4; ++m)
#pragma unroll
        for (int n = 0; n < 2; ++n) acc[m][n] = (f32x4){0.f, 0.f, 0.f, 0.f};

    for (int kk = 0; kk < kspan; kk += BK) {
        __syncthreads();
#pragma unroll
        for (int j = 0; j < 2; ++j)
            gload16(aptr[j] + kk, &As[(wv * 2 + j) * 512]);
#pragma unroll
        for (int j = 0; j < 4; ++j)
            gload16(bptr[j] + kk, &Bs[(wv * 4 + j) * 512]);
        __syncthreads();
#pragma unroll
        for (int s = 0; s < 2; ++s) {
            bf16x8 af[4], bfv[2];
#pragma unroll
            for (int m = 0; m < 4; ++m) af[m] = *(const bf16x8*)&As[aoff[s][m]];
#pragma unroll
            for (int n = 0; n < 2; ++n) bfv[n] = *(const bf16x8*)&Bs[boff[s][n]];
#pragma unroll
            for (int m = 0; m < 4; ++m)
#pragma unroll
                for (int n = 0; n < 2; ++n)
                    acc[m][n] = __builtin_amdgcn_mfma_f32_16x16x32_bf16(af[m], bfv[n], acc[m][n], 0, 0, 0);
        }
    }

    const float* __restrict__ b2e = b2 + e * D_DIM;
    const int crb = (lane >> 4) * 4, ccol = lane & 15;
#pragma unroll
    for (int n = 0; n < 2; ++n) {
        const int gc = n0 + wc + n * 16 + ccol;
        const float bias = (ks == 0) ? b2e[gc] : 0.f;
#pragma unroll
        for (int m = 0; m < 4; ++m) {
#pragma unroll
            for (int j = 0; j < 4; ++j) {
                const int gr = row0 + m * 16 + crb + j;
                if (gr < row_end) {
                    const float yv = acc[m][n][j] + bias;
                    const int t = tok_list[e * CAP_E + gr];
                    const float p = prob_list[e * CAP_E + gr];
                    atomicAdd(&out[(size_t)t * D_DIM + gc], p * yv);
                }
            }
        }
    }
}

extern "C" void kernel_launch(void* const* d_in, const int* in_sizes, int n_in,
                              void* d_out, int out_size, void* d_ws, size_t ws_size,
                              hipStream_t stream)
{
    const float* x  = (const float*)d_in[0];
    const float* w1 = (const float*)d_in[1];
    const float* b1 = (const float*)d_in[2];
    const float* w2 = (const float*)d_in[3];
    const float* b2 = (const float*)d_in[4];
    const float* gw = (const float*)d_in[5];
    const float* gb = (const float*)d_in[6];
    float* out = (float*)d_out;

    char* w = (char*)d_ws;
    int*   counts    = (int*)w;
    int*   offsets   = (int*)(w + 64);
    int*   tok_list  = (int*)(w + 128);
    float* prob_list = (float*)(w + 128 + (size_t)CAP_E * E_NUM * 4);
    size_t off = 128 + 2 * (size_t)CAP_E * E_NUM * 4;
    off = (off + 255) & ~(size_t)255;
    unsigned short* xb = (unsigned short*)(w + off);
    off += (size_t)NTOK * D_DIM * 2;

    const size_t wslab = (size_t)D_DIM * H_DIM * 2;       // bf16 per expert
    const size_t hfull = (size_t)2 * NTOK * H_DIM * 2;    // packed h, bf16
    const size_t need_full = off + 2 * E_NUM * wslab + hfull;

    hipMemsetAsync(d_out, 0, (size_t)out_size * sizeof(float), stream);
    hipMemsetAsync(counts, 0, 64, stream);

    if (ws_size >= need_full) {
        unsigned short* w1t = (unsigned short*)(w + off);
        unsigned short* w2t = (unsigned short*)(w + off + E_NUM * wslab);
        unsigned short* h_ws = (unsigned short*)(w + off + 2 * E_NUM * wslab);

        // A: gate || w1-transpose (independent roles, one launch)
        fused_gate_w1trans<<<GATE_BLKS + W1T_BLKS, 256, 0, stream>>>(
            x, gw, gb, counts, tok_list, prob_list, xb, w1, w1t);
        offsets_kernel<<<1, 64, 0, stream>>>(counts, offsets);
        // B: fc1 || w2-transpose (fc1 reads A's outputs; w2t read only by fc2)
        fused_fc1_w2trans<<<FC1_BLKS + W2T_BLKS, 256, 0, stream>>>(
            xb, w1t, b1, counts, offsets, tok_list, h_ws, w2, w2t);
        // C: fc2
        expert_fc2<<<8 * 64 * 2 * 8, 256, 0, stream>>>(
            h_ws, w2t, b2, counts, offsets, tok_list, prob_list, out,
            2, -1, -1, 0, NTOK, 1);
    } else {
        // per-expert chunked fallback (atomics)
        gate_kernel<<<GATE_BLKS, 256, 0, stream>>>(x, gw, gb, counts, tok_list, prob_list, xb);
        offsets_kernel<<<1, 64, 0, stream>>>(counts, offsets);
        unsigned short* w1te = (unsigned short*)(w + off);
        unsigned short* w2te = (unsigned short*)(w + off + wslab);
        size_t h_off = off + 2 * wslab;
        unsigned short* h_e = (unsigned short*)(w + h_off);
        size_t h_avail = (ws_size > h_off) ? (ws_size - h_off) / ((size_t)H_DIM * 2) : 0;
        int cap = (int)((h_avail < (size_t)NTOK) ? h_avail : (size_t)NTOK);
        cap = (cap / BM) * BM;
        if (cap < BM) cap = BM;
        const int chunks = (NTOK + cap - 1) / cap;
        for (int e = 0; e < E_NUM; ++e) {
            wtrans_kernel<<<dim3(H_DIM / 64, D_DIM / 64, 1), 256, 0, stream>>>(
                w1 + (size_t)e * D_DIM * H_DIM, w1te, D_DIM, H_DIM);
            wtrans_kernel<<<dim3(D_DIM / 64, H_DIM / 64, 1), 256, 0, stream>>>(
                w2 + (size_t)e * H_DIM * D_DIM, w2te, H_DIM, D_DIM);
            for (int c = 0; c < chunks; ++c) {
                const int rs = c * cap;
                expert_fc1<<<32 * ((cap + 63) / 64), 256, 0, stream>>>(
                    xb, w1te, b1, counts, offsets, tok_list, h_e,
                    e, 0, rs, cap, 0);
                expert_fc2<<<8 * ((cap + 63) / 64), 256, 0, stream>>>(
                    h_e, w2te, b2, counts, offsets, tok_list, prob_list, out,
                    1, e, 0, rs, cap, 0);
            }
        }
    }
}

// Round 19
// 385.293 us; speedup vs baseline: 1.4527x; 1.0053x over previous
//
#include <hip/hip_runtime.h>
#include <hip/hip_bf16.h>
#include <stdint.h>

#define D_DIM 1024
#define H_DIM 4096
#define E_NUM 8
#define NTOK  4096   // B*S
#define CAP_E 4096
#define BM 128
#define BN 128
#define BK 64        // bf16 elems per K-tile; LDS row = 128 B = 8 chunks of 16 B

#define GATE_BLKS (NTOK / 16)         // 256 (16 tokens per block)
#define W1T_BLKS  (64 * 16 * E_NUM)   // 8192  (H/64 x D/64 x E)
#define FC1_BLKS  (E_NUM * 32 * 64)   // 16384 (e x bx x by)
#define W2T_BLKS  (16 * 64 * E_NUM)   // 8192  (D/64 x H/64 x E)

typedef __bf16 bf16x8 __attribute__((ext_vector_type(8)));
typedef float  f32x4  __attribute__((ext_vector_type(4)));

static __device__ __forceinline__ unsigned short f2bf(float f) {
    union { float f; unsigned u; } v; v.f = f;
    unsigned r = v.u + 0x7fffu + ((v.u >> 16) & 1u);   // RNE
    return (unsigned short)(r >> 16);
}

static __device__ __forceinline__ void gload16(const unsigned short* g, unsigned short* l) {
    __builtin_amdgcn_global_load_lds(
        (const __attribute__((address_space(1))) unsigned int*)g,
        (__attribute__((address_space(3))) unsigned int*)l,
        16, 0, 0);
}

// exact-erf GELU via Abramowitz-Stegun 7.1.26 (|err| <= 1.5e-7)
static __device__ __forceinline__ float gelu_f(float v) {
    const float z = fabsf(v) * 0.70710678118654752f;
    const float t = __builtin_amdgcn_rcpf(__builtin_fmaf(0.3275911f, z, 1.f));
    float p = __builtin_fmaf(1.061405429f, t, -1.453152027f);
    p = __builtin_fmaf(p, t, 1.421413741f);
    p = __builtin_fmaf(p, t, -0.284496736f);
    p = __builtin_fmaf(p, t, 0.254829592f);
    const float e = 1.f - p * t * __expf(-z * z);
    const float erfv = (v < 0.f) ? -e : e;
    return v * (0.5f + 0.5f * erfv);
}

// inline 8-bin exclusive prefix of counts (replaces offsets kernel)
static __device__ __forceinline__ int packed_base(const int* __restrict__ counts, int e) {
    int hb = 0;
#pragma unroll
    for (int i = 0; i < E_NUM; ++i) hb += (i < e) ? counts[i] : 0;
    return hb;
}

// ================= bodies (verified logic, dispatch-agnostic) ===============

// gate: 16 tokens per 256-thread block; LDS histogram -> 8 atomics per block
static __device__ void gate_body(
    const float* __restrict__ x, const float* __restrict__ gw,
    const float* __restrict__ gb, int* __restrict__ counts,
    int* __restrict__ tok_list, float* __restrict__ prob_list,
    unsigned short* __restrict__ xb, char* pool, int bid)
{
    int*   se0  = (int*)pool;          // [16]
    int*   se1  = se0 + 16;            // [16]
    float* sp0  = (float*)(se1 + 16);  // [16]
    float* sp1  = sp0 + 16;            // [16]
    int*   hc   = (int*)(sp1 + 16);    // [8]
    int*   base = hc + 8;              // [8]

    const int wave = threadIdx.x >> 6, lane = threadIdx.x & 63;
#pragma unroll
    for (int g = 0; g < 4; ++g) {
        const int slot = g * 4 + wave;
        const int t = bid * 16 + slot;
        double s[E_NUM];
#pragma unroll
        for (int j = 0; j < E_NUM; ++j) s[j] = 0.0;
        const float* xr = x + (size_t)t * D_DIM;
        unsigned short* xbr = xb + (size_t)t * D_DIM;
#pragma unroll
        for (int i = 0; i < D_DIM / 64; ++i) {
            const int d = i * 64 + lane;
            const float xv = xr[d];
            xbr[d] = f2bf(xv);
            const float4 g0 = *(const float4*)(gw + d * 8);
            const float4 g1 = *(const float4*)(gw + d * 8 + 4);
            s[0] += (double)xv * g0.x; s[1] += (double)xv * g0.y;
            s[2] += (double)xv * g0.z; s[3] += (double)xv * g0.w;
            s[4] += (double)xv * g1.x; s[5] += (double)xv * g1.y;
            s[6] += (double)xv * g1.z; s[7] += (double)xv * g1.w;
        }
#pragma unroll
        for (int off = 32; off >= 1; off >>= 1)
#pragma unroll
            for (int j = 0; j < E_NUM; ++j) s[j] += __shfl_xor(s[j], off, 64);

        if (lane == 0) {
#pragma unroll
            for (int j = 0; j < E_NUM; ++j) s[j] += (double)gb[j];
            int i0 = 0;
            for (int j = 1; j < E_NUM; ++j) if (s[j] > s[i0]) i0 = j;
            int i1 = (i0 == 0) ? 1 : 0;
            for (int j = 0; j < E_NUM; ++j) if (j != i0 && s[j] > s[i1]) i1 = j;
            const double e1 = exp(s[i1] - s[i0]);
            se0[slot] = i0;
            se1[slot] = i1;
            sp0[slot] = (float)(1.0 / (1.0 + e1));
            sp1[slot] = (float)(e1 / (1.0 + e1));
        }
    }
    __syncthreads();
    if (threadIdx.x == 0) {
        int h[E_NUM];
#pragma unroll
        for (int e = 0; e < E_NUM; ++e) h[e] = 0;
        for (int k = 0; k < 16; ++k) { h[se0[k]]++; h[se1[k]]++; }
#pragma unroll
        for (int e = 0; e < E_NUM; ++e) hc[e] = h[e];
    }
    __syncthreads();
    if (threadIdx.x < E_NUM)
        base[threadIdx.x] = atomicAdd(&counts[threadIdx.x], hc[threadIdx.x]);
    __syncthreads();
    if (threadIdx.x == 0) {
        int cur[E_NUM];
#pragma unroll
        for (int e = 0; e < E_NUM; ++e) cur[e] = base[e];
        for (int k = 0; k < 16; ++k) {
            const int t = bid * 16 + k;
            int e = se0[k]; int pos = cur[e]++;
            tok_list[e * CAP_E + pos] = t; prob_list[e * CAP_E + pos] = sp0[k];
            e = se1[k]; pos = cur[e]++;
            tok_list[e * CAP_E + pos] = t; prob_list[e * CAP_E + pos] = sp1[k];
        }
    }
}

// transpose+convert one 64x64 tile: in [R][C] fp32 -> out [C][R] bf16
static __device__ void wtrans_body(
    char* pool, const float* __restrict__ in, unsigned short* __restrict__ out,
    int R, int C, int cx, int cy, int bz)
{
    unsigned (*tile)[33] = (unsigned (*)[33])pool;   // 64x33 = 8448 B
    const size_t slab = (size_t)bz * (size_t)R * C;
    const float* inp = in + slab;
    unsigned short* outp = out + slab;
    const int c0 = cx * 64, r0 = cy * 64;
    const int tid = threadIdx.x;
    const int cq = tid & 15, p0 = tid >> 4;
#pragma unroll
    for (int s = 0; s < 2; ++s) {
        const int p = p0 + s * 16;
        const int r = r0 + 2 * p;
        const int c = c0 + cq * 4;
        const float4 va = *(const float4*)(inp + (size_t)r * C + c);
        const float4 vb = *(const float4*)(inp + (size_t)(r + 1) * C + c);
        const float* fa = (const float*)&va;
        const float* fb = (const float*)&vb;
#pragma unroll
        for (int i = 0; i < 4; ++i)
            tile[cq * 4 + i][p] = (unsigned)f2bf(fa[i]) | ((unsigned)f2bf(fb[i]) << 16);
    }
    __syncthreads();
    const int cl = tid >> 2, q = tid & 3;
#pragma unroll
    for (int s = 0; s < 2; ++s) {
        const int qq = q + s * 4;
        uint4 wv;
        wv.x = tile[cl][qq * 4 + 0]; wv.y = tile[cl][qq * 4 + 1];
        wv.z = tile[cl][qq * 4 + 2]; wv.w = tile[cl][qq * 4 + 3];
        *(uint4*)(outp + (size_t)(c0 + cl) * R + r0 + qq * 8) = wv;
    }
}

// FC1 64x128 tile, 24KB pool, LDS-bounce epilogue
static __device__ void fc1_body(
    char* pool,
    const unsigned short* __restrict__ xb, const unsigned short* __restrict__ w1t,
    const float* __restrict__ b1, const int* __restrict__ counts,
    const int* __restrict__ tok_list,
    unsigned short* __restrict__ h_ws,
    int e, int we, int bx, int by, int row_start, int cap, int packed)
{
    unsigned short* smem = (unsigned short*)pool;   // 12288 shorts
    unsigned short* As = smem;                      // [64][64]
    unsigned short* Bs = smem + 4096;               // [128][64]

    const int cnt = counts[e];
    const int row_end = min(cnt, row_start + cap);
    const int row0 = row_start + by * 64;
    if (row0 >= row_end) return;
    const int n0 = bx * BN;
    const int hb = packed ? packed_base(counts, e) : 0;
    const int tid = threadIdx.x;

    const int wv = tid >> 6, lane = tid & 63;
    const int schunk = (lane & 7) ^ (lane >> 3);
    const unsigned short* __restrict__ w1e = w1t + (size_t)we * H_DIM * D_DIM;

    const unsigned short* aptr[2];
#pragma unroll
    for (int j = 0; j < 2; ++j) {
        const int rloc = (wv * 2 + j) * 8 + (lane >> 3);   // 0..63
        const int rr = min(row0 + rloc, row_end - 1);
        aptr[j] = xb + (size_t)tok_list[e * CAP_E + rr] * D_DIM + schunk * 8;
    }
    const unsigned short* bptr[4];
#pragma unroll
    for (int j = 0; j < 4; ++j) {
        const int rloc = (wv * 4 + j) * 8 + (lane >> 3);   // 0..127
        bptr[j] = w1e + (size_t)(n0 + rloc) * D_DIM + schunk * 8;
    }

    const int wc = wv * 32;
    const int rl = lane & 15, x7 = lane & 7, kg = lane >> 4;
    int aoff[2][4], boff[2][2];
#pragma unroll
    for (int s = 0; s < 2; ++s) {
        const int slot = ((((s << 2) + kg) ^ x7) << 3);
#pragma unroll
        for (int m = 0; m < 4; ++m) aoff[s][m] = ((m * 16 + rl) << 6) + slot;
#pragma unroll
        for (int n = 0; n < 2; ++n) boff[s][n] = ((wc + n * 16 + rl) << 6) + slot;
    }

    f32x4 acc[4][2];
#pragma unroll
    for (int m = 0; m < 4; ++m)
#pragma unroll
        for (int n = 0; n < 2; ++n) acc[m][n] = (f32x4){0.f, 0.f, 0.f, 0.f};

    for (int kk = 0; kk < D_DIM; kk += BK) {
        __syncthreads();
#pragma unroll
        for (int j = 0; j < 2; ++j)
            gload16(aptr[j] + kk, &As[(wv * 2 + j) * 512]);
#pragma unroll
        for (int j = 0; j < 4; ++j)
            gload16(bptr[j] + kk, &Bs[(wv * 4 + j) * 512]);
        __syncthreads();
#pragma unroll
        for (int s = 0; s < 2; ++s) {
            bf16x8 af[4], bfv[2];
#pragma unroll
            for (int m = 0; m < 4; ++m) af[m] = *(const bf16x8*)&As[aoff[s][m]];
#pragma unroll
            for (int n = 0; n < 2; ++n) bfv[n] = *(const bf16x8*)&Bs[boff[s][n]];
#pragma unroll
            for (int m = 0; m < 4; ++m)
#pragma unroll
                for (int n = 0; n < 2; ++n)
                    acc[m][n] = __builtin_amdgcn_mfma_f32_16x16x32_bf16(af[m], bfv[n], acc[m][n], 0, 0, 0);
        }
    }

    // epilogue: GELU + bias, LDS-bounce (64 rows x stride 132) -> 16B stores
    const float* __restrict__ b1e = b1 + e * H_DIM;
    const int crb = (lane >> 4) * 4, ccol = lane & 15;
    float bias[2];
#pragma unroll
    for (int n = 0; n < 2; ++n) bias[n] = b1e[n0 + wc + n * 16 + ccol];

    __syncthreads();
#pragma unroll
    for (int n = 0; n < 2; ++n)
#pragma unroll
        for (int m = 0; m < 4; ++m)
#pragma unroll
            for (int j = 0; j < 4; ++j) {
                const int rloc = m * 16 + crb + j;
                const int col = wc + n * 16 + ccol;
                smem[rloc * 132 + col] = f2bf(gelu_f(acc[m][n][j] + bias[n]));
            }
    __syncthreads();
#pragma unroll
    for (int i = 0; i < 4; ++i) {
        const int idx = tid + i * 256;
        const int row = idx >> 4, c8 = idx & 15;
        const uint4 val = *(const uint4*)&smem[row * 132 + c8 * 8];
        const int gr = row0 + row;
        if (gr < row_end)
            *(uint4*)&h_ws[(size_t)(hb + gr - row_start) * H_DIM + n0 + c8 * 8] = val;
    }
}

// ================= kernels ==================================================

__global__ __launch_bounds__(256) void fused_gate_w1trans(
    const float* __restrict__ x, const float* __restrict__ gw,
    const float* __restrict__ gb, int* __restrict__ counts,
    int* __restrict__ tok_list, float* __restrict__ prob_list,
    unsigned short* __restrict__ xb,
    const float* __restrict__ w1, unsigned short* __restrict__ w1t)
{
    __shared__ __align__(16) char pool[8448];
    const int bid = (int)blockIdx.x;
    if (bid < GATE_BLKS) {
        gate_body(x, gw, gb, counts, tok_list, prob_list, xb, pool, bid);
    } else {
        int i = bid - GATE_BLKS;
        const int cx = i & 63; i >>= 6;
        const int cy = i & 15; i >>= 4;
        wtrans_body(pool, w1, w1t, D_DIM, H_DIM, cx, cy, i);
    }
}

__global__ __launch_bounds__(256) void gate_kernel(
    const float* __restrict__ x, const float* __restrict__ gw,
    const float* __restrict__ gb, int* __restrict__ counts,
    int* __restrict__ tok_list, float* __restrict__ prob_list,
    unsigned short* __restrict__ xb)
{
    __shared__ __align__(16) char pool[8448];
    gate_body(x, gw, gb, counts, tok_list, prob_list, xb, pool, (int)blockIdx.x);
}

__global__ __launch_bounds__(256) void wtrans_kernel(
    const float* __restrict__ in, unsigned short* __restrict__ out, int R, int C)
{
    __shared__ __align__(16) char pool[8448];
    wtrans_body(pool, in, out, R, C, (int)blockIdx.x, (int)blockIdx.y, (int)blockIdx.z);
}

__global__ __launch_bounds__(256) void fused_fc1_w2trans(
    const unsigned short* __restrict__ xb, const unsigned short* __restrict__ w1t,
    const float* __restrict__ b1, const int* __restrict__ counts,
    const int* __restrict__ tok_list,
    unsigned short* __restrict__ h_ws,
    const float* __restrict__ w2, unsigned short* __restrict__ w2t)
{
    __shared__ __align__(16) char pool[24576];
    const int bid = (int)blockIdx.x;
    if (bid < FC1_BLKS) {
        const int e = bid & 7; const int r = bid >> 3;
        fc1_body(pool, xb, w1t, b1, counts, tok_list, h_ws,
                 e, e, r & 31, r >> 5, 0, NTOK, 1);
    } else {
        int i = bid - FC1_BLKS;
        const int cx = i & 15; i >>= 4;
        const int cy = i & 63; i >>= 6;
        wtrans_body(pool, w2, w2t, H_DIM, D_DIM, cx, cy, i);
    }
}

__global__ __launch_bounds__(256) void expert_fc1(
    const unsigned short* __restrict__ xb, const unsigned short* __restrict__ w1t,
    const float* __restrict__ b1, const int* __restrict__ counts,
    const int* __restrict__ tok_list,
    unsigned short* __restrict__ h_ws,
    int e_param, int we_param, int row_start, int cap, int packed)
{
    __shared__ __align__(16) char pool[24576];
    const int bx = (int)blockIdx.x & 31, by = (int)blockIdx.x >> 5;
    fc1_body(pool, xb, w1t, b1, counts, tok_list, h_ws,
             e_param, we_param, bx, by, row_start, cap, packed);
}

// ---------------- FC2: 64x128 tile, 24KB, split-K=2, atomic combine ---------
// full decode: bx = bid&7 (column-stripe -> XCD); r=bid>>3: by=r&63; r>>=6:
// ks=r&1, e=r>>1.
__global__ __launch_bounds__(256) void expert_fc2(
    const unsigned short* __restrict__ h_ws, const unsigned short* __restrict__ w2t,
    const float* __restrict__ b2, const int* __restrict__ counts,
    const int* __restrict__ tok_list,
    const float* __restrict__ prob_list, float* __restrict__ out,
    int splitk, int e_param, int we_param, int row_start, int cap, int packed)
{
    __shared__ __align__(16) unsigned short As[64 * BK];    // 8 KB
    __shared__ __align__(16) unsigned short Bs[128 * BK];   // 16 KB

    int e, bx, by, ks;
    if (e_param >= 0) { e = e_param; bx = (int)blockIdx.x & 7; by = (int)blockIdx.x >> 3; ks = 0; }
    else { bx = (int)blockIdx.x & 7; int r = (int)blockIdx.x >> 3;
           by = r & 63; r >>= 6; ks = r & 1; e = r >> 1; }

    const int we = (we_param >= 0) ? we_param : e;
    const int cnt = counts[e];
    const int row_end = min(cnt, row_start + cap);
    const int row0 = row_start + by * 64;
    if (row0 >= row_end) return;
    const int n0 = bx * BN;
    const int hb = packed ? packed_base(counts, e) : 0;
    const int tid = threadIdx.x;

    const int kspan = H_DIM / splitk;
    const int k0 = ks * kspan;

    const int wv = tid >> 6, lane = tid & 63;
    const int schunk = (lane & 7) ^ (lane >> 3);
    const unsigned short* __restrict__ w2e = w2t + (size_t)we * D_DIM * H_DIM;

    const unsigned short* aptr[2];
#pragma unroll
    for (int j = 0; j < 2; ++j) {
        const int rloc = (wv * 2 + j) * 8 + (lane >> 3);   // 0..63
        int r = row0 + rloc; if (r >= row_end) r = row_end - 1;
        aptr[j] = h_ws + (size_t)(hb + r - row_start) * H_DIM + k0 + schunk * 8;
    }
    const unsigned short* bptr[4];
#pragma unroll
    for (int j = 0; j < 4; ++j) {
        const int rloc = (wv * 4 + j) * 8 + (lane >> 3);   // 0..127
        bptr[j] = w2e + (size_t)(n0 + rloc) * H_DIM + k0 + schunk * 8;
    }

    const int wc = wv * 32;
    const int rl = lane & 15, x7 = lane & 7, kg = lane >> 4;
    int aoff[2][4], boff[2][2];
#pragma unroll
    for (int s = 0; s < 2; ++s) {
        const int slot = ((((s << 2) + kg) ^ x7) << 3);
#pragma unroll
        for (int m = 0; m < 4; ++m) aoff[s][m] = ((m * 16 + rl) << 6) + slot;
#pragma unroll
        for (int n = 0; n < 2; ++n) boff[s][n] = ((wc + n * 16 + rl) << 6) + slot;
    }

    f32x4 acc[4][2];
#pragma unroll
    for (int m = 0; m < 4; ++m)
#pragma unroll
        for (int n = 0; n < 2; ++n) acc[m][n] = (f32x4){0.f, 0.f, 0.f, 0.f};

    for (int kk = 0; kk < kspan; kk += BK) {
        __syncthreads();
#pragma unroll
        for (int j = 0; j < 2; ++j)
            gload16(aptr[j] + kk, &As[(wv * 2 + j) * 512]);
#pragma unroll
        for (int j = 0; j < 4; ++j)
            gload16(bptr[j] + kk, &Bs[(wv * 4 + j) * 512]);
        __syncthreads();
#pragma unroll
        for (int s = 0; s < 2; ++s) {
            bf16x8 af[4], bfv[2];
#pragma unroll
            for (int m = 0; m < 4; ++m) af[m] = *(const bf16x8*)&As[aoff[s][m]];
#pragma unroll
            for (int n = 0; n < 2; ++n) bfv[n] = *(const bf16x8*)&Bs[boff[s][n]];
#pragma unroll
            for (int m = 0; m < 4; ++m)
#pragma unroll
                for (int n = 0; n < 2; ++n)
                    acc[m][n] = __builtin_amdgcn_mfma_f32_16x16x32_bf16(af[m], bfv[n], acc[m][n], 0, 0, 0);
        }
    }

    const float* __restrict__ b2e = b2 + e * D_DIM;
    const int crb = (lane >> 4) * 4, ccol = lane & 15;
#pragma unroll
    for (int n = 0; n < 2; ++n) {
        const int gc = n0 + wc + n * 16 + ccol;
        const float bias = (ks == 0) ? b2e[gc] : 0.f;
#pragma unroll
        for (int m = 0; m < 4; ++m) {
#pragma unroll
            for (int j = 0; j < 4; ++j) {
                const int gr = row0 + m * 16 + crb + j;
                if (gr < row_end) {
                    const float yv = acc[m][n][j] + bias;
                    const int t = tok_list[e * CAP_E + gr];
                    const float p = prob_list[e * CAP_E + gr];
                    atomicAdd(&out[(size_t)t * D_DIM + gc], p * yv);
                }
            }
        }
    }
}

extern "C" void kernel_launch(void* const* d_in, const int* in_sizes, int n_in,
                              void* d_out, int out_size, void* d_ws, size_t ws_size,
                              hipStream_t stream)
{
    const float* x  = (const float*)d_in[0];
    const float* w1 = (const float*)d_in[1];
    const float* b1 = (const float*)d_in[2];
    const float* w2 = (const float*)d_in[3];
    const float* b2 = (const float*)d_in[4];
    const float* gw = (const float*)d_in[5];
    const float* gb = (const float*)d_in[6];
    float* out = (float*)d_out;

    char* w = (char*)d_ws;
    int*   counts    = (int*)w;
    int*   tok_list  = (int*)(w + 128);
    float* prob_list = (float*)(w + 128 + (size_t)CAP_E * E_NUM * 4);
    size_t off = 128 + 2 * (size_t)CAP_E * E_NUM * 4;
    off = (off + 255) & ~(size_t)255;
    unsigned short* xb = (unsigned short*)(w + off);
    off += (size_t)NTOK * D_DIM * 2;

    const size_t wslab = (size_t)D_DIM * H_DIM * 2;       // bf16 per expert
    const size_t hfull = (size_t)2 * NTOK * H_DIM * 2;    // packed h, bf16
    const size_t need_full = off + 2 * E_NUM * wslab + hfull;

    hipMemsetAsync(d_out, 0, (size_t)out_size * sizeof(float), stream);
    hipMemsetAsync(counts, 0, 64, stream);

    if (ws_size >= need_full) {
        unsigned short* w1t = (unsigned short*)(w + off);
        unsigned short* w2t = (unsigned short*)(w + off + E_NUM * wslab);
        unsigned short* h_ws = (unsigned short*)(w + off + 2 * E_NUM * wslab);

        // A: gate || w1-transpose (independent roles, one launch)
        fused_gate_w1trans<<<GATE_BLKS + W1T_BLKS, 256, 0, stream>>>(
            x, gw, gb, counts, tok_list, prob_list, xb, w1, w1t);
        // B: fc1 || w2-transpose (fc1 reads A's outputs; w2t read only by fc2)
        fused_fc1_w2trans<<<FC1_BLKS + W2T_BLKS, 256, 0, stream>>>(
            xb, w1t, b1, counts, tok_list, h_ws, w2, w2t);
        // C: fc2
        expert_fc2<<<8 * 64 * 2 * 8, 256, 0, stream>>>(
            h_ws, w2t, b2, counts, tok_list, prob_list, out,
            2, -1, -1, 0, NTOK, 1);
    } else {
        // per-expert chunked fallback (atomics)
        gate_kernel<<<GATE_BLKS, 256, 0, stream>>>(x, gw, gb, counts, tok_list, prob_list, xb);
        unsigned short* w1te = (unsigned short*)(w + off);
        unsigned short* w2te = (unsigned short*)(w + off + wslab);
        size_t h_off = off + 2 * wslab;
        unsigned short* h_e = (unsigned short*)(w + h_off);
        size_t h_avail = (ws_size > h_off) ? (ws_size - h_off) / ((size_t)H_DIM * 2) : 0;
        int cap = (int)((h_avail < (size_t)NTOK) ? h_avail : (size_t)NTOK);
        cap = (cap / BM) * BM;
        if (cap < BM) cap = BM;
        const int chunks = (NTOK + cap - 1) / cap;
        for (int e = 0; e < E_NUM; ++e) {
            wtrans_kernel<<<dim3(H_DIM / 64, D_DIM / 64, 1), 256, 0, stream>>>(
                w1 + (size_t)e * D_DIM * H_DIM, w1te, D_DIM, H_DIM);
            wtrans_kernel<<<dim3(D_DIM / 64, H_DIM / 64, 1), 256, 0, stream>>>(
                w2 + (size_t)e * H_DIM * D_DIM, w2te, H_DIM, D_DIM);
            for (int c = 0; c < chunks; ++c) {
                const int rs = c * cap;
                expert_fc1<<<32 * ((cap + 63) / 64), 256, 0, stream>>>(
                    xb, w1te, b1, counts, tok_list, h_e,
                    e, 0, rs, cap, 0);
                expert_fc2<<<8 * ((cap + 63) / 64), 256, 0, stream>>>(
                    h_e, w2te, b2, counts, tok_list, prob_list, out,
                    1, e, 0, rs, cap, 0);
            }
        }
    }
}

// Round 20
// 380.650 us; speedup vs baseline: 1.4704x; 1.0122x over previous
//
#include <hip/hip_runtime.h>
#include <hip/hip_bf16.h>
#include <stdint.h>

#define D_DIM 1024
#define H_DIM 4096
#define E_NUM 8
#define NTOK  4096   // B*S
#define CAP_E 4096
#define BM 128
#define BN 128
#define BK 64        // bf16 elems per K-tile; LDS row = 128 B = 8 chunks of 16 B

#define GATE_BLKS (NTOK / 16)         // 256 (16 tokens per block)
#define W1T_BLKS  (64 * 16 * E_NUM)   // 8192  (H/64 x D/64 x E)
#define FC1_BLKS  (E_NUM * 32 * 64)   // 16384 (e x bx x by)
#define W2T_BLKS  (16 * 64 * E_NUM)   // 8192  (D/64 x H/64 x E)

typedef __bf16 bf16x8 __attribute__((ext_vector_type(8)));
typedef float  f32x4  __attribute__((ext_vector_type(4)));

static __device__ __forceinline__ unsigned short f2bf(float f) {
    union { float f; unsigned u; } v; v.f = f;
    unsigned r = v.u + 0x7fffu + ((v.u >> 16) & 1u);   // RNE
    return (unsigned short)(r >> 16);
}

static __device__ __forceinline__ void gload16(const unsigned short* g, unsigned short* l) {
    __builtin_amdgcn_global_load_lds(
        (const __attribute__((address_space(1))) unsigned int*)g,
        (__attribute__((address_space(3))) unsigned int*)l,
        16, 0, 0);
}

// exact-erf GELU via Abramowitz-Stegun 7.1.26 (|err| <= 1.5e-7)
static __device__ __forceinline__ float gelu_f(float v) {
    const float z = fabsf(v) * 0.70710678118654752f;
    const float t = __builtin_amdgcn_rcpf(__builtin_fmaf(0.3275911f, z, 1.f));
    float p = __builtin_fmaf(1.061405429f, t, -1.453152027f);
    p = __builtin_fmaf(p, t, 1.421413741f);
    p = __builtin_fmaf(p, t, -0.284496736f);
    p = __builtin_fmaf(p, t, 0.254829592f);
    const float e = 1.f - p * t * __expf(-z * z);
    const float erfv = (v < 0.f) ? -e : e;
    return v * (0.5f + 0.5f * erfv);
}

// inline 8-bin exclusive prefix of counts (replaces offsets kernel)
static __device__ __forceinline__ int packed_base(const int* __restrict__ counts, int e) {
    int hb = 0;
#pragma unroll
    for (int i = 0; i < E_NUM; ++i) hb += (i < e) ? counts[i] : 0;
    return hb;
}

// ================= bodies (verified logic, dispatch-agnostic) ===============

// gate: 16 tokens per 256-thread block; LDS histogram -> 8 atomics per block
static __device__ void gate_body(
    const float* __restrict__ x, const float* __restrict__ gw,
    const float* __restrict__ gb, int* __restrict__ counts,
    int* __restrict__ tok_list, float* __restrict__ prob_list,
    unsigned short* __restrict__ xb, char* pool, int bid)
{
    int*   se0  = (int*)pool;          // [16]
    int*   se1  = se0 + 16;            // [16]
    float* sp0  = (float*)(se1 + 16);  // [16]
    float* sp1  = sp0 + 16;            // [16]
    int*   hc   = (int*)(sp1 + 16);    // [8]
    int*   base = hc + 8;              // [8]

    const int wave = threadIdx.x >> 6, lane = threadIdx.x & 63;
#pragma unroll
    for (int g = 0; g < 4; ++g) {
        const int slot = g * 4 + wave;
        const int t = bid * 16 + slot;
        double s[E_NUM];
#pragma unroll
        for (int j = 0; j < E_NUM; ++j) s[j] = 0.0;
        const float* xr = x + (size_t)t * D_DIM;
        unsigned short* xbr = xb + (size_t)t * D_DIM;
#pragma unroll
        for (int i = 0; i < D_DIM / 64; ++i) {
            const int d = i * 64 + lane;
            const float xv = xr[d];
            xbr[d] = f2bf(xv);
            const float4 g0 = *(const float4*)(gw + d * 8);
            const float4 g1 = *(const float4*)(gw + d * 8 + 4);
            s[0] += (double)xv * g0.x; s[1] += (double)xv * g0.y;
            s[2] += (double)xv * g0.z; s[3] += (double)xv * g0.w;
            s[4] += (double)xv * g1.x; s[5] += (double)xv * g1.y;
            s[6] += (double)xv * g1.z; s[7] += (double)xv * g1.w;
        }
#pragma unroll
        for (int off = 32; off >= 1; off >>= 1)
#pragma unroll
            for (int j = 0; j < E_NUM; ++j) s[j] += __shfl_xor(s[j], off, 64);

        if (lane == 0) {
#pragma unroll
            for (int j = 0; j < E_NUM; ++j) s[j] += (double)gb[j];
            int i0 = 0;
            for (int j = 1; j < E_NUM; ++j) if (s[j] > s[i0]) i0 = j;
            int i1 = (i0 == 0) ? 1 : 0;
            for (int j = 0; j < E_NUM; ++j) if (j != i0 && s[j] > s[i1]) i1 = j;
            const double e1 = exp(s[i1] - s[i0]);
            se0[slot] = i0;
            se1[slot] = i1;
            sp0[slot] = (float)(1.0 / (1.0 + e1));
            sp1[slot] = (float)(e1 / (1.0 + e1));
        }
    }
    __syncthreads();
    if (threadIdx.x == 0) {
        int h[E_NUM];
#pragma unroll
        for (int e = 0; e < E_NUM; ++e) h[e] = 0;
        for (int k = 0; k < 16; ++k) { h[se0[k]]++; h[se1[k]]++; }
#pragma unroll
        for (int e = 0; e < E_NUM; ++e) hc[e] = h[e];
    }
    __syncthreads();
    if (threadIdx.x < E_NUM)
        base[threadIdx.x] = atomicAdd(&counts[threadIdx.x], hc[threadIdx.x]);
    __syncthreads();
    if (threadIdx.x == 0) {
        int cur[E_NUM];
#pragma unroll
        for (int e = 0; e < E_NUM; ++e) cur[e] = base[e];
        for (int k = 0; k < 16; ++k) {
            const int t = bid * 16 + k;
            int e = se0[k]; int pos = cur[e]++;
            tok_list[e * CAP_E + pos] = t; prob_list[e * CAP_E + pos] = sp0[k];
            e = se1[k]; pos = cur[e]++;
            tok_list[e * CAP_E + pos] = t; prob_list[e * CAP_E + pos] = sp1[k];
        }
    }
}

// transpose+convert one 64x64 tile: in [R][C] fp32 -> out [C][R] bf16
static __device__ void wtrans_body(
    char* pool, const float* __restrict__ in, unsigned short* __restrict__ out,
    int R, int C, int cx, int cy, int bz)
{
    unsigned (*tile)[33] = (unsigned (*)[33])pool;   // 64x33 = 8448 B
    const size_t slab = (size_t)bz * (size_t)R * C;
    const float* inp = in + slab;
    unsigned short* outp = out + slab;
    const int c0 = cx * 64, r0 = cy * 64;
    const int tid = threadIdx.x;
    const int cq = tid & 15, p0 = tid >> 4;
#pragma unroll
    for (int s = 0; s < 2; ++s) {
        const int p = p0 + s * 16;
        const int r = r0 + 2 * p;
        const int c = c0 + cq * 4;
        const float4 va = *(const float4*)(inp + (size_t)r * C + c);
        const float4 vb = *(const float4*)(inp + (size_t)(r + 1) * C + c);
        const float* fa = (const float*)&va;
        const float* fb = (const float*)&vb;
#pragma unroll
        for (int i = 0; i < 4; ++i)
            tile[cq * 4 + i][p] = (unsigned)f2bf(fa[i]) | ((unsigned)f2bf(fb[i]) << 16);
    }
    __syncthreads();
    const int cl = tid >> 2, q = tid & 3;
#pragma unroll
    for (int s = 0; s < 2; ++s) {
        const int qq = q + s * 4;
        uint4 wv;
        wv.x = tile[cl][qq * 4 + 0]; wv.y = tile[cl][qq * 4 + 1];
        wv.z = tile[cl][qq * 4 + 2]; wv.w = tile[cl][qq * 4 + 3];
        *(uint4*)(outp + (size_t)(c0 + cl) * R + r0 + qq * 8) = wv;
    }
}

// FC1 64x128 tile, 24KB pool, LDS-bounce epilogue
static __device__ void fc1_body(
    char* pool,
    const unsigned short* __restrict__ xb, const unsigned short* __restrict__ w1t,
    const float* __restrict__ b1, const int* __restrict__ counts,
    const int* __restrict__ tok_list,
    unsigned short* __restrict__ h_ws,
    int e, int we, int bx, int by, int row_start, int cap, int packed)
{
    unsigned short* smem = (unsigned short*)pool;   // 12288 shorts
    unsigned short* As = smem;                      // [64][64]
    unsigned short* Bs = smem + 4096;               // [128][64]

    const int cnt = counts[e];
    const int row_end = min(cnt, row_start + cap);
    const int row0 = row_start + by * 64;
    if (row0 >= row_end) return;
    const int n0 = bx * BN;
    const int hb = packed ? packed_base(counts, e) : 0;
    const int tid = threadIdx.x;

    const int wv = tid >> 6, lane = tid & 63;
    const int schunk = (lane & 7) ^ (lane >> 3);
    const unsigned short* __restrict__ w1e = w1t + (size_t)we * H_DIM * D_DIM;

    const unsigned short* aptr[2];
#pragma unroll
    for (int j = 0; j < 2; ++j) {
        const int rloc = (wv * 2 + j) * 8 + (lane >> 3);   // 0..63
        const int rr = min(row0 + rloc, row_end - 1);
        aptr[j] = xb + (size_t)tok_list[e * CAP_E + rr] * D_DIM + schunk * 8;
    }
    const unsigned short* bptr[4];
#pragma unroll
    for (int j = 0; j < 4; ++j) {
        const int rloc = (wv * 4 + j) * 8 + (lane >> 3);   // 0..127
        bptr[j] = w1e + (size_t)(n0 + rloc) * D_DIM + schunk * 8;
    }

    const int wc = wv * 32;
    const int rl = lane & 15, x7 = lane & 7, kg = lane >> 4;
    int aoff[2][4], boff[2][2];
#pragma unroll
    for (int s = 0; s < 2; ++s) {
        const int slot = ((((s << 2) + kg) ^ x7) << 3);
#pragma unroll
        for (int m = 0; m < 4; ++m) aoff[s][m] = ((m * 16 + rl) << 6) + slot;
#pragma unroll
        for (int n = 0; n < 2; ++n) boff[s][n] = ((wc + n * 16 + rl) << 6) + slot;
    }

    f32x4 acc[4][2];
#pragma unroll
    for (int m = 0; m < 4; ++m)
#pragma unroll
        for (int n = 0; n < 2; ++n) acc[m][n] = (f32x4){0.f, 0.f, 0.f, 0.f};

    for (int kk = 0; kk < D_DIM; kk += BK) {
        __syncthreads();
#pragma unroll
        for (int j = 0; j < 2; ++j)
            gload16(aptr[j] + kk, &As[(wv * 2 + j) * 512]);
#pragma unroll
        for (int j = 0; j < 4; ++j)
            gload16(bptr[j] + kk, &Bs[(wv * 4 + j) * 512]);
        __syncthreads();
#pragma unroll
        for (int s = 0; s < 2; ++s) {
            bf16x8 af[4], bfv[2];
#pragma unroll
            for (int m = 0; m < 4; ++m) af[m] = *(const bf16x8*)&As[aoff[s][m]];
#pragma unroll
            for (int n = 0; n < 2; ++n) bfv[n] = *(const bf16x8*)&Bs[boff[s][n]];
#pragma unroll
            for (int m = 0; m < 4; ++m)
#pragma unroll
                for (int n = 0; n < 2; ++n)
                    acc[m][n] = __builtin_amdgcn_mfma_f32_16x16x32_bf16(af[m], bfv[n], acc[m][n], 0, 0, 0);
        }
    }

    // epilogue: GELU + bias, LDS-bounce (64 rows x stride 132) -> 16B stores
    const float* __restrict__ b1e = b1 + e * H_DIM;
    const int crb = (lane >> 4) * 4, ccol = lane & 15;
    float bias[2];
#pragma unroll
    for (int n = 0; n < 2; ++n) bias[n] = b1e[n0 + wc + n * 16 + ccol];

    __syncthreads();
#pragma unroll
    for (int n = 0; n < 2; ++n)
#pragma unroll
        for (int m = 0; m < 4; ++m)
#pragma unroll
            for (int j = 0; j < 4; ++j) {
                const int rloc = m * 16 + crb + j;
                const int col = wc + n * 16 + ccol;
                smem[rloc * 132 + col] = f2bf(gelu_f(acc[m][n][j] + bias[n]));
            }
    __syncthreads();
#pragma unroll
    for (int i = 0; i < 4; ++i) {
        const int idx = tid + i * 256;
        const int row = idx >> 4, c8 = idx & 15;
        const uint4 val = *(const uint4*)&smem[row * 132 + c8 * 8];
        const int gr = row0 + row;
        if (gr < row_end)
            *(uint4*)&h_ws[(size_t)(hb + gr - row_start) * H_DIM + n0 + c8 * 8] = val;
    }
}

// ================= kernels ==================================================

__global__ __launch_bounds__(256) void fused_gate_w1trans(
    const float* __restrict__ x, const float* __restrict__ gw,
    const float* __restrict__ gb, int* __restrict__ counts,
    int* __restrict__ tok_list, float* __restrict__ prob_list,
    unsigned short* __restrict__ xb,
    const float* __restrict__ w1, unsigned short* __restrict__ w1t)
{
    __shared__ __align__(16) char pool[8448];
    const int bid = (int)blockIdx.x;
    if (bid < GATE_BLKS) {
        gate_body(x, gw, gb, counts, tok_list, prob_list, xb, pool, bid);
    } else {
        int i = bid - GATE_BLKS;
        const int cx = i & 63; i >>= 6;
        const int cy = i & 15; i >>= 4;
        wtrans_body(pool, w1, w1t, D_DIM, H_DIM, cx, cy, i);
    }
}

__global__ __launch_bounds__(256) void gate_kernel(
    const float* __restrict__ x, const float* __restrict__ gw,
    const float* __restrict__ gb, int* __restrict__ counts,
    int* __restrict__ tok_list, float* __restrict__ prob_list,
    unsigned short* __restrict__ xb)
{
    __shared__ __align__(16) char pool[8448];
    gate_body(x, gw, gb, counts, tok_list, prob_list, xb, pool, (int)blockIdx.x);
}

__global__ __launch_bounds__(256) void wtrans_kernel(
    const float* __restrict__ in, unsigned short* __restrict__ out, int R, int C)
{
    __shared__ __align__(16) char pool[8448];
    wtrans_body(pool, in, out, R, C, (int)blockIdx.x, (int)blockIdx.y, (int)blockIdx.z);
}

__global__ __launch_bounds__(256) void fused_fc1_w2trans(
    const unsigned short* __restrict__ xb, const unsigned short* __restrict__ w1t,
    const float* __restrict__ b1, const int* __restrict__ counts,
    const int* __restrict__ tok_list,
    unsigned short* __restrict__ h_ws,
    const float* __restrict__ w2, unsigned short* __restrict__ w2t)
{
    __shared__ __align__(16) char pool[24576];
    const int bid = (int)blockIdx.x;
    if (bid < FC1_BLKS) {
        const int e = bid & 7; const int r = bid >> 3;
        fc1_body(pool, xb, w1t, b1, counts, tok_list, h_ws,
                 e, e, r & 31, r >> 5, 0, NTOK, 1);
    } else {
        int i = bid - FC1_BLKS;
        const int cx = i & 15; i >>= 4;
        const int cy = i & 63; i >>= 6;
        wtrans_body(pool, w2, w2t, H_DIM, D_DIM, cx, cy, i);
    }
}

__global__ __launch_bounds__(256) void expert_fc1(
    const unsigned short* __restrict__ xb, const unsigned short* __restrict__ w1t,
    const float* __restrict__ b1, const int* __restrict__ counts,
    const int* __restrict__ tok_list,
    unsigned short* __restrict__ h_ws,
    int e_param, int we_param, int row_start, int cap, int packed)
{
    __shared__ __align__(16) char pool[24576];
    const int bx = (int)blockIdx.x & 31, by = (int)blockIdx.x >> 5;
    fc1_body(pool, xb, w1t, b1, counts, tok_list, h_ws,
             e_param, we_param, bx, by, row_start, cap, packed);
}

// ---------------- FC2: 64x128 tile, 24KB, split-K=2, atomic combine ---------
// full decode (expert->XCD pinned): e = bid&7; r=bid>>3: bx=r&7; r>>=3:
// by=r&63; ks=r>>6.  Per-XCD working set ~17 MB (h slice + w2t stripe).
__global__ __launch_bounds__(256) void expert_fc2(
    const unsigned short* __restrict__ h_ws, const unsigned short* __restrict__ w2t,
    const float* __restrict__ b2, const int* __restrict__ counts,
    const int* __restrict__ tok_list,
    const float* __restrict__ prob_list, float* __restrict__ out,
    int splitk, int e_param, int we_param, int row_start, int cap, int packed)
{
    __shared__ __align__(16) unsigned short As[64 * BK];    // 8 KB
    __shared__ __align__(16) unsigned short Bs[128 * BK];   // 16 KB

    int e, bx, by, ks;
    if (e_param >= 0) { e = e_param; bx = (int)blockIdx.x & 7; by = (int)blockIdx.x >> 3; ks = 0; }
    else { e = (int)blockIdx.x & 7; int r = (int)blockIdx.x >> 3;
           bx = r & 7; r >>= 3; by = r & 63; ks = r >> 6; }

    const int we = (we_param >= 0) ? we_param : e;
    const int cnt = counts[e];
    const int row_end = min(cnt, row_start + cap);
    const int row0 = row_start + by * 64;
    if (row0 >= row_end) return;
    const int n0 = bx * BN;
    const int hb = packed ? packed_base(counts, e) : 0;
    const int tid = threadIdx.x;

    const int kspan = H_DIM / splitk;
    const int k0 = ks * kspan;

    const int wv = tid >> 6, lane = tid & 63;
    const int schunk = (lane & 7) ^ (lane >> 3);
    const unsigned short* __restrict__ w2e = w2t + (size_t)we * D_DIM * H_DIM;

    const unsigned short* aptr[2];
#pragma unroll
    for (int j = 0; j < 2; ++j) {
        const int rloc = (wv * 2 + j) * 8 + (lane >> 3);   // 0..63
        int r = row0 + rloc; if (r >= row_end) r = row_end - 1;
        aptr[j] = h_ws + (size_t)(hb + r - row_start) * H_DIM + k0 + schunk * 8;
    }
    const unsigned short* bptr[4];
#pragma unroll
    for (int j = 0; j < 4; ++j) {
        const int rloc = (wv * 4 + j) * 8 + (lane >> 3);   // 0..127
        bptr[j] = w2e + (size_t)(n0 + rloc) * H_DIM + k0 + schunk * 8;
    }

    const int wc = wv * 32;
    const int rl = lane & 15, x7 = lane & 7, kg = lane >> 4;
    int aoff[2][4], boff[2][2];
#pragma unroll
    for (int s = 0; s < 2; ++s) {
        const int slot = ((((s << 2) + kg) ^ x7) << 3);
#pragma unroll
        for (int m = 0; m < 4; ++m) aoff[s][m] = ((m * 16 + rl) << 6) + slot;
#pragma unroll
        for (int n = 0; n < 2; ++n) boff[s][n] = ((wc + n * 16 + rl) << 6) + slot;
    }

    f32x4 acc[4][2];
#pragma unroll
    for (int m = 0; m < 4; ++m)
#pragma unroll
        for (int n = 0; n < 2; ++n) acc[m][n] = (f32x4){0.f, 0.f, 0.f, 0.f};

    for (int kk = 0; kk < kspan; kk += BK) {
        __syncthreads();
#pragma unroll
        for (int j = 0; j < 2; ++j)
            gload16(aptr[j] + kk, &As[(wv * 2 + j) * 512]);
#pragma unroll
        for (int j = 0; j < 4; ++j)
            gload16(bptr[j] + kk, &Bs[(wv * 4 + j) * 512]);
        __syncthreads();
#pragma unroll
        for (int s = 0; s < 2; ++s) {
            bf16x8 af[4], bfv[2];
#pragma unroll
            for (int m = 0; m < 4; ++m) af[m] = *(const bf16x8*)&As[aoff[s][m]];
#pragma unroll
            for (int n = 0; n < 2; ++n) bfv[n] = *(const bf16x8*)&Bs[boff[s][n]];
#pragma unroll
            for (int m = 0; m < 4; ++m)
#pragma unroll
                for (int n = 0; n < 2; ++n)
                    acc[m][n] = __builtin_amdgcn_mfma_f32_16x16x32_bf16(af[m], bfv[n], acc[m][n], 0, 0, 0);
        }
    }

    const float* __restrict__ b2e = b2 + e * D_DIM;
    const int crb = (lane >> 4) * 4, ccol = lane & 15;
#pragma unroll
    for (int n = 0; n < 2; ++n) {
        const int gc = n0 + wc + n * 16 + ccol;
        const float bias = (ks == 0) ? b2e[gc] : 0.f;
#pragma unroll
        for (int m = 0; m < 4; ++m) {
#pragma unroll
            for (int j = 0; j < 4; ++j) {
                const int gr = row0 + m * 16 + crb + j;
                if (gr < row_end) {
                    const float yv = acc[m][n][j] + bias;
                    const int t = tok_list[e * CAP_E + gr];
                    const float p = prob_list[e * CAP_E + gr];
                    atomicAdd(&out[(size_t)t * D_DIM + gc], p * yv);
                }
            }
        }
    }
}

extern "C" void kernel_launch(void* const* d_in, const int* in_sizes, int n_in,
                              void* d_out, int out_size, void* d_ws, size_t ws_size,
                              hipStream_t stream)
{
    const float* x  = (const float*)d_in[0];
    const float* w1 = (const float*)d_in[1];
    const float* b1 = (const float*)d_in[2];
    const float* w2 = (const float*)d_in[3];
    const float* b2 = (const float*)d_in[4];
    const float* gw = (const float*)d_in[5];
    const float* gb = (const float*)d_in[6];
    float* out = (float*)d_out;

    char* w = (char*)d_ws;
    int*   counts    = (int*)w;
    int*   tok_list  = (int*)(w + 128);
    float* prob_list = (float*)(w + 128 + (size_t)CAP_E * E_NUM * 4);
    size_t off = 128 + 2 * (size_t)CAP_E * E_NUM * 4;
    off = (off + 255) & ~(size_t)255;
    unsigned short* xb = (unsigned short*)(w + off);
    off += (size_t)NTOK * D_DIM * 2;

    const size_t wslab = (size_t)D_DIM * H_DIM * 2;       // bf16 per expert
    const size_t hfull = (size_t)2 * NTOK * H_DIM * 2;    // packed h, bf16
    const size_t need_full = off + 2 * E_NUM * wslab + hfull;

    hipMemsetAsync(d_out, 0, (size_t)out_size * sizeof(float), stream);
    hipMemsetAsync(counts, 0, 64, stream);

    if (ws_size >= need_full) {
        unsigned short* w1t = (unsigned short*)(w + off);
        unsigned short* w2t = (unsigned short*)(w + off + E_NUM * wslab);
        unsigned short* h_ws = (unsigned short*)(w + off + 2 * E_NUM * wslab);

        // A: gate || w1-transpose (independent roles, one launch)
        fused_gate_w1trans<<<GATE_BLKS + W1T_BLKS, 256, 0, stream>>>(
            x, gw, gb, counts, tok_list, prob_list, xb, w1, w1t);
        // B: fc1 || w2-transpose (fc1 reads A's outputs; w2t read only by fc2)
        fused_fc1_w2trans<<<FC1_BLKS + W2T_BLKS, 256, 0, stream>>>(
            xb, w1t, b1, counts, tok_list, h_ws, w2, w2t);
        // C: fc2 (expert->XCD pinned decode)
        expert_fc2<<<8 * 8 * 64 * 2, 256, 0, stream>>>(
            h_ws, w2t, b2, counts, tok_list, prob_list, out,
            2, -1, -1, 0, NTOK, 1);
    } else {
        // per-expert chunked fallback (atomics)
        gate_kernel<<<GATE_BLKS, 256, 0, stream>>>(x, gw, gb, counts, tok_list, prob_list, xb);
        unsigned short* w1te = (unsigned short*)(w + off);
        unsigned short* w2te = (unsigned short*)(w + off + wslab);
        size_t h_off = off + 2 * wslab;
        unsigned short* h_e = (unsigned short*)(w + h_off);
        size_t h_avail = (ws_size > h_off) ? (ws_size - h_off) / ((size_t)H_DIM * 2) : 0;
        int cap = (int)((h_avail < (size_t)NTOK) ? h_avail : (size_t)NTOK);
        cap = (cap / BM) * BM;
        if (cap < BM) cap = BM;
        const int chunks = (NTOK + cap - 1) / cap;
        for (int e = 0; e < E_NUM; ++e) {
            wtrans_kernel<<<dim3(H_DIM / 64, D_DIM / 64, 1), 256, 0, stream>>>(
                w1 + (size_t)e * D_DIM * H_DIM, w1te, D_DIM, H_DIM);
            wtrans_kernel<<<dim3(D_DIM / 64, H_DIM / 64, 1), 256, 0, stream>>>(
                w2 + (size_t)e * H_DIM * D_DIM, w2te, H_DIM, D_DIM);
            for (int c = 0; c < chunks; ++c) {
                const int rs = c * cap;
                expert_fc1<<<32 * ((cap + 63) / 64), 256, 0, stream>>>(
                    xb, w1te, b1, counts, tok_list, h_e,
                    e, 0, rs, cap, 0);
                expert_fc2<<<8 * ((cap + 63) / 64), 256, 0, stream>>>(
                    h_e, w2te, b2, counts, tok_list, prob_list, out,
                    1, e, 0, rs, cap, 0);
            }
        }
    }
}

// Round 21
// 378.317 us; speedup vs baseline: 1.4795x; 1.0062x over previous
//
#include <hip/hip_runtime.h>
#include <hip/hip_bf16.h>
#include <stdint.h>

#define D_DIM 1024
#define H_DIM 4096
#define E_NUM 8
#define NTOK  4096   // B*S
#define CAP_E 4096
#define BM 128
#define BN 128
#define BK 64        // bf16 elems per K-tile; LDS row = 128 B = 8 chunks of 16 B

#define GATE_BLKS (NTOK / 16)         // 256 (16 tokens per block)
#define W1T_BLKS  (64 * 16 * E_NUM)   // 8192  (H/64 x D/64 x E)
#define ZERO_BLKS (NTOK * D_DIM / 4096) // 1024 (zero d_out, 16 KB/block)
#define FC1_BLKS  (E_NUM * 32 * 64)   // 16384 (e x bx x by)
#define W2T_BLKS  (16 * 64 * E_NUM)   // 8192  (D/64 x H/64 x E)

typedef __bf16 bf16x8 __attribute__((ext_vector_type(8)));
typedef float  f32x4  __attribute__((ext_vector_type(4)));

static __device__ __forceinline__ unsigned short f2bf(float f) {
    union { float f; unsigned u; } v; v.f = f;
    unsigned r = v.u + 0x7fffu + ((v.u >> 16) & 1u);   // RNE
    return (unsigned short)(r >> 16);
}

static __device__ __forceinline__ void gload16(const unsigned short* g, unsigned short* l) {
    __builtin_amdgcn_global_load_lds(
        (const __attribute__((address_space(1))) unsigned int*)g,
        (__attribute__((address_space(3))) unsigned int*)l,
        16, 0, 0);
}

// exact-erf GELU via Abramowitz-Stegun 7.1.26 (|err| <= 1.5e-7)
static __device__ __forceinline__ float gelu_f(float v) {
    const float z = fabsf(v) * 0.70710678118654752f;
    const float t = __builtin_amdgcn_rcpf(__builtin_fmaf(0.3275911f, z, 1.f));
    float p = __builtin_fmaf(1.061405429f, t, -1.453152027f);
    p = __builtin_fmaf(p, t, 1.421413741f);
    p = __builtin_fmaf(p, t, -0.284496736f);
    p = __builtin_fmaf(p, t, 0.254829592f);
    const float e = 1.f - p * t * __expf(-z * z);
    const float erfv = (v < 0.f) ? -e : e;
    return v * (0.5f + 0.5f * erfv);
}

// inline 8-bin exclusive prefix of counts (replaces offsets kernel)
static __device__ __forceinline__ int packed_base(const int* __restrict__ counts, int e) {
    int hb = 0;
#pragma unroll
    for (int i = 0; i < E_NUM; ++i) hb += (i < e) ? counts[i] : 0;
    return hb;
}

// ================= bodies (verified logic, dispatch-agnostic) ===============

// gate: 16 tokens per 256-thread block; LDS histogram -> 8 atomics per block
static __device__ void gate_body(
    const float* __restrict__ x, const float* __restrict__ gw,
    const float* __restrict__ gb, int* __restrict__ counts,
    int* __restrict__ tok_list, float* __restrict__ prob_list,
    unsigned short* __restrict__ xb, char* pool, int bid)
{
    int*   se0  = (int*)pool;          // [16]
    int*   se1  = se0 + 16;            // [16]
    float* sp0  = (float*)(se1 + 16);  // [16]
    float* sp1  = sp0 + 16;            // [16]
    int*   hc   = (int*)(sp1 + 16);    // [8]
    int*   base = hc + 8;              // [8]

    const int wave = threadIdx.x >> 6, lane = threadIdx.x & 63;
#pragma unroll
    for (int g = 0; g < 4; ++g) {
        const int slot = g * 4 + wave;
        const int t = bid * 16 + slot;
        double s[E_NUM];
#pragma unroll
        for (int j = 0; j < E_NUM; ++j) s[j] = 0.0;
        const float* xr = x + (size_t)t * D_DIM;
        unsigned short* xbr = xb + (size_t)t * D_DIM;
#pragma unroll
        for (int i = 0; i < D_DIM / 64; ++i) {
            const int d = i * 64 + lane;
            const float xv = xr[d];
            xbr[d] = f2bf(xv);
            const float4 g0 = *(const float4*)(gw + d * 8);
            const float4 g1 = *(const float4*)(gw + d * 8 + 4);
            s[0] += (double)xv * g0.x; s[1] += (double)xv * g0.y;
            s[2] += (double)xv * g0.z; s[3] += (double)xv * g0.w;
            s[4] += (double)xv * g1.x; s[5] += (double)xv * g1.y;
            s[6] += (double)xv * g1.z; s[7] += (double)xv * g1.w;
        }
#pragma unroll
        for (int off = 32; off >= 1; off >>= 1)
#pragma unroll
            for (int j = 0; j < E_NUM; ++j) s[j] += __shfl_xor(s[j], off, 64);

        if (lane == 0) {
#pragma unroll
            for (int j = 0; j < E_NUM; ++j) s[j] += (double)gb[j];
            int i0 = 0;
            for (int j = 1; j < E_NUM; ++j) if (s[j] > s[i0]) i0 = j;
            int i1 = (i0 == 0) ? 1 : 0;
            for (int j = 0; j < E_NUM; ++j) if (j != i0 && s[j] > s[i1]) i1 = j;
            const double e1 = exp(s[i1] - s[i0]);
            se0[slot] = i0;
            se1[slot] = i1;
            sp0[slot] = (float)(1.0 / (1.0 + e1));
            sp1[slot] = (float)(e1 / (1.0 + e1));
        }
    }
    __syncthreads();
    if (threadIdx.x == 0) {
        int h[E_NUM];
#pragma unroll
        for (int e = 0; e < E_NUM; ++e) h[e] = 0;
        for (int k = 0; k < 16; ++k) { h[se0[k]]++; h[se1[k]]++; }
#pragma unroll
        for (int e = 0; e < E_NUM; ++e) hc[e] = h[e];
    }
    __syncthreads();
    if (threadIdx.x < E_NUM)
        base[threadIdx.x] = atomicAdd(&counts[threadIdx.x], hc[threadIdx.x]);
    __syncthreads();
    if (threadIdx.x == 0) {
        int cur[E_NUM];
#pragma unroll
        for (int e = 0; e < E_NUM; ++e) cur[e] = base[e];
        for (int k = 0; k < 16; ++k) {
            const int t = bid * 16 + k;
            int e = se0[k]; int pos = cur[e]++;
            tok_list[e * CAP_E + pos] = t; prob_list[e * CAP_E + pos] = sp0[k];
            e = se1[k]; pos = cur[e]++;
            tok_list[e * CAP_E + pos] = t; prob_list[e * CAP_E + pos] = sp1[k];
        }
    }
}

// transpose+convert one 64x64 tile: in [R][C] fp32 -> out [C][R] bf16
static __device__ void wtrans_body(
    char* pool, const float* __restrict__ in, unsigned short* __restrict__ out,
    int R, int C, int cx, int cy, int bz)
{
    unsigned (*tile)[33] = (unsigned (*)[33])pool;   // 64x33 = 8448 B
    const size_t slab = (size_t)bz * (size_t)R * C;
    const float* inp = in + slab;
    unsigned short* outp = out + slab;
    const int c0 = cx * 64, r0 = cy * 64;
    const int tid = threadIdx.x;
    const int cq = tid & 15, p0 = tid >> 4;
#pragma unroll
    for (int s = 0; s < 2; ++s) {
        const int p = p0 + s * 16;
        const int r = r0 + 2 * p;
        const int c = c0 + cq * 4;
        const float4 va = *(const float4*)(inp + (size_t)r * C + c);
        const float4 vb = *(const float4*)(inp + (size_t)(r + 1) * C + c);
        const float* fa = (const float*)&va;
        const float* fb = (const float*)&vb;
#pragma unroll
        for (int i = 0; i < 4; ++i)
            tile[cq * 4 + i][p] = (unsigned)f2bf(fa[i]) | ((unsigned)f2bf(fb[i]) << 16);
    }
    __syncthreads();
    const int cl = tid >> 2, q = tid & 3;
#pragma unroll
    for (int s = 0; s < 2; ++s) {
        const int qq = q + s * 4;
        uint4 wv;
        wv.x = tile[cl][qq * 4 + 0]; wv.y = tile[cl][qq * 4 + 1];
        wv.z = tile[cl][qq * 4 + 2]; wv.w = tile[cl][qq * 4 + 3];
        *(uint4*)(outp + (size_t)(c0 + cl) * R + r0 + qq * 8) = wv;
    }
}

// FC1 64x128 tile, 24KB pool, LDS-bounce epilogue
static __device__ void fc1_body(
    char* pool,
    const unsigned short* __restrict__ xb, const unsigned short* __restrict__ w1t,
    const float* __restrict__ b1, const int* __restrict__ counts,
    const int* __restrict__ tok_list,
    unsigned short* __restrict__ h_ws,
    int e, int we, int bx, int by, int row_start, int cap, int packed)
{
    unsigned short* smem = (unsigned short*)pool;   // 12288 shorts
    unsigned short* As = smem;                      // [64][64]
    unsigned short* Bs = smem + 4096;               // [128][64]

    const int cnt = counts[e];
    const int row_end = min(cnt, row_start + cap);
    const int row0 = row_start + by * 64;
    if (row0 >= row_end) return;
    const int n0 = bx * BN;
    const int hb = packed ? packed_base(counts, e) : 0;
    const int tid = threadIdx.x;

    const int wv = tid >> 6, lane = tid & 63;
    const int schunk = (lane & 7) ^ (lane >> 3);
    const unsigned short* __restrict__ w1e = w1t + (size_t)we * H_DIM * D_DIM;

    const unsigned short* aptr[2];
#pragma unroll
    for (int j = 0; j < 2; ++j) {
        const int rloc = (wv * 2 + j) * 8 + (lane >> 3);   // 0..63
        const int rr = min(row0 + rloc, row_end - 1);
        aptr[j] = xb + (size_t)tok_list[e * CAP_E + rr] * D_DIM + schunk * 8;
    }
    const unsigned short* bptr[4];
#pragma unroll
    for (int j = 0; j < 4; ++j) {
        const int rloc = (wv * 4 + j) * 8 + (lane >> 3);   // 0..127
        bptr[j] = w1e + (size_t)(n0 + rloc) * D_DIM + schunk * 8;
    }

    const int wc = wv * 32;
    const int rl = lane & 15, x7 = lane & 7, kg = lane >> 4;
    int aoff[2][4], boff[2][2];
#pragma unroll
    for (int s = 0; s < 2; ++s) {
        const int slot = ((((s << 2) + kg) ^ x7) << 3);
#pragma unroll
        for (int m = 0; m < 4; ++m) aoff[s][m] = ((m * 16 + rl) << 6) + slot;
#pragma unroll
        for (int n = 0; n < 2; ++n) boff[s][n] = ((wc + n * 16 + rl) << 6) + slot;
    }

    f32x4 acc[4][2];
#pragma unroll
    for (int m = 0; m < 4; ++m)
#pragma unroll
        for (int n = 0; n < 2; ++n) acc[m][n] = (f32x4){0.f, 0.f, 0.f, 0.f};

    for (int kk = 0; kk < D_DIM; kk += BK) {
        __syncthreads();
#pragma unroll
        for (int j = 0; j < 2; ++j)
            gload16(aptr[j] + kk, &As[(wv * 2 + j) * 512]);
#pragma unroll
        for (int j = 0; j < 4; ++j)
            gload16(bptr[j] + kk, &Bs[(wv * 4 + j) * 512]);
        __syncthreads();
#pragma unroll
        for (int s = 0; s < 2; ++s) {
            bf16x8 af[4], bfv[2];
#pragma unroll
            for (int m = 0; m < 4; ++m) af[m] = *(const bf16x8*)&As[aoff[s][m]];
#pragma unroll
            for (int n = 0; n < 2; ++n) bfv[n] = *(const bf16x8*)&Bs[boff[s][n]];
#pragma unroll
            for (int m = 0; m < 4; ++m)
#pragma unroll
                for (int n = 0; n < 2; ++n)
                    acc[m][n] = __builtin_amdgcn_mfma_f32_16x16x32_bf16(af[m], bfv[n], acc[m][n], 0, 0, 0);
        }
    }

    // epilogue: GELU + bias, LDS-bounce (64 rows x stride 132) -> 16B stores
    const float* __restrict__ b1e = b1 + e * H_DIM;
    const int crb = (lane >> 4) * 4, ccol = lane & 15;
    float bias[2];
#pragma unroll
    for (int n = 0; n < 2; ++n) bias[n] = b1e[n0 + wc + n * 16 + ccol];

    __syncthreads();
#pragma unroll
    for (int n = 0; n < 2; ++n)
#pragma unroll
        for (int m = 0; m < 4; ++m)
#pragma unroll
            for (int j = 0; j < 4; ++j) {
                const int rloc = m * 16 + crb + j;
                const int col = wc + n * 16 + ccol;
                smem[rloc * 132 + col] = f2bf(gelu_f(acc[m][n][j] + bias[n]));
            }
    __syncthreads();
#pragma unroll
    for (int i = 0; i < 4; ++i) {
        const int idx = tid + i * 256;
        const int row = idx >> 4, c8 = idx & 15;
        const uint4 val = *(const uint4*)&smem[row * 132 + c8 * 8];
        const int gr = row0 + row;
        if (gr < row_end)
            *(uint4*)&h_ws[(size_t)(hb + gr - row_start) * H_DIM + n0 + c8 * 8] = val;
    }
}

// ================= kernels ==================================================

__global__ __launch_bounds__(256) void fused_gate_w1trans(
    const float* __restrict__ x, const float* __restrict__ gw,
    const float* __restrict__ gb, int* __restrict__ counts,
    int* __restrict__ tok_list, float* __restrict__ prob_list,
    unsigned short* __restrict__ xb,
    const float* __restrict__ w1, unsigned short* __restrict__ w1t,
    float* __restrict__ out_zero)
{
    __shared__ __align__(16) char pool[8448];
    const int bid = (int)blockIdx.x;
    if (bid < GATE_BLKS) {
        gate_body(x, gw, gb, counts, tok_list, prob_list, xb, pool, bid);
    } else if (bid < GATE_BLKS + W1T_BLKS) {
        int i = bid - GATE_BLKS;
        const int cx = i & 63; i >>= 6;
        const int cy = i & 15; i >>= 4;
        wtrans_body(pool, w1, w1t, D_DIM, H_DIM, cx, cy, i);
    } else {
        // zero d_out: 4096 floats per block, float4 stores
        const int i = bid - GATE_BLKS - W1T_BLKS;
        float* base = out_zero + (size_t)i * 4096;
        const f32x4 z = (f32x4){0.f, 0.f, 0.f, 0.f};
#pragma unroll
        for (int it = 0; it < 4; ++it)
            *(f32x4*)(base + (it * 256 + (int)threadIdx.x) * 4) = z;
    }
}

__global__ __launch_bounds__(256) void gate_kernel(
    const float* __restrict__ x, const float* __restrict__ gw,
    const float* __restrict__ gb, int* __restrict__ counts,
    int* __restrict__ tok_list, float* __restrict__ prob_list,
    unsigned short* __restrict__ xb)
{
    __shared__ __align__(16) char pool[8448];
    gate_body(x, gw, gb, counts, tok_list, prob_list, xb, pool, (int)blockIdx.x);
}

__global__ __launch_bounds__(256) void wtrans_kernel(
    const float* __restrict__ in, unsigned short* __restrict__ out, int R, int C)
{
    __shared__ __align__(16) char pool[8448];
    wtrans_body(pool, in, out, R, C, (int)blockIdx.x, (int)blockIdx.y, (int)blockIdx.z);
}

__global__ __launch_bounds__(256) void fused_fc1_w2trans(
    const unsigned short* __restrict__ xb, const unsigned short* __restrict__ w1t,
    const float* __restrict__ b1, const int* __restrict__ counts,
    const int* __restrict__ tok_list,
    unsigned short* __restrict__ h_ws,
    const float* __restrict__ w2, unsigned short* __restrict__ w2t)
{
    __shared__ __align__(16) char pool[24576];
    const int bid = (int)blockIdx.x;
    if (bid < FC1_BLKS) {
        const int e = bid & 7; const int r = bid >> 3;
        fc1_body(pool, xb, w1t, b1, counts, tok_list, h_ws,
                 e, e, r & 31, r >> 5, 0, NTOK, 1);
    } else {
        int i = bid - FC1_BLKS;
        const int cx = i & 15; i >>= 4;
        const int cy = i & 63; i >>= 6;
        wtrans_body(pool, w2, w2t, H_DIM, D_DIM, cx, cy, i);
    }
}

__global__ __launch_bounds__(256) void expert_fc1(
    const unsigned short* __restrict__ xb, const unsigned short* __restrict__ w1t,
    const float* __restrict__ b1, const int* __restrict__ counts,
    const int* __restrict__ tok_list,
    unsigned short* __restrict__ h_ws,
    int e_param, int we_param, int row_start, int cap, int packed)
{
    __shared__ __align__(16) char pool[24576];
    const int bx = (int)blockIdx.x & 31, by = (int)blockIdx.x >> 5;
    fc1_body(pool, xb, w1t, b1, counts, tok_list, h_ws,
             e_param, we_param, bx, by, row_start, cap, packed);
}

// ---------------- FC2: 64x128 tile, 24KB, split-K=2, atomic combine ---------
// full decode (expert->XCD pinned): e = bid&7; r=bid>>3: bx=r&7; r>>=3:
// by=r&63; ks=r>>6.  Per-XCD working set ~17 MB (h slice + w2t stripe).
__global__ __launch_bounds__(256) void expert_fc2(
    const unsigned short* __restrict__ h_ws, const unsigned short* __restrict__ w2t,
    const float* __restrict__ b2, const int* __restrict__ counts,
    const int* __restrict__ tok_list,
    const float* __restrict__ prob_list, float* __restrict__ out,
    int splitk, int e_param, int we_param, int row_start, int cap, int packed)
{
    __shared__ __align__(16) unsigned short As[64 * BK];    // 8 KB
    __shared__ __align__(16) unsigned short Bs[128 * BK];   // 16 KB

    int e, bx, by, ks;
    if (e_param >= 0) { e = e_param; bx = (int)blockIdx.x & 7; by = (int)blockIdx.x >> 3; ks = 0; }
    else { e = (int)blockIdx.x & 7; int r = (int)blockIdx.x >> 3;
           bx = r & 7; r >>= 3; by = r & 63; ks = r >> 6; }

    const int we = (we_param >= 0) ? we_param : e;
    const int cnt = counts[e];
    const int row_end = min(cnt, row_start + cap);
    const int row0 = row_start + by * 64;
    if (row0 >= row_end) return;
    const int n0 = bx * BN;
    const int hb = packed ? packed_base(counts, e) : 0;
    const int tid = threadIdx.x;

    const int kspan = H_DIM / splitk;
    const int k0 = ks * kspan;

    const int wv = tid >> 6, lane = tid & 63;
    const int schunk = (lane & 7) ^ (lane >> 3);
    const unsigned short* __restrict__ w2e = w2t + (size_t)we * D_DIM * H_DIM;

    const unsigned short* aptr[2];
#pragma unroll
    for (int j = 0; j < 2; ++j) {
        const int rloc = (wv * 2 + j) * 8 + (lane >> 3);   // 0..63
        int r = row0 + rloc; if (r >= row_end) r = row_end - 1;
        aptr[j] = h_ws + (size_t)(hb + r - row_start) * H_DIM + k0 + schunk * 8;
    }
    const unsigned short* bptr[4];
#pragma unroll
    for (int j = 0; j < 4; ++j) {
        const int rloc = (wv * 4 + j) * 8 + (lane >> 3);   // 0..127
        bptr[j] = w2e + (size_t)(n0 + rloc) * H_DIM + k0 + schunk * 8;
    }

    const int wc = wv * 32;
    const int rl = lane & 15, x7 = lane & 7, kg = lane >> 4;
    int aoff[2][4], boff[2][2];
#pragma unroll
    for (int s = 0; s < 2; ++s) {
        const int slot = ((((s << 2) + kg) ^ x7) << 3);
#pragma unroll
        for (int m = 0; m < 4; ++m) aoff[s][m] = ((m * 16 + rl) << 6) + slot;
#pragma unroll
        for (int n = 0; n < 2; ++n) boff[s][n] = ((wc + n * 16 + rl) << 6) + slot;
    }

    f32x4 acc[4][2];
#pragma unroll
    for (int m = 0; m < 4; ++m)
#pragma unroll
        for (int n = 0; n < 2; ++n) acc[m][n] = (f32x4){0.f, 0.f, 0.f, 0.f};

    for (int kk = 0; kk < kspan; kk += BK) {
        __syncthreads();
#pragma unroll
        for (int j = 0; j < 2; ++j)
            gload16(aptr[j] + kk, &As[(wv * 2 + j) * 512]);
#pragma unroll
        for (int j = 0; j < 4; ++j)
            gload16(bptr[j] + kk, &Bs[(wv * 4 + j) * 512]);
        __syncthreads();
#pragma unroll
        for (int s = 0; s < 2; ++s) {
            bf16x8 af[4], bfv[2];
#pragma unroll
            for (int m = 0; m < 4; ++m) af[m] = *(const bf16x8*)&As[aoff[s][m]];
#pragma unroll
            for (int n = 0; n < 2; ++n) bfv[n] = *(const bf16x8*)&Bs[boff[s][n]];
#pragma unroll
            for (int m = 0; m < 4; ++m)
#pragma unroll
                for (int n = 0; n < 2; ++n)
                    acc[m][n] = __builtin_amdgcn_mfma_f32_16x16x32_bf16(af[m], bfv[n], acc[m][n], 0, 0, 0);
        }
    }

    const float* __restrict__ b2e = b2 + e * D_DIM;
    const int crb = (lane >> 4) * 4, ccol = lane & 15;
#pragma unroll
    for (int n = 0; n < 2; ++n) {
        const int gc = n0 + wc + n * 16 + ccol;
        const float bias = (ks == 0) ? b2e[gc] : 0.f;
#pragma unroll
        for (int m = 0; m < 4; ++m) {
#pragma unroll
            for (int j = 0; j < 4; ++j) {
                const int gr = row0 + m * 16 + crb + j;
                if (gr < row_end) {
                    const float yv = acc[m][n][j] + bias;
                    const int t = tok_list[e * CAP_E + gr];
                    const float p = prob_list[e * CAP_E + gr];
                    atomicAdd(&out[(size_t)t * D_DIM + gc], p * yv);
                }
            }
        }
    }
}

extern "C" void kernel_launch(void* const* d_in, const int* in_sizes, int n_in,
                              void* d_out, int out_size, void* d_ws, size_t ws_size,
                              hipStream_t stream)
{
    const float* x  = (const float*)d_in[0];
    const float* w1 = (const float*)d_in[1];
    const float* b1 = (const float*)d_in[2];
    const float* w2 = (const float*)d_in[3];
    const float* b2 = (const float*)d_in[4];
    const float* gw = (const float*)d_in[5];
    const float* gb = (const float*)d_in[6];
    float* out = (float*)d_out;

    char* w = (char*)d_ws;
    int*   counts    = (int*)w;
    int*   tok_list  = (int*)(w + 128);
    float* prob_list = (float*)(w + 128 + (size_t)CAP_E * E_NUM * 4);
    size_t off = 128 + 2 * (size_t)CAP_E * E_NUM * 4;
    off = (off + 255) & ~(size_t)255;
    unsigned short* xb = (unsigned short*)(w + off);
    off += (size_t)NTOK * D_DIM * 2;

    const size_t wslab = (size_t)D_DIM * H_DIM * 2;       // bf16 per expert
    const size_t hfull = (size_t)2 * NTOK * H_DIM * 2;    // packed h, bf16
    const size_t need_full = off + 2 * E_NUM * wslab + hfull;

    hipMemsetAsync(counts, 0, 64, stream);

    if (ws_size >= need_full) {
        unsigned short* w1t = (unsigned short*)(w + off);
        unsigned short* w2t = (unsigned short*)(w + off + E_NUM * wslab);
        unsigned short* h_ws = (unsigned short*)(w + off + 2 * E_NUM * wslab);

        // A: gate || w1-transpose || zero-d_out (one launch)
        fused_gate_w1trans<<<GATE_BLKS + W1T_BLKS + ZERO_BLKS, 256, 0, stream>>>(
            x, gw, gb, counts, tok_list, prob_list, xb, w1, w1t, out);
        // B: fc1 || w2-transpose (fc1 reads A's outputs; w2t read only by fc2)
        fused_fc1_w2trans<<<FC1_BLKS + W2T_BLKS, 256, 0, stream>>>(
            xb, w1t, b1, counts, tok_list, h_ws, w2, w2t);
        // C: fc2 (expert->XCD pinned decode; atomics into zeroed out)
        expert_fc2<<<8 * 8 * 64 * 2, 256, 0, stream>>>(
            h_ws, w2t, b2, counts, tok_list, prob_list, out,
            2, -1, -1, 0, NTOK, 1);
    } else {
        // per-expert chunked fallback (atomics)
        hipMemsetAsync(d_out, 0, (size_t)out_size * sizeof(float), stream);
        gate_kernel<<<GATE_BLKS, 256, 0, stream>>>(x, gw, gb, counts, tok_list, prob_list, xb);
        unsigned short* w1te = (unsigned short*)(w + off);
        unsigned short* w2te = (unsigned short*)(w + off + wslab);
        size_t h_off = off + 2 * wslab;
        unsigned short* h_e = (unsigned short*)(w + h_off);
        size_t h_avail = (ws_size > h_off) ? (ws_size - h_off) / ((size_t)H_DIM * 2) : 0;
        int cap = (int)((h_avail < (size_t)NTOK) ? h_avail : (size_t)NTOK);
        cap = (cap / BM) * BM;
        if (cap < BM) cap = BM;
        const int chunks = (NTOK + cap - 1) / cap;
        for (int e = 0; e < E_NUM; ++e) {
            wtrans_kernel<<<dim3(H_DIM / 64, D_DIM / 64, 1), 256, 0, stream>>>(
                w1 + (size_t)e * D_DIM * H_DIM, w1te, D_DIM, H_DIM);
            wtrans_kernel<<<dim3(D_DIM / 64, H_DIM / 64, 1), 256, 0, stream>>>(
                w2 + (size_t)e * H_DIM * D_DIM, w2te, H_DIM, D_DIM);
            for (int c = 0; c < chunks; ++c) {
                const int rs = c * cap;
                expert_fc1<<<32 * ((cap + 63) / 64), 256, 0, stream>>>(
                    xb, w1te, b1, counts, tok_list, h_e,
                    e, 0, rs, cap, 0);
                expert_fc2<<<8 * ((cap + 63) / 64), 256, 0, stream>>>(
                    h_e, w2te, b2, counts, tok_list, prob_list, out,
                    1, e, 0, rs, cap, 0);
            }
        }
    }
}